// Round 5
// baseline (764.848 us; speedup 1.0000x reference)
//
#include <hip/hip_runtime.h>
#include <cstdint>

#define DEV __device__ __forceinline__

typedef __attribute__((ext_vector_type(4))) float f32x4;
typedef __attribute__((ext_vector_type(4))) float float4v;
typedef __attribute__((ext_vector_type(8))) short bf16x8;
typedef __attribute__((ext_vector_type(4))) unsigned short ushort4v;
typedef __attribute__((ext_vector_type(2))) unsigned int uint2v;
typedef unsigned short u16;

static constexpr int Bb = 4, Tt = 2048, Hh = 16, KVh = 4, Dd = 128;

DEV u16 f2bf(float x) {
    union { float f; unsigned u; } v; v.f = x;
    unsigned r = v.u + 0x7FFF + ((v.u >> 16) & 1);
    return (u16)(r >> 16);
}
DEV float bf2f(u16 b) {
    union { unsigned u; float f; } v; v.u = ((unsigned)b) << 16;
    return v.f;
}
DEV unsigned cvtpk(float lo, float hi) {
    unsigned d;
    asm("v_cvt_pk_bf16_f32 %0, %1, %2" : "=v"(d) : "v"(lo), "v"(hi));
    return d;
}

typedef const void __attribute__((address_space(1)))* gas1;
typedef void __attribute__((address_space(3)))* las3;
DEV void gload16(const void* g, void* l) {
    __builtin_amdgcn_global_load_lds((gas1)g, (las3)l, 16, 0, 0);
}

// ---------------- cast x -> bf16 ----------------
__global__ __launch_bounds__(256) void cast_k(const float* __restrict__ x, u16* __restrict__ xb, long n4) {
    long id = (long)blockIdx.x * 256 + threadIdx.x;
    if (id >= n4) return;
    float4v v = *(const float4v*)&x[id * 4];
    ushort4v o;
    o[0] = f2bf(v[0]); o[1] = f2bf(v[1]); o[2] = f2bf(v[2]); o[3] = f2bf(v[3]);
    *(ushort4v*)&xb[id * 4] = o;
}

// ---------------- transpose+cast weight: W (K x N) f32 -> Wt (N x K) bf16 ----------------
__global__ __launch_bounds__(256) void twt_k(const float* __restrict__ W, u16* __restrict__ Wt, int K, int N) {
    __shared__ float tile[32][33];
    int tx = threadIdx.x, ty = threadIdx.y;
    long n0 = (long)blockIdx.x * 32, k0 = (long)blockIdx.y * 32;
#pragma unroll
    for (int j = 0; j < 4; j++)
        tile[ty + j * 8][tx] = W[(k0 + ty + j * 8) * (long)N + n0 + tx];
    __syncthreads();
#pragma unroll
    for (int j = 0; j < 4; j++)
        Wt[(n0 + ty + j * 8) * (long)K + k0 + tx] = f2bf(tile[tx][ty + j * 8]);
}

// ---------------- transpose v (b,t,kv,d) -> vt (b,kv,d,t) ----------------
__global__ __launch_bounds__(256) void tv_k(const u16* __restrict__ v, u16* __restrict__ vt) {
    __shared__ u16 tile[32][33];
    int tx = threadIdx.x, ty = threadIdx.y;
    int d0 = blockIdx.x * 32;
    int t0 = blockIdx.y * 32;
    int bk = blockIdx.z;
    int b = bk >> 2, kv = bk & 3;
#pragma unroll
    for (int j = 0; j < 4; j++)
        tile[ty + j * 8][tx] = v[((long)(b * Tt + t0 + ty + j * 8) * KVh + kv) * Dd + d0 + tx];
    __syncthreads();
#pragma unroll
    for (int j = 0; j < 4; j++)
        vt[((long)(b * KVh + kv) * Dd + d0 + ty + j * 8) * Tt + t0 + tx] = tile[tx][ty + j * 8];
}

// ---------------- rope tables: [t][i], i<64 ----------------
__global__ __launch_bounds__(256) void tables_k(float* __restrict__ cosb, float* __restrict__ sinb) {
    int id = blockIdx.x * 256 + threadIdx.x; // < 2048*64
    int t = id >> 6, i = id & 63;
    float inv = powf(10000.0f, -(float)i * (1.0f / 64.0f));
    float f = (float)t * inv;
    cosb[id] = cosf(f);
    sinb[id] = sinf(f);
}

// ---------------- rope in-place on (b,t,nh,128); scale folded for q ----------------
__global__ __launch_bounds__(256) void rope_k(u16* __restrict__ p, const float* __restrict__ cosb,
                                              const float* __restrict__ sinb, int nh, float scale, int total) {
    int id = blockIdx.x * 256 + threadIdx.x;
    if (id >= total) return;
    int i = id & 63;
    int bth = id >> 6;
    int t = (bth / nh) % Tt;
    u16* ptr = p + (long)bth * Dd;
    float x1 = bf2f(ptr[i]), x2 = bf2f(ptr[i + 64]);
    float c = cosb[t * 64 + i], s = sinb[t * 64 + i];
    ptr[i] = f2bf((x1 * c - x2 * s) * scale);
    ptr[i + 64] = f2bf((x2 * c + x1 * s) * scale);
}

// ---------------- GEMM: A (M x K) bf16 row-major, Bt (N x K) bf16 row-major -> C (M x N) ----------------
template <int F32OUT>
__global__ __launch_bounds__(256) void gemm_k(const u16* __restrict__ A, const u16* __restrict__ Bt,
                                              void* __restrict__ Cout, int M, int N, int K) {
    __shared__ u16 aLds[128 * 32];
    __shared__ u16 bLds[128 * 32];
    const int tid = threadIdx.x;
    const int lane = tid & 63;
    const int wid = __builtin_amdgcn_readfirstlane(tid >> 6);
    const long m0 = (long)blockIdx.x * 128;
    const long n0 = (long)blockIdx.y * 128;
    const int wr = wid >> 1, wc = wid & 1;
    const int r0 = wid * 32;
    const int lrow = lane >> 2;
    const int lkb = (lane & 3) * 8;
    const u16* gA = A + (m0 + r0 + lrow) * (long)K + lkb;
    const u16* gB = Bt + (n0 + r0 + lrow) * (long)K + lkb;
    u16* lA = &aLds[r0 * 32];
    u16* lB = &bLds[r0 * 32];
    f32x4 acc[4][4] = {};
    const int fr = lane & 15, fk = (lane >> 4) * 8;
    for (int kt = 0; kt < K; kt += 32) {
        gload16(gA + kt, lA);
        gload16(gA + kt + 16 * (long)K, lA + 16 * 32);
        gload16(gB + kt, lB);
        gload16(gB + kt + 16 * (long)K, lB + 16 * 32);
        __syncthreads();
        bf16x8 af[4], bfr[4];
#pragma unroll
        for (int i = 0; i < 4; i++) {
            af[i] = *(const bf16x8*)&aLds[(wr * 64 + i * 16 + fr) * 32 + fk];
            bfr[i] = *(const bf16x8*)&bLds[(wc * 64 + i * 16 + fr) * 32 + fk];
        }
#pragma unroll
        for (int i = 0; i < 4; i++)
#pragma unroll
            for (int j = 0; j < 4; j++)
                acc[i][j] = __builtin_amdgcn_mfma_f32_16x16x32_bf16(af[i], bfr[j], acc[i][j], 0, 0, 0);
        __syncthreads();
    }
    const int orow = (lane >> 4) * 4, ocol = lane & 15;
#pragma unroll
    for (int i = 0; i < 4; i++)
#pragma unroll
        for (int j = 0; j < 4; j++) {
            long r = m0 + wr * 64 + i * 16 + orow;
            long c = n0 + wc * 64 + j * 16 + ocol;
#pragma unroll
            for (int t = 0; t < 4; t++) {
                if (F32OUT)
                    ((float*)Cout)[(r + t) * N + c] = acc[i][j][t];
                else
                    ((u16*)Cout)[(r + t) * N + c] = f2bf(acc[i][j][t]);
            }
        }
}

// ---------------- flash attention v4: 1 wave/block, swapped QK^T, in-reg softmax, LDS P^T ----------------
// S^T = mfma(K,Q): lane holds q (col) = lane&15; k (row) = kf*16 + (lane>>4)*4 + r.
// P^T staged in LDS as pT[qi][q=fr][k] (padded row 40): write 4 packed bf16 per (qi,kf) via b64,
// read B-frag as contiguous b128 at pT[qi][fr][kg*8] (k = kg*8+j matches V^T A-frag slotting).
// O^T = mfma(V^T, P): lane holds q (col) = lane&15, d (row) = df*16 + (lane>>4)*4 + r.
// q pre-scaled by (1/sqrt(D))*log2(e) so softmax uses exp2 directly.
__global__ __launch_bounds__(64, 3) void attn_k(const u16* __restrict__ q, const u16* __restrict__ k,
                                                const u16* __restrict__ vt, u16* __restrict__ o) {
    __shared__ u16 pT[2][16][40];     // [qi][q-row][k-col], row stride 80B (8B-aligned, bank-spread)
    const int lane = threadIdx.x;
    const int qt = 63 - blockIdx.x;   // heavy blocks first
    const int h = blockIdx.y, b = blockIdx.z;
    const int kv = h >> 2;
    const int q0 = qt * 32;
    const int fr = lane & 15, kg = lane >> 4;
    const long HD = (long)Hh * Dd;
    const long KD = (long)KVh * Dd;
    const long qbase = ((long)(b * Tt + q0)) * HD + (long)h * Dd;
    const long kbase = ((long)(b * Tt)) * KD + (long)kv * Dd;
    const long vbase = ((long)(b * KVh + kv)) * (long)Dd * Tt;

    bf16x8 qa[2][4];
#pragma unroll
    for (int qi = 0; qi < 2; qi++)
#pragma unroll
        for (int kc = 0; kc < 4; kc++)
            qa[qi][kc] = *(const bf16x8*)&q[qbase + (long)(qi * 16 + fr) * HD + kc * 32 + kg * 8];

    f32x4 ot[8][2] = {};              // O^T accumulator: [df][qi]
    float mr0 = -1e30f, mr1 = -1e30f, lr0 = 0.0f, lr1 = 0.0f;

    const int nt = qt + 1;

    for (int it = 0; it < nt; ++it) {
        const long s0 = (long)it * 32;
        // ---- S^T = K * Q^T ----
        f32x4 st[2][2] = {};          // [kf][qi]
#pragma unroll
        for (int kf = 0; kf < 2; kf++) {
            bf16x8 ka[4];
#pragma unroll
            for (int kc = 0; kc < 4; kc++)
                ka[kc] = *(const bf16x8*)&k[kbase + (s0 + kf * 16 + fr) * KD + kc * 32 + kg * 8];
#pragma unroll
            for (int kc = 0; kc < 4; kc++) {
                st[kf][0] = __builtin_amdgcn_mfma_f32_16x16x32_bf16(ka[kc], qa[0][kc], st[kf][0], 0, 0, 0);
                st[kf][1] = __builtin_amdgcn_mfma_f32_16x16x32_bf16(ka[kc], qa[1][kc], st[kf][1], 0, 0, 0);
            }
        }
        // ---- causal mask (only the diagonal tile) ----
        if (it == nt - 1) {
            const int kb0 = (int)s0 + kg * 4;
#pragma unroll
            for (int kf = 0; kf < 2; kf++)
#pragma unroll
                for (int qi = 0; qi < 2; qi++) {
                    const int qq = q0 + qi * 16 + fr;
#pragma unroll
                    for (int r = 0; r < 4; r++)
                        if (kb0 + kf * 16 + r > qq) st[kf][qi][r] = -1e30f;
                }
        }
        // ---- in-register online softmax (base-2 domain), rescale every tile ----
        float tm0 = fmaxf(fmaxf(fmaxf(st[0][0][0], st[0][0][1]), fmaxf(st[0][0][2], st[0][0][3])),
                          fmaxf(fmaxf(st[1][0][0], st[1][0][1]), fmaxf(st[1][0][2], st[1][0][3])));
        float tm1 = fmaxf(fmaxf(fmaxf(st[0][1][0], st[0][1][1]), fmaxf(st[0][1][2], st[0][1][3])),
                          fmaxf(fmaxf(st[1][1][0], st[1][1][1]), fmaxf(st[1][1][2], st[1][1][3])));
        tm0 = fmaxf(tm0, __shfl_xor(tm0, 16)); tm0 = fmaxf(tm0, __shfl_xor(tm0, 32));
        tm1 = fmaxf(tm1, __shfl_xor(tm1, 16)); tm1 = fmaxf(tm1, __shfl_xor(tm1, 32));
        {
            float mn0 = fmaxf(mr0, tm0), mn1 = fmaxf(mr1, tm1);
            float al0 = __builtin_amdgcn_exp2f(mr0 - mn0);
            float al1 = __builtin_amdgcn_exp2f(mr1 - mn1);
            mr0 = mn0; mr1 = mn1;
            lr0 *= al0; lr1 *= al1;
#pragma unroll
            for (int df = 0; df < 8; df++) { ot[df][0] *= al0; ot[df][1] *= al1; }
        }
        f32x4 p00, p10, p01, p11;
#pragma unroll
        for (int r = 0; r < 4; r++) {
            p00[r] = __builtin_amdgcn_exp2f(st[0][0][r] - mr0);
            p10[r] = __builtin_amdgcn_exp2f(st[1][0][r] - mr0);
            p01[r] = __builtin_amdgcn_exp2f(st[0][1][r] - mr1);
            p11[r] = __builtin_amdgcn_exp2f(st[1][1][r] - mr1);
        }
        float rs0 = ((p00[0] + p00[1]) + (p00[2] + p00[3])) + ((p10[0] + p10[1]) + (p10[2] + p10[3]));
        float rs1 = ((p01[0] + p01[1]) + (p01[2] + p01[3])) + ((p11[0] + p11[1]) + (p11[2] + p11[3]));
        rs0 += __shfl_xor(rs0, 16); rs0 += __shfl_xor(rs0, 32);
        rs1 += __shfl_xor(rs1, 16); rs1 += __shfl_xor(rs1, 32);
        lr0 += rs0; lr1 += rs1;
        // ---- stage P^T in LDS: lane (fr,kg) owns k = kf*16 + kg*4 + r for q-col fr ----
        {
            uint2v a; a[0] = cvtpk(p00[0], p00[1]); a[1] = cvtpk(p00[2], p00[3]);
            *(uint2v*)&pT[0][fr][kg * 4] = a;
            uint2v bwd; bwd[0] = cvtpk(p10[0], p10[1]); bwd[1] = cvtpk(p10[2], p10[3]);
            *(uint2v*)&pT[0][fr][16 + kg * 4] = bwd;
            uint2v c; c[0] = cvtpk(p01[0], p01[1]); c[1] = cvtpk(p01[2], p01[3]);
            *(uint2v*)&pT[1][fr][kg * 4] = c;
            uint2v d; d[0] = cvtpk(p11[0], p11[1]); d[1] = cvtpk(p11[2], p11[3]);
            *(uint2v*)&pT[1][fr][16 + kg * 4] = d;
        }
        __syncthreads();
        bf16x8 bq0 = *(const bf16x8*)&pT[0][fr][kg * 8];
        bf16x8 bq1 = *(const bf16x8*)&pT[1][fr][kg * 8];
        // ---- O^T += V^T * P ----
#pragma unroll
        for (int df = 0; df < 8; df++) {
            bf16x8 va = *(const bf16x8*)&vt[vbase + (long)(df * 16 + fr) * Tt + s0 + kg * 8];
            ot[df][0] = __builtin_amdgcn_mfma_f32_16x16x32_bf16(va, bq0, ot[df][0], 0, 0, 0);
            ot[df][1] = __builtin_amdgcn_mfma_f32_16x16x32_bf16(va, bq1, ot[df][1], 0, 0, 0);
        }
    }
    // ---- store: lane holds 4 consecutive d (row) for q (col) = qi*16+fr ----
    const float il0 = 1.0f / lr0, il1 = 1.0f / lr1;
#pragma unroll
    for (int df = 0; df < 8; df++) {
        uint2v w0, w1;
        w0[0] = cvtpk(ot[df][0][0] * il0, ot[df][0][1] * il0);
        w0[1] = cvtpk(ot[df][0][2] * il0, ot[df][0][3] * il0);
        w1[0] = cvtpk(ot[df][1][0] * il1, ot[df][1][1] * il1);
        w1[1] = cvtpk(ot[df][1][2] * il1, ot[df][1][3] * il1);
        *(uint2v*)&o[qbase + (long)(fr) * HD + df * 16 + kg * 4] = w0;
        *(uint2v*)&o[qbase + (long)(16 + fr) * HD + df * 16 + kg * 4] = w1;
    }
}

extern "C" void kernel_launch(void* const* d_in, const int* in_sizes, int n_in,
                              void* d_out, int out_size, void* d_ws, size_t ws_size,
                              hipStream_t stream) {
    (void)in_sizes; (void)n_in; (void)out_size; (void)ws_size;
    const float* x = (const float*)d_in[0];
    const float* Wq = (const float*)d_in[1];
    const float* Wk = (const float*)d_in[2];
    const float* Wv = (const float*)d_in[3];
    const float* Wo = (const float*)d_in[4];

    char* ws = (char*)d_ws;
    u16* xb   = (u16*)(ws + 0);            // 33.5MB  (b,t,c) bf16; later reused as attn output (b,t,h,d)
    u16* kbuf = (u16*)(ws + 33554432);     // 8.4MB   (b,t,kv,d)
    u16* vbuf = (u16*)(ws + 41943040);     // 8.4MB   (b,t,kv,d)
    u16* vtb  = (u16*)(ws + 50331648);     // 8.4MB   (b,kv,d,t)
    u16* wqt  = (u16*)(ws + 58720256);     // 8.4MB
    u16* wkt  = (u16*)(ws + 67108864);     // 2.1MB
    u16* wvt  = (u16*)(ws + 69206016);     // 2.1MB
    u16* wot  = (u16*)(ws + 71303168);     // 8.4MB
    float* cosb = (float*)(ws + 79691776); // 0.5MB
    float* sinb = (float*)(ws + 80216064); // 0.5MB
    u16* qbuf = (u16*)d_out;               // q (b,t,h,d) bf16 lives in d_out until final GEMM

    dim3 tb(32, 8);
    cast_k<<<16384, 256, 0, stream>>>(x, xb, 4194304);
    twt_k<<<dim3(64, 64), tb, 0, stream>>>(Wq, wqt, 2048, 2048);
    twt_k<<<dim3(16, 64), tb, 0, stream>>>(Wk, wkt, 2048, 512);
    twt_k<<<dim3(16, 64), tb, 0, stream>>>(Wv, wvt, 2048, 512);
    twt_k<<<dim3(64, 64), tb, 0, stream>>>(Wo, wot, 2048, 2048);
    tables_k<<<512, 256, 0, stream>>>(cosb, sinb);

    gemm_k<0><<<dim3(64, 16), 256, 0, stream>>>(xb, wqt, qbuf, 8192, 2048, 2048);
    gemm_k<0><<<dim3(64, 4), 256, 0, stream>>>(xb, wkt, kbuf, 8192, 512, 2048);
    gemm_k<0><<<dim3(64, 4), 256, 0, stream>>>(xb, wvt, vbuf, 8192, 512, 2048);

    // q scale = (1/sqrt(128)) * log2(e) -> softmax runs in exp2 domain
    rope_k<<<32768, 256, 0, stream>>>(qbuf, cosb, sinb, 16, 0.1275174316f, 8388608);
    rope_k<<<8192, 256, 0, stream>>>(kbuf, cosb, sinb, 4, 1.0f, 2097152);
    tv_k<<<dim3(4, 64, 16), tb, 0, stream>>>(vbuf, vtb);

    attn_k<<<dim3(64, 16, 4), 64, 0, stream>>>(qbuf, kbuf, vtb, xb);

    gemm_k<1><<<dim3(64, 16), 256, 0, stream>>>(xb, wot, d_out, 8192, 2048, 2048);
}

// Round 6
// 753.628 us; speedup vs baseline: 1.0149x; 1.0149x over previous
//
#include <hip/hip_runtime.h>
#include <cstdint>

#define DEV __device__ __forceinline__

typedef __attribute__((ext_vector_type(4))) float f32x4;
typedef __attribute__((ext_vector_type(4))) float float4v;
typedef __attribute__((ext_vector_type(8))) short bf16x8;
typedef __attribute__((ext_vector_type(4))) unsigned short ushort4v;
typedef __attribute__((ext_vector_type(2))) unsigned int uint2v;
typedef unsigned short u16;

static constexpr int Bb = 4, Tt = 2048, Hh = 16, KVh = 4, Dd = 128;

DEV u16 f2bf(float x) {
    union { float f; unsigned u; } v; v.f = x;
    unsigned r = v.u + 0x7FFF + ((v.u >> 16) & 1);
    return (u16)(r >> 16);
}
DEV float bf2f(u16 b) {
    union { unsigned u; float f; } v; v.u = ((unsigned)b) << 16;
    return v.f;
}
DEV unsigned cvtpk(float lo, float hi) {
    unsigned d;
    asm("v_cvt_pk_bf16_f32 %0, %1, %2" : "=v"(d) : "v"(lo), "v"(hi));
    return d;
}

typedef const void __attribute__((address_space(1)))* gas1;
typedef void __attribute__((address_space(3)))* las3;
DEV void gload16(const void* g, void* l) {
    __builtin_amdgcn_global_load_lds((gas1)g, (las3)l, 16, 0, 0);
}

// ---------------- cast x -> bf16 ----------------
__global__ __launch_bounds__(256) void cast_k(const float* __restrict__ x, u16* __restrict__ xb, long n4) {
    long id = (long)blockIdx.x * 256 + threadIdx.x;
    if (id >= n4) return;
    float4v v = *(const float4v*)&x[id * 4];
    ushort4v o;
    o[0] = f2bf(v[0]); o[1] = f2bf(v[1]); o[2] = f2bf(v[2]); o[3] = f2bf(v[3]);
    *(ushort4v*)&xb[id * 4] = o;
}

// ---------------- transpose+cast weight: W (K x N) f32 -> Wt (N x K) bf16 ----------------
__global__ __launch_bounds__(256) void twt_k(const float* __restrict__ W, u16* __restrict__ Wt, int K, int N) {
    __shared__ float tile[32][33];
    int tx = threadIdx.x, ty = threadIdx.y;
    long n0 = (long)blockIdx.x * 32, k0 = (long)blockIdx.y * 32;
#pragma unroll
    for (int j = 0; j < 4; j++)
        tile[ty + j * 8][tx] = W[(k0 + ty + j * 8) * (long)N + n0 + tx];
    __syncthreads();
#pragma unroll
    for (int j = 0; j < 4; j++)
        Wt[(n0 + ty + j * 8) * (long)K + k0 + tx] = f2bf(tile[tx][ty + j * 8]);
}

// ---------------- transpose v (b,t,kv,d) -> vt (b,kv,d,t) ----------------
__global__ __launch_bounds__(256) void tv_k(const u16* __restrict__ v, u16* __restrict__ vt) {
    __shared__ u16 tile[32][33];
    int tx = threadIdx.x, ty = threadIdx.y;
    int d0 = blockIdx.x * 32;
    int t0 = blockIdx.y * 32;
    int bk = blockIdx.z;
    int b = bk >> 2, kv = bk & 3;
#pragma unroll
    for (int j = 0; j < 4; j++)
        tile[ty + j * 8][tx] = v[((long)(b * Tt + t0 + ty + j * 8) * KVh + kv) * Dd + d0 + tx];
    __syncthreads();
#pragma unroll
    for (int j = 0; j < 4; j++)
        vt[((long)(b * KVh + kv) * Dd + d0 + ty + j * 8) * Tt + t0 + tx] = tile[tx][ty + j * 8];
}

// ---------------- rope tables: [t][i], i<64 ----------------
__global__ __launch_bounds__(256) void tables_k(float* __restrict__ cosb, float* __restrict__ sinb) {
    int id = blockIdx.x * 256 + threadIdx.x; // < 2048*64
    int t = id >> 6, i = id & 63;
    float inv = powf(10000.0f, -(float)i * (1.0f / 64.0f));
    float f = (float)t * inv;
    cosb[id] = cosf(f);
    sinb[id] = sinf(f);
}

// ---------------- rope in-place on (b,t,nh,128); scale folded for q ----------------
__global__ __launch_bounds__(256) void rope_k(u16* __restrict__ p, const float* __restrict__ cosb,
                                              const float* __restrict__ sinb, int nh, float scale, int total) {
    int id = blockIdx.x * 256 + threadIdx.x;
    if (id >= total) return;
    int i = id & 63;
    int bth = id >> 6;
    int t = (bth / nh) % Tt;
    u16* ptr = p + (long)bth * Dd;
    float x1 = bf2f(ptr[i]), x2 = bf2f(ptr[i + 64]);
    float c = cosb[t * 64 + i], s = sinb[t * 64 + i];
    ptr[i] = f2bf((x1 * c - x2 * s) * scale);
    ptr[i + 64] = f2bf((x2 * c + x1 * s) * scale);
}

// ---------------- GEMM: A (M x K) bf16 row-major, Bt (N x K) bf16 row-major -> C (M x N) ----------------
template <int F32OUT>
__global__ __launch_bounds__(256) void gemm_k(const u16* __restrict__ A, const u16* __restrict__ Bt,
                                              void* __restrict__ Cout, int M, int N, int K) {
    __shared__ u16 aLds[128 * 32];
    __shared__ u16 bLds[128 * 32];
    const int tid = threadIdx.x;
    const int lane = tid & 63;
    const int wid = __builtin_amdgcn_readfirstlane(tid >> 6);
    const long m0 = (long)blockIdx.x * 128;
    const long n0 = (long)blockIdx.y * 128;
    const int wr = wid >> 1, wc = wid & 1;
    const int r0 = wid * 32;
    const int lrow = lane >> 2;
    const int lkb = (lane & 3) * 8;
    const u16* gA = A + (m0 + r0 + lrow) * (long)K + lkb;
    const u16* gB = Bt + (n0 + r0 + lrow) * (long)K + lkb;
    u16* lA = &aLds[r0 * 32];
    u16* lB = &bLds[r0 * 32];
    f32x4 acc[4][4] = {};
    const int fr = lane & 15, fk = (lane >> 4) * 8;
    for (int kt = 0; kt < K; kt += 32) {
        gload16(gA + kt, lA);
        gload16(gA + kt + 16 * (long)K, lA + 16 * 32);
        gload16(gB + kt, lB);
        gload16(gB + kt + 16 * (long)K, lB + 16 * 32);
        __syncthreads();
        bf16x8 af[4], bfr[4];
#pragma unroll
        for (int i = 0; i < 4; i++) {
            af[i] = *(const bf16x8*)&aLds[(wr * 64 + i * 16 + fr) * 32 + fk];
            bfr[i] = *(const bf16x8*)&bLds[(wc * 64 + i * 16 + fr) * 32 + fk];
        }
#pragma unroll
        for (int i = 0; i < 4; i++)
#pragma unroll
            for (int j = 0; j < 4; j++)
                acc[i][j] = __builtin_amdgcn_mfma_f32_16x16x32_bf16(af[i], bfr[j], acc[i][j], 0, 0, 0);
        __syncthreads();
    }
    const int orow = (lane >> 4) * 4, ocol = lane & 15;
#pragma unroll
    for (int i = 0; i < 4; i++)
#pragma unroll
        for (int j = 0; j < 4; j++) {
            long r = m0 + wr * 64 + i * 16 + orow;
            long c = n0 + wc * 64 + j * 16 + ocol;
#pragma unroll
            for (int t = 0; t < 4; t++) {
                if (F32OUT)
                    ((float*)Cout)[(r + t) * N + c] = acc[i][j][t];
                else
                    ((u16*)Cout)[(r + t) * N + c] = f2bf(acc[i][j][t]);
            }
        }
}

// ---------------- flash attention v5: 1 wave/block, KVBLK=64, swapped QK^T, in-reg softmax, LDS P^T ----------------
// S^T = mfma(K,Q): lane holds q (col) = lane&15; k (row) = kf*16 + (lane>>4)*4 + r, kf=0..3.
// P^T staged per-wave in LDS pT[qi][q=fr][k0..63] (row stride 72): b64 writes, b128 B-frag reads.
// O^T = mfma(V^T, P) over two ks-slices; defer-max (T13, thr=8 base-2) skips ot rescale most tiles.
__global__ __launch_bounds__(64, 3) void attn_k(const u16* __restrict__ q, const u16* __restrict__ k,
                                                const u16* __restrict__ vt, u16* __restrict__ o) {
    __shared__ u16 pT[2][16][72];
    const int lane = threadIdx.x;
    const int qt = 63 - blockIdx.x;   // heavy blocks first
    const int h = blockIdx.y, b = blockIdx.z;
    const int kv = h >> 2;
    const int q0 = qt * 32;
    const int fr = lane & 15, kg = lane >> 4;
    const long HD = (long)Hh * Dd;
    const long KD = (long)KVh * Dd;
    const long qbase = ((long)(b * Tt + q0)) * HD + (long)h * Dd;
    const long kbase = ((long)(b * Tt)) * KD + (long)kv * Dd;
    const long vbase = ((long)(b * KVh + kv)) * (long)Dd * Tt;

    bf16x8 qa[2][4];
#pragma unroll
    for (int qi = 0; qi < 2; qi++)
#pragma unroll
        for (int kc = 0; kc < 4; kc++)
            qa[qi][kc] = *(const bf16x8*)&q[qbase + (long)(qi * 16 + fr) * HD + kc * 32 + kg * 8];

    f32x4 ot[8][2] = {};              // O^T accumulator: [df][qi]
    float mr0 = -1e30f, mr1 = -1e30f, lr0 = 0.0f, lr1 = 0.0f;

    const int nt = (q0 + 95) >> 6;    // k-tiles of 64 covering [0, q0+32)

    for (int it = 0; it < nt; ++it) {
        const long s0 = (long)it * 64;
        // ---- S^T = K * Q^T, four 16-row k-fragments in two load halves ----
        f32x4 st[4][2] = {};          // [kf][qi]
#pragma unroll
        for (int kfh = 0; kfh < 2; kfh++) {
            bf16x8 ka[2][4];
#pragma unroll
            for (int j = 0; j < 2; j++)
#pragma unroll
                for (int kc = 0; kc < 4; kc++)
                    ka[j][kc] = *(const bf16x8*)&k[kbase + (s0 + (kfh * 2 + j) * 16 + fr) * KD + kc * 32 + kg * 8];
#pragma unroll
            for (int j = 0; j < 2; j++)
#pragma unroll
                for (int kc = 0; kc < 4; kc++) {
                    st[kfh * 2 + j][0] = __builtin_amdgcn_mfma_f32_16x16x32_bf16(ka[j][kc], qa[0][kc], st[kfh * 2 + j][0], 0, 0, 0);
                    st[kfh * 2 + j][1] = __builtin_amdgcn_mfma_f32_16x16x32_bf16(ka[j][kc], qa[1][kc], st[kfh * 2 + j][1], 0, 0, 0);
                }
        }
        // ---- causal mask (diagonal tile only) ----
        if (it == nt - 1) {
#pragma unroll
            for (int kf = 0; kf < 4; kf++)
#pragma unroll
                for (int qi = 0; qi < 2; qi++) {
                    const int qq = q0 + qi * 16 + fr;
                    const int kb0 = (int)s0 + kf * 16 + kg * 4;
#pragma unroll
                    for (int r = 0; r < 4; r++)
                        if (kb0 + r > qq) st[kf][qi][r] = -1e30f;
                }
        }
        // ---- in-register online softmax (base-2 domain) ----
        float tm0 = st[0][0][0], tm1 = st[0][1][0];
#pragma unroll
        for (int kf = 0; kf < 4; kf++)
#pragma unroll
            for (int r = 0; r < 4; r++)
                if (kf | r) {
                    tm0 = fmaxf(tm0, st[kf][0][r]);
                    tm1 = fmaxf(tm1, st[kf][1][r]);
                }
        tm0 = fmaxf(tm0, __shfl_xor(tm0, 16)); tm0 = fmaxf(tm0, __shfl_xor(tm0, 32));
        tm1 = fmaxf(tm1, __shfl_xor(tm1, 16)); tm1 = fmaxf(tm1, __shfl_xor(tm1, 32));
        // defer-max (T13): skip accumulator rescale unless max grew by >8 (base-2)
        if (__any(fmaxf(tm0 - mr0, tm1 - mr1) > 8.0f)) {
            float mn0 = fmaxf(mr0, tm0), mn1 = fmaxf(mr1, tm1);
            float al0 = __builtin_amdgcn_exp2f(mr0 - mn0);
            float al1 = __builtin_amdgcn_exp2f(mr1 - mn1);
            mr0 = mn0; mr1 = mn1;
            lr0 *= al0; lr1 *= al1;
#pragma unroll
            for (int df = 0; df < 8; df++) { ot[df][0] *= al0; ot[df][1] *= al1; }
        }
        float rs0 = 0.0f, rs1 = 0.0f;
#pragma unroll
        for (int kf = 0; kf < 4; kf++)
#pragma unroll
            for (int r = 0; r < 4; r++) {
                st[kf][0][r] = __builtin_amdgcn_exp2f(st[kf][0][r] - mr0); rs0 += st[kf][0][r];
                st[kf][1][r] = __builtin_amdgcn_exp2f(st[kf][1][r] - mr1); rs1 += st[kf][1][r];
            }
        rs0 += __shfl_xor(rs0, 16); rs0 += __shfl_xor(rs0, 32);
        rs1 += __shfl_xor(rs1, 16); rs1 += __shfl_xor(rs1, 32);
        lr0 += rs0; lr1 += rs1;
        // ---- stage P^T in LDS: lane (fr,kg) owns k = kf*16 + kg*4 + r for q-col fr ----
#pragma unroll
        for (int qi = 0; qi < 2; qi++)
#pragma unroll
            for (int kf = 0; kf < 4; kf++) {
                uint2v w;
                w[0] = cvtpk(st[kf][qi][0], st[kf][qi][1]);
                w[1] = cvtpk(st[kf][qi][2], st[kf][qi][3]);
                *(uint2v*)&pT[qi][fr][kf * 16 + kg * 4] = w;
            }
        __syncthreads();
        bf16x8 bq[2][2];
        bq[0][0] = *(const bf16x8*)&pT[0][fr][kg * 8];
        bq[0][1] = *(const bf16x8*)&pT[0][fr][32 + kg * 8];
        bq[1][0] = *(const bf16x8*)&pT[1][fr][kg * 8];
        bq[1][1] = *(const bf16x8*)&pT[1][fr][32 + kg * 8];
        // ---- O^T += V^T * P over two ks-slices ----
#pragma unroll
        for (int ks = 0; ks < 2; ks++) {
            bf16x8 va[8];
#pragma unroll
            for (int df = 0; df < 8; df++)
                va[df] = *(const bf16x8*)&vt[vbase + (long)(df * 16 + fr) * Tt + s0 + ks * 32 + kg * 8];
#pragma unroll
            for (int df = 0; df < 8; df++) {
                ot[df][0] = __builtin_amdgcn_mfma_f32_16x16x32_bf16(va[df], bq[0][ks], ot[df][0], 0, 0, 0);
                ot[df][1] = __builtin_amdgcn_mfma_f32_16x16x32_bf16(va[df], bq[1][ks], ot[df][1], 0, 0, 0);
            }
        }
    }
    // ---- store: lane holds 4 consecutive d (row) for q (col) = qi*16+fr ----
    const float il0 = 1.0f / lr0, il1 = 1.0f / lr1;
#pragma unroll
    for (int df = 0; df < 8; df++) {
        uint2v w0, w1;
        w0[0] = cvtpk(ot[df][0][0] * il0, ot[df][0][1] * il0);
        w0[1] = cvtpk(ot[df][0][2] * il0, ot[df][0][3] * il0);
        w1[0] = cvtpk(ot[df][1][0] * il1, ot[df][1][1] * il1);
        w1[1] = cvtpk(ot[df][1][2] * il1, ot[df][1][3] * il1);
        *(uint2v*)&o[qbase + (long)(fr) * HD + df * 16 + kg * 4] = w0;
        *(uint2v*)&o[qbase + (long)(16 + fr) * HD + df * 16 + kg * 4] = w1;
    }
}

extern "C" void kernel_launch(void* const* d_in, const int* in_sizes, int n_in,
                              void* d_out, int out_size, void* d_ws, size_t ws_size,
                              hipStream_t stream) {
    (void)in_sizes; (void)n_in; (void)out_size; (void)ws_size;
    const float* x = (const float*)d_in[0];
    const float* Wq = (const float*)d_in[1];
    const float* Wk = (const float*)d_in[2];
    const float* Wv = (const float*)d_in[3];
    const float* Wo = (const float*)d_in[4];

    char* ws = (char*)d_ws;
    u16* xb   = (u16*)(ws + 0);            // 33.5MB  (b,t,c) bf16; later reused as attn output (b,t,h,d)
    u16* kbuf = (u16*)(ws + 33554432);     // 8.4MB   (b,t,kv,d)
    u16* vbuf = (u16*)(ws + 41943040);     // 8.4MB   (b,t,kv,d)
    u16* vtb  = (u16*)(ws + 50331648);     // 8.4MB   (b,kv,d,t)
    u16* wqt  = (u16*)(ws + 58720256);     // 8.4MB
    u16* wkt  = (u16*)(ws + 67108864);     // 2.1MB
    u16* wvt  = (u16*)(ws + 69206016);     // 2.1MB
    u16* wot  = (u16*)(ws + 71303168);     // 8.4MB
    float* cosb = (float*)(ws + 79691776); // 0.5MB
    float* sinb = (float*)(ws + 80216064); // 0.5MB
    u16* qbuf = (u16*)d_out;               // q (b,t,h,d) bf16 lives in d_out until final GEMM

    dim3 tb(32, 8);
    cast_k<<<16384, 256, 0, stream>>>(x, xb, 4194304);
    twt_k<<<dim3(64, 64), tb, 0, stream>>>(Wq, wqt, 2048, 2048);
    twt_k<<<dim3(16, 64), tb, 0, stream>>>(Wk, wkt, 2048, 512);
    twt_k<<<dim3(16, 64), tb, 0, stream>>>(Wv, wvt, 2048, 512);
    twt_k<<<dim3(64, 64), tb, 0, stream>>>(Wo, wot, 2048, 2048);
    tables_k<<<512, 256, 0, stream>>>(cosb, sinb);

    gemm_k<0><<<dim3(64, 16), 256, 0, stream>>>(xb, wqt, qbuf, 8192, 2048, 2048);
    gemm_k<0><<<dim3(64, 4), 256, 0, stream>>>(xb, wkt, kbuf, 8192, 512, 2048);
    gemm_k<0><<<dim3(64, 4), 256, 0, stream>>>(xb, wvt, vbuf, 8192, 512, 2048);

    // q scale = (1/sqrt(128)) * log2(e) -> softmax runs in exp2 domain
    rope_k<<<32768, 256, 0, stream>>>(qbuf, cosb, sinb, 16, 0.1275174316f, 8388608);
    rope_k<<<8192, 256, 0, stream>>>(kbuf, cosb, sinb, 4, 1.0f, 2097152);
    tv_k<<<dim3(4, 64, 16), tb, 0, stream>>>(vbuf, vtb);

    attn_k<<<dim3(64, 16, 4), 64, 0, stream>>>(qbuf, kbuf, vtb, xb);

    gemm_k<1><<<dim3(64, 16), 256, 0, stream>>>(xb, wot, d_out, 8192, 2048, 2048);
}

// Round 7
// 555.215 us; speedup vs baseline: 1.3776x; 1.3574x over previous
//
#include <hip/hip_runtime.h>
#include <cstdint>

#define DEV __device__ __forceinline__

typedef __attribute__((ext_vector_type(4))) float f32x4;
typedef __attribute__((ext_vector_type(4))) float float4v;
typedef __attribute__((ext_vector_type(8))) short bf16x8;
typedef __attribute__((ext_vector_type(4))) unsigned short ushort4v;
typedef __attribute__((ext_vector_type(2))) unsigned int uint2v;
typedef unsigned short u16;

static constexpr int Bb = 4, Tt = 2048, Hh = 16, KVh = 4, Dd = 128;

DEV u16 f2bf(float x) {
    union { float f; unsigned u; } v; v.f = x;
    unsigned r = v.u + 0x7FFF + ((v.u >> 16) & 1);
    return (u16)(r >> 16);
}
DEV float bf2f(u16 b) {
    union { unsigned u; float f; } v; v.u = ((unsigned)b) << 16;
    return v.f;
}
DEV unsigned cvtpk(float lo, float hi) {
    unsigned d;
    asm("v_cvt_pk_bf16_f32 %0, %1, %2" : "=v"(d) : "v"(lo), "v"(hi));
    return d;
}

typedef const void __attribute__((address_space(1)))* gas1;
typedef void __attribute__((address_space(3)))* las3;
DEV void gload16(const void* g, void* l) {
    __builtin_amdgcn_global_load_lds((gas1)g, (las3)l, 16, 0, 0);
}

// ---------------- cast x -> bf16 ----------------
__global__ __launch_bounds__(256) void cast_k(const float* __restrict__ x, u16* __restrict__ xb, long n4) {
    long id = (long)blockIdx.x * 256 + threadIdx.x;
    if (id >= n4) return;
    float4v v = *(const float4v*)&x[id * 4];
    ushort4v o;
    o[0] = f2bf(v[0]); o[1] = f2bf(v[1]); o[2] = f2bf(v[2]); o[3] = f2bf(v[3]);
    *(ushort4v*)&xb[id * 4] = o;
}

// ---------------- transpose+cast weight: W (K x N) f32 -> Wt (N x K) bf16 ----------------
__global__ __launch_bounds__(256) void twt_k(const float* __restrict__ W, u16* __restrict__ Wt, int K, int N) {
    __shared__ float tile[32][33];
    int tx = threadIdx.x, ty = threadIdx.y;
    long n0 = (long)blockIdx.x * 32, k0 = (long)blockIdx.y * 32;
#pragma unroll
    for (int j = 0; j < 4; j++)
        tile[ty + j * 8][tx] = W[(k0 + ty + j * 8) * (long)N + n0 + tx];
    __syncthreads();
#pragma unroll
    for (int j = 0; j < 4; j++)
        Wt[(n0 + ty + j * 8) * (long)K + k0 + tx] = f2bf(tile[tx][ty + j * 8]);
}

// ---------------- transpose v (b,t,kv,d) -> vt (b,kv,d,t) ----------------
__global__ __launch_bounds__(256) void tv_k(const u16* __restrict__ v, u16* __restrict__ vt) {
    __shared__ u16 tile[32][33];
    int tx = threadIdx.x, ty = threadIdx.y;
    int d0 = blockIdx.x * 32;
    int t0 = blockIdx.y * 32;
    int bk = blockIdx.z;
    int b = bk >> 2, kv = bk & 3;
#pragma unroll
    for (int j = 0; j < 4; j++)
        tile[ty + j * 8][tx] = v[((long)(b * Tt + t0 + ty + j * 8) * KVh + kv) * Dd + d0 + tx];
    __syncthreads();
#pragma unroll
    for (int j = 0; j < 4; j++)
        vt[((long)(b * KVh + kv) * Dd + d0 + ty + j * 8) * Tt + t0 + tx] = tile[tx][ty + j * 8];
}

// ---------------- rope tables: [t][i], i<64 ----------------
__global__ __launch_bounds__(256) void tables_k(float* __restrict__ cosb, float* __restrict__ sinb) {
    int id = blockIdx.x * 256 + threadIdx.x; // < 2048*64
    int t = id >> 6, i = id & 63;
    float inv = powf(10000.0f, -(float)i * (1.0f / 64.0f));
    float f = (float)t * inv;
    cosb[id] = cosf(f);
    sinb[id] = sinf(f);
}

// ---------------- rope in-place on (b,t,nh,128); scale folded for q ----------------
__global__ __launch_bounds__(256) void rope_k(u16* __restrict__ p, const float* __restrict__ cosb,
                                              const float* __restrict__ sinb, int nh, float scale, int total) {
    int id = blockIdx.x * 256 + threadIdx.x;
    if (id >= total) return;
    int i = id & 63;
    int bth = id >> 6;
    int t = (bth / nh) % Tt;
    u16* ptr = p + (long)bth * Dd;
    float x1 = bf2f(ptr[i]), x2 = bf2f(ptr[i + 64]);
    float c = cosb[t * 64 + i], s = sinb[t * 64 + i];
    ptr[i] = f2bf((x1 * c - x2 * s) * scale);
    ptr[i + 64] = f2bf((x2 * c + x1 * s) * scale);
}

// ---------------- GEMM: A (M x K) bf16 row-major, Bt (N x K) bf16 row-major -> C (M x N) ----------------
template <int F32OUT>
__global__ __launch_bounds__(256) void gemm_k(const u16* __restrict__ A, const u16* __restrict__ Bt,
                                              void* __restrict__ Cout, int M, int N, int K) {
    __shared__ u16 aLds[128 * 32];
    __shared__ u16 bLds[128 * 32];
    const int tid = threadIdx.x;
    const int lane = tid & 63;
    const int wid = __builtin_amdgcn_readfirstlane(tid >> 6);
    const long m0 = (long)blockIdx.x * 128;
    const long n0 = (long)blockIdx.y * 128;
    const int wr = wid >> 1, wc = wid & 1;
    const int r0 = wid * 32;
    const int lrow = lane >> 2;
    const int lkb = (lane & 3) * 8;
    const u16* gA = A + (m0 + r0 + lrow) * (long)K + lkb;
    const u16* gB = Bt + (n0 + r0 + lrow) * (long)K + lkb;
    u16* lA = &aLds[r0 * 32];
    u16* lB = &bLds[r0 * 32];
    f32x4 acc[4][4] = {};
    const int fr = lane & 15, fk = (lane >> 4) * 8;
    for (int kt = 0; kt < K; kt += 32) {
        gload16(gA + kt, lA);
        gload16(gA + kt + 16 * (long)K, lA + 16 * 32);
        gload16(gB + kt, lB);
        gload16(gB + kt + 16 * (long)K, lB + 16 * 32);
        __syncthreads();
        bf16x8 af[4], bfr[4];
#pragma unroll
        for (int i = 0; i < 4; i++) {
            af[i] = *(const bf16x8*)&aLds[(wr * 64 + i * 16 + fr) * 32 + fk];
            bfr[i] = *(const bf16x8*)&bLds[(wc * 64 + i * 16 + fr) * 32 + fk];
        }
#pragma unroll
        for (int i = 0; i < 4; i++)
#pragma unroll
            for (int j = 0; j < 4; j++)
                acc[i][j] = __builtin_amdgcn_mfma_f32_16x16x32_bf16(af[i], bfr[j], acc[i][j], 0, 0, 0);
        __syncthreads();
    }
    const int orow = (lane >> 4) * 4, ocol = lane & 15;
#pragma unroll
    for (int i = 0; i < 4; i++)
#pragma unroll
        for (int j = 0; j < 4; j++) {
            long r = m0 + wr * 64 + i * 16 + orow;
            long c = n0 + wc * 64 + j * 16 + ocol;
#pragma unroll
            for (int t = 0; t < 4; t++) {
                if (F32OUT)
                    ((float*)Cout)[(r + t) * N + c] = acc[i][j][t];
                else
                    ((u16*)Cout)[(r + t) * N + c] = f2bf(acc[i][j][t]);
            }
        }
}

// ---------------- flash attention v6: 4 waves/block (QBLK=128, 32/wave), KVBLK=32 ----------------
// K/V staged in double-buffered LDS via global_load_lds (m173: linear dest, inverse-XOR source,
// XOR on read). Per-wave math identical to the verified v5: swapped QK^T (S^T = mfma(K,Q)),
// in-register softmax (exp2 domain, defer-max T13), P^T through per-wave LDS, O^T = mfma(V^T,P).
// K tile: kl[32][128] u16, slot swizzle c16 ^= row&7.
// V tile: vl packs 4 d-rows (32 k each) per 256B LDS row: row'=r>>2, c16u=(r&3)*4+kcol, c16=c16u^(row'&7).
__global__ __launch_bounds__(256, 3) void attn_k(const u16* __restrict__ q, const u16* __restrict__ k,
                                                 const u16* __restrict__ vt, u16* __restrict__ o) {
    __shared__ u16 kl[2][4096];
    __shared__ u16 vl[2][4096];
    __shared__ u16 pT[4][2][16][72];
    const int tid = threadIdx.x;
    const int lane = tid & 63;
    const int w = tid >> 6;
    const int qb = 15 - blockIdx.x;   // heavy causal blocks dispatch first
    const int h = blockIdx.y, b = blockIdx.z;
    const int kv = h >> 2;
    const int q0w = qb * 128 + w * 32;
    const int fr = lane & 15, kg = lane >> 4;
    const long HD = (long)Hh * Dd;
    const long KD = (long)KVh * Dd;
    const long qbase = ((long)(b * Tt + q0w)) * HD + (long)h * Dd;
    const long kbase = ((long)(b * Tt)) * KD + (long)kv * Dd;
    const long vbase = ((long)(b * KVh + kv)) * (long)Dd * Tt;

    bf16x8 qa[2][4];
#pragma unroll
    for (int qi = 0; qi < 2; qi++)
#pragma unroll
        for (int kc = 0; kc < 4; kc++)
            qa[qi][kc] = *(const bf16x8*)&q[qbase + (long)(qi * 16 + fr) * HD + kc * 32 + kg * 8];

    f32x4 ot[8][2] = {};              // O^T accumulator: [df][qi]
    float mr0 = -1e30f, mr1 = -1e30f, lr0 = 0.0f, lr1 = 0.0f;

    const int dtile = qb * 4 + w;     // this wave's diagonal tile index
    const int nt = qb * 4 + 4;        // tiles staged by the block

    auto stage = [&](int bb, int it) {
        const int s0 = it * 32;
        const int lh = lane >> 4;     // 0..3
#pragma unroll
        for (int j = 0; j < 2; j++) { // K: 8 chunks of 1KB, chunk c = j*4+w
            int c = j * 4 + w;
            int row = c * 4 + lh;
            int c16 = (lane & 15) ^ (row & 7);
            gload16(k + kbase + (long)(s0 + row) * KD + c16 * 8, &kl[bb][c * 512]);
        }
#pragma unroll
        for (int j = 0; j < 2; j++) { // V: 8 chunks of 1KB
            int c = j * 4 + w;
            int rowp = c * 4 + lh;
            int c16u = (lane & 15) ^ (rowp & 7);
            int r = rowp * 4 + (c16u >> 2);
            gload16(vt + vbase + (long)r * Tt + s0 + (c16u & 3) * 8, &vl[bb][c * 512]);
        }
    };

    stage(0, 0);
    __syncthreads();
    int cur = 0;
    for (int it = 0; it < nt; ++it) {
        if (it + 1 < nt) stage(cur ^ 1, it + 1);
        if (it <= dtile) {
            const int s0 = it * 32;
            // ---- S^T = K * Q^T from swizzled kl ----
            f32x4 st[2][2] = {};      // [kf][qi]
            __builtin_amdgcn_s_setprio(1);
#pragma unroll
            for (int kf = 0; kf < 2; kf++) {
                const int rr = kf * 16 + fr;
                bf16x8 ka[4];
#pragma unroll
                for (int kc = 0; kc < 4; kc++)
                    ka[kc] = *(const bf16x8*)&kl[cur][rr * 128 + (((kc * 4 + kg) ^ (rr & 7)) * 8)];
#pragma unroll
                for (int kc = 0; kc < 4; kc++) {
                    st[kf][0] = __builtin_amdgcn_mfma_f32_16x16x32_bf16(ka[kc], qa[0][kc], st[kf][0], 0, 0, 0);
                    st[kf][1] = __builtin_amdgcn_mfma_f32_16x16x32_bf16(ka[kc], qa[1][kc], st[kf][1], 0, 0, 0);
                }
            }
            __builtin_amdgcn_s_setprio(0);
            // ---- causal mask (diagonal tile only) ----
            if (it == dtile) {
#pragma unroll
                for (int kf = 0; kf < 2; kf++)
#pragma unroll
                    for (int qi = 0; qi < 2; qi++) {
                        const int qq = q0w + qi * 16 + fr;
                        const int kb0 = s0 + kf * 16 + kg * 4;
#pragma unroll
                        for (int r = 0; r < 4; r++)
                            if (kb0 + r > qq) st[kf][qi][r] = -1e30f;
                    }
            }
            // ---- in-register online softmax (base-2 domain) ----
            float tm0 = st[0][0][0], tm1 = st[0][1][0];
#pragma unroll
            for (int kf = 0; kf < 2; kf++)
#pragma unroll
                for (int r = 0; r < 4; r++)
                    if (kf | r) {
                        tm0 = fmaxf(tm0, st[kf][0][r]);
                        tm1 = fmaxf(tm1, st[kf][1][r]);
                    }
            tm0 = fmaxf(tm0, __shfl_xor(tm0, 16)); tm0 = fmaxf(tm0, __shfl_xor(tm0, 32));
            tm1 = fmaxf(tm1, __shfl_xor(tm1, 16)); tm1 = fmaxf(tm1, __shfl_xor(tm1, 32));
            if (__any(fmaxf(tm0 - mr0, tm1 - mr1) > 8.0f)) {
                float mn0 = fmaxf(mr0, tm0), mn1 = fmaxf(mr1, tm1);
                float al0 = __builtin_amdgcn_exp2f(mr0 - mn0);
                float al1 = __builtin_amdgcn_exp2f(mr1 - mn1);
                mr0 = mn0; mr1 = mn1;
                lr0 *= al0; lr1 *= al1;
#pragma unroll
                for (int df = 0; df < 8; df++) { ot[df][0] *= al0; ot[df][1] *= al1; }
            }
            float rs0 = 0.0f, rs1 = 0.0f;
#pragma unroll
            for (int kf = 0; kf < 2; kf++)
#pragma unroll
                for (int r = 0; r < 4; r++) {
                    st[kf][0][r] = __builtin_amdgcn_exp2f(st[kf][0][r] - mr0); rs0 += st[kf][0][r];
                    st[kf][1][r] = __builtin_amdgcn_exp2f(st[kf][1][r] - mr1); rs1 += st[kf][1][r];
                }
            rs0 += __shfl_xor(rs0, 16); rs0 += __shfl_xor(rs0, 32);
            rs1 += __shfl_xor(rs1, 16); rs1 += __shfl_xor(rs1, 32);
            lr0 += rs0; lr1 += rs1;
            // ---- stage P^T (per-wave): lane (fr,kg) owns k = kf*16 + kg*4 + r for q-col fr ----
#pragma unroll
            for (int qi = 0; qi < 2; qi++)
#pragma unroll
                for (int kf = 0; kf < 2; kf++) {
                    uint2v pw;
                    pw[0] = cvtpk(st[kf][qi][0], st[kf][qi][1]);
                    pw[1] = cvtpk(st[kf][qi][2], st[kf][qi][3]);
                    *(uint2v*)&pT[w][qi][fr][kf * 16 + kg * 4] = pw;
                }
            bf16x8 bq0 = *(const bf16x8*)&pT[w][0][fr][kg * 8];
            bf16x8 bq1 = *(const bf16x8*)&pT[w][1][fr][kg * 8];
            // ---- O^T += V^T * P from swizzled vl ----
            __builtin_amdgcn_s_setprio(1);
#pragma unroll
            for (int df = 0; df < 8; df++) {
                const int r = df * 16 + fr;
                const int rowp = r >> 2;
                const int c16 = (((r & 3) * 4 + kg) ^ (rowp & 7));
                bf16x8 va = *(const bf16x8*)&vl[cur][rowp * 128 + c16 * 8];
                ot[df][0] = __builtin_amdgcn_mfma_f32_16x16x32_bf16(va, bq0, ot[df][0], 0, 0, 0);
                ot[df][1] = __builtin_amdgcn_mfma_f32_16x16x32_bf16(va, bq1, ot[df][1], 0, 0, 0);
            }
            __builtin_amdgcn_s_setprio(0);
        }
        __syncthreads();
        cur ^= 1;
    }
    // ---- store: lane holds 4 consecutive d (row) for q (col) = qi*16+fr ----
    const float il0 = 1.0f / lr0, il1 = 1.0f / lr1;
#pragma unroll
    for (int df = 0; df < 8; df++) {
        uint2v w0, w1;
        w0[0] = cvtpk(ot[df][0][0] * il0, ot[df][0][1] * il0);
        w0[1] = cvtpk(ot[df][0][2] * il0, ot[df][0][3] * il0);
        w1[0] = cvtpk(ot[df][1][0] * il1, ot[df][1][1] * il1);
        w1[1] = cvtpk(ot[df][1][2] * il1, ot[df][1][3] * il1);
        *(uint2v*)&o[qbase + (long)(fr) * HD + df * 16 + kg * 4] = w0;
        *(uint2v*)&o[qbase + (long)(16 + fr) * HD + df * 16 + kg * 4] = w1;
    }
}

extern "C" void kernel_launch(void* const* d_in, const int* in_sizes, int n_in,
                              void* d_out, int out_size, void* d_ws, size_t ws_size,
                              hipStream_t stream) {
    (void)in_sizes; (void)n_in; (void)out_size; (void)ws_size;
    const float* x = (const float*)d_in[0];
    const float* Wq = (const float*)d_in[1];
    const float* Wk = (const float*)d_in[2];
    const float* Wv = (const float*)d_in[3];
    const float* Wo = (const float*)d_in[4];

    char* ws = (char*)d_ws;
    u16* xb   = (u16*)(ws + 0);            // 33.5MB  (b,t,c) bf16; later reused as attn output (b,t,h,d)
    u16* kbuf = (u16*)(ws + 33554432);     // 8.4MB   (b,t,kv,d)
    u16* vbuf = (u16*)(ws + 41943040);     // 8.4MB   (b,t,kv,d)
    u16* vtb  = (u16*)(ws + 50331648);     // 8.4MB   (b,kv,d,t)
    u16* wqt  = (u16*)(ws + 58720256);     // 8.4MB
    u16* wkt  = (u16*)(ws + 67108864);     // 2.1MB
    u16* wvt  = (u16*)(ws + 69206016);     // 2.1MB
    u16* wot  = (u16*)(ws + 71303168);     // 8.4MB
    float* cosb = (float*)(ws + 79691776); // 0.5MB
    float* sinb = (float*)(ws + 80216064); // 0.5MB
    u16* qbuf = (u16*)d_out;               // q (b,t,h,d) bf16 lives in d_out until final GEMM

    dim3 tb(32, 8);
    cast_k<<<16384, 256, 0, stream>>>(x, xb, 4194304);
    twt_k<<<dim3(64, 64), tb, 0, stream>>>(Wq, wqt, 2048, 2048);
    twt_k<<<dim3(16, 64), tb, 0, stream>>>(Wk, wkt, 2048, 512);
    twt_k<<<dim3(16, 64), tb, 0, stream>>>(Wv, wvt, 2048, 512);
    twt_k<<<dim3(64, 64), tb, 0, stream>>>(Wo, wot, 2048, 2048);
    tables_k<<<512, 256, 0, stream>>>(cosb, sinb);

    gemm_k<0><<<dim3(64, 16), 256, 0, stream>>>(xb, wqt, qbuf, 8192, 2048, 2048);
    gemm_k<0><<<dim3(64, 4), 256, 0, stream>>>(xb, wkt, kbuf, 8192, 512, 2048);
    gemm_k<0><<<dim3(64, 4), 256, 0, stream>>>(xb, wvt, vbuf, 8192, 512, 2048);

    // q scale = (1/sqrt(128)) * log2(e) -> softmax runs in exp2 domain
    rope_k<<<32768, 256, 0, stream>>>(qbuf, cosb, sinb, 16, 0.1275174316f, 8388608);
    rope_k<<<8192, 256, 0, stream>>>(kbuf, cosb, sinb, 4, 1.0f, 2097152);
    tv_k<<<dim3(4, 64, 16), tb, 0, stream>>>(vbuf, vtb);

    attn_k<<<dim3(16, 16, 4), 256, 0, stream>>>(qbuf, kbuf, vtb, xb);

    gemm_k<1><<<dim3(64, 16), 256, 0, stream>>>(xb, wot, d_out, 8192, 2048, 2048);
}

// Round 8
// 538.352 us; speedup vs baseline: 1.4207x; 1.0313x over previous
//
#include <hip/hip_runtime.h>
#include <cstdint>

#define DEV __device__ __forceinline__

typedef __attribute__((ext_vector_type(4))) float f32x4;
typedef __attribute__((ext_vector_type(4))) float float4v;
typedef __attribute__((ext_vector_type(8))) short bf16x8;
typedef __attribute__((ext_vector_type(4))) unsigned short ushort4v;
typedef __attribute__((ext_vector_type(2))) unsigned int uint2v;
typedef unsigned short u16;

static constexpr int Bb = 4, Tt = 2048, Hh = 16, KVh = 4, Dd = 128;

DEV u16 f2bf(float x) {
    union { float f; unsigned u; } v; v.f = x;
    unsigned r = v.u + 0x7FFF + ((v.u >> 16) & 1);
    return (u16)(r >> 16);
}
DEV float bf2f(u16 b) {
    union { unsigned u; float f; } v; v.u = ((unsigned)b) << 16;
    return v.f;
}
DEV unsigned cvtpk(float lo, float hi) {
    unsigned d;
    asm("v_cvt_pk_bf16_f32 %0, %1, %2" : "=v"(d) : "v"(lo), "v"(hi));
    return d;
}

typedef const void __attribute__((address_space(1)))* gas1;
typedef void __attribute__((address_space(3)))* las3;
DEV void gload16(const void* g, void* l) {
    __builtin_amdgcn_global_load_lds((gas1)g, (las3)l, 16, 0, 0);
}

// ---------------- cast x -> bf16 ----------------
__global__ __launch_bounds__(256) void cast_k(const float* __restrict__ x, u16* __restrict__ xb, long n4) {
    long id = (long)blockIdx.x * 256 + threadIdx.x;
    if (id >= n4) return;
    float4v v = *(const float4v*)&x[id * 4];
    ushort4v o;
    o[0] = f2bf(v[0]); o[1] = f2bf(v[1]); o[2] = f2bf(v[2]); o[3] = f2bf(v[3]);
    *(ushort4v*)&xb[id * 4] = o;
}

// ---------------- transpose+cast weight: W (K x N) f32 -> Wt (N x K) bf16 ----------------
__global__ __launch_bounds__(256) void twt_k(const float* __restrict__ W, u16* __restrict__ Wt, int K, int N) {
    __shared__ float tile[32][33];
    int tx = threadIdx.x, ty = threadIdx.y;
    long n0 = (long)blockIdx.x * 32, k0 = (long)blockIdx.y * 32;
#pragma unroll
    for (int j = 0; j < 4; j++)
        tile[ty + j * 8][tx] = W[(k0 + ty + j * 8) * (long)N + n0 + tx];
    __syncthreads();
#pragma unroll
    for (int j = 0; j < 4; j++)
        Wt[(n0 + ty + j * 8) * (long)K + k0 + tx] = f2bf(tile[tx][ty + j * 8]);
}

// ---------------- transpose v (b,t,kv,d) -> vt (b,kv,d,t) ----------------
__global__ __launch_bounds__(256) void tv_k(const u16* __restrict__ v, u16* __restrict__ vt) {
    __shared__ u16 tile[32][33];
    int tx = threadIdx.x, ty = threadIdx.y;
    int d0 = blockIdx.x * 32;
    int t0 = blockIdx.y * 32;
    int bk = blockIdx.z;
    int b = bk >> 2, kv = bk & 3;
#pragma unroll
    for (int j = 0; j < 4; j++)
        tile[ty + j * 8][tx] = v[((long)(b * Tt + t0 + ty + j * 8) * KVh + kv) * Dd + d0 + tx];
    __syncthreads();
#pragma unroll
    for (int j = 0; j < 4; j++)
        vt[((long)(b * KVh + kv) * Dd + d0 + ty + j * 8) * Tt + t0 + tx] = tile[tx][ty + j * 8];
}

// ---------------- rope tables: [t][i], i<64 ----------------
__global__ __launch_bounds__(256) void tables_k(float* __restrict__ cosb, float* __restrict__ sinb) {
    int id = blockIdx.x * 256 + threadIdx.x; // < 2048*64
    int t = id >> 6, i = id & 63;
    float inv = powf(10000.0f, -(float)i * (1.0f / 64.0f));
    float f = (float)t * inv;
    cosb[id] = cosf(f);
    sinb[id] = sinf(f);
}

// ---------------- rope in-place on (b,t,nh,128); scale folded for q ----------------
__global__ __launch_bounds__(256) void rope_k(u16* __restrict__ p, const float* __restrict__ cosb,
                                              const float* __restrict__ sinb, int nh, float scale, int total) {
    int id = blockIdx.x * 256 + threadIdx.x;
    if (id >= total) return;
    int i = id & 63;
    int bth = id >> 6;
    int t = (bth / nh) % Tt;
    u16* ptr = p + (long)bth * Dd;
    float x1 = bf2f(ptr[i]), x2 = bf2f(ptr[i + 64]);
    float c = cosb[t * 64 + i], s = sinb[t * 64 + i];
    ptr[i] = f2bf((x1 * c - x2 * s) * scale);
    ptr[i + 64] = f2bf((x2 * c + x1 * s) * scale);
}

// ---------------- GEMM: A (M x K) bf16 row-major, Bt (N x K) bf16 row-major -> C (M x N) ----------------
template <int F32OUT>
__global__ __launch_bounds__(256) void gemm_k(const u16* __restrict__ A, const u16* __restrict__ Bt,
                                              void* __restrict__ Cout, int M, int N, int K) {
    __shared__ u16 aLds[128 * 32];
    __shared__ u16 bLds[128 * 32];
    const int tid = threadIdx.x;
    const int lane = tid & 63;
    const int wid = __builtin_amdgcn_readfirstlane(tid >> 6);
    const long m0 = (long)blockIdx.x * 128;
    const long n0 = (long)blockIdx.y * 128;
    const int wr = wid >> 1, wc = wid & 1;
    const int r0 = wid * 32;
    const int lrow = lane >> 2;
    const int lkb = (lane & 3) * 8;
    const u16* gA = A + (m0 + r0 + lrow) * (long)K + lkb;
    const u16* gB = Bt + (n0 + r0 + lrow) * (long)K + lkb;
    u16* lA = &aLds[r0 * 32];
    u16* lB = &bLds[r0 * 32];
    f32x4 acc[4][4] = {};
    const int fr = lane & 15, fk = (lane >> 4) * 8;
    for (int kt = 0; kt < K; kt += 32) {
        gload16(gA + kt, lA);
        gload16(gA + kt + 16 * (long)K, lA + 16 * 32);
        gload16(gB + kt, lB);
        gload16(gB + kt + 16 * (long)K, lB + 16 * 32);
        __syncthreads();
        bf16x8 af[4], bfr[4];
#pragma unroll
        for (int i = 0; i < 4; i++) {
            af[i] = *(const bf16x8*)&aLds[(wr * 64 + i * 16 + fr) * 32 + fk];
            bfr[i] = *(const bf16x8*)&bLds[(wc * 64 + i * 16 + fr) * 32 + fk];
        }
#pragma unroll
        for (int i = 0; i < 4; i++)
#pragma unroll
            for (int j = 0; j < 4; j++)
                acc[i][j] = __builtin_amdgcn_mfma_f32_16x16x32_bf16(af[i], bfr[j], acc[i][j], 0, 0, 0);
        __syncthreads();
    }
    const int orow = (lane >> 4) * 4, ocol = lane & 15;
#pragma unroll
    for (int i = 0; i < 4; i++)
#pragma unroll
        for (int j = 0; j < 4; j++) {
            long r = m0 + wr * 64 + i * 16 + orow;
            long c = n0 + wc * 64 + j * 16 + ocol;
#pragma unroll
            for (int t = 0; t < 4; t++) {
                if (F32OUT)
                    ((float*)Cout)[(r + t) * N + c] = acc[i][j][t];
                else
                    ((u16*)Cout)[(r + t) * N + c] = f2bf(acc[i][j][t]);
            }
        }
}

// ---------------- flash attention v7: block = (qb, kv, b), wave = head-in-group ----------------
// 4 heads of one kv group share double-buffered K/V LDS staging (4x less traffic than v6);
// all waves have the SAME q-range [qb*32, qb*32+32) -> identical diagonal tile, perfect balance.
// Per-wave math verbatim from verified v5/v6: swapped QK^T (S^T = mfma(K,Q)), in-register
// softmax (exp2 domain, defer-max T13), P^T via per-wave LDS (stride 36 u16 = 18 dwords,
// 9*fr bijective mod 16 -> conflict-free), O^T = mfma(V^T, P), sequential qi reuse of pT.
__global__ __launch_bounds__(256, 3) void attn_k(const u16* __restrict__ q, const u16* __restrict__ k,
                                                 const u16* __restrict__ vt, u16* __restrict__ o) {
    __shared__ u16 kl[2][4096];
    __shared__ u16 vl[2][4096];
    __shared__ u16 pT[4][16][36];
    const int tid = threadIdx.x;
    const int lane = tid & 63;
    const int w = tid >> 6;
    const int qb = 63 - blockIdx.x;   // heavy causal blocks dispatch first
    const int kv = blockIdx.y, b = blockIdx.z;
    const int h = kv * 4 + w;
    const int q0 = qb * 32;
    const int fr = lane & 15, kg = lane >> 4;
    const long HD = (long)Hh * Dd;
    const long KD = (long)KVh * Dd;
    const long qbase = ((long)(b * Tt + q0)) * HD + (long)h * Dd;
    const long kbase = ((long)(b * Tt)) * KD + (long)kv * Dd;
    const long vbase = ((long)(b * KVh + kv)) * (long)Dd * Tt;

    bf16x8 qa[2][4];
#pragma unroll
    for (int qi = 0; qi < 2; qi++)
#pragma unroll
        for (int kc = 0; kc < 4; kc++)
            qa[qi][kc] = *(const bf16x8*)&q[qbase + (long)(qi * 16 + fr) * HD + kc * 32 + kg * 8];

    f32x4 ot[8][2] = {};              // O^T accumulator: [df][qi]
    float mr0 = -1e30f, mr1 = -1e30f, lr0 = 0.0f, lr1 = 0.0f;

    const int nt = qb + 1;            // k-tiles of 32 covering [0, q0+32)

    auto stage = [&](int bb, int it) {
        const int s0 = it * 32;
        const int lh = lane >> 4;     // 0..3
#pragma unroll
        for (int j = 0; j < 2; j++) { // K: 8 chunks of 1KB, chunk c = j*4+w
            int c = j * 4 + w;
            int row = c * 4 + lh;
            int c16 = (lane & 15) ^ (row & 7);
            gload16(k + kbase + (long)(s0 + row) * KD + c16 * 8, &kl[bb][c * 512]);
        }
#pragma unroll
        for (int j = 0; j < 2; j++) { // V: 8 chunks of 1KB
            int c = j * 4 + w;
            int rowp = c * 4 + lh;
            int c16u = (lane & 15) ^ (rowp & 7);
            int r = rowp * 4 + (c16u >> 2);
            gload16(vt + vbase + (long)r * Tt + s0 + (c16u & 3) * 8, &vl[bb][c * 512]);
        }
    };

    stage(0, 0);
    __syncthreads();
    int cur = 0;
    for (int it = 0; it < nt; ++it) {
        if (it + 1 < nt) stage(cur ^ 1, it + 1);
        const int s0 = it * 32;
        // ---- S^T = K * Q^T from swizzled kl ----
        f32x4 st[2][2] = {};          // [kf][qi]
        __builtin_amdgcn_s_setprio(1);
#pragma unroll
        for (int kf = 0; kf < 2; kf++) {
            const int rr = kf * 16 + fr;
            bf16x8 ka[4];
#pragma unroll
            for (int kc = 0; kc < 4; kc++)
                ka[kc] = *(const bf16x8*)&kl[cur][rr * 128 + (((kc * 4 + kg) ^ (rr & 7)) * 8)];
#pragma unroll
            for (int kc = 0; kc < 4; kc++) {
                st[kf][0] = __builtin_amdgcn_mfma_f32_16x16x32_bf16(ka[kc], qa[0][kc], st[kf][0], 0, 0, 0);
                st[kf][1] = __builtin_amdgcn_mfma_f32_16x16x32_bf16(ka[kc], qa[1][kc], st[kf][1], 0, 0, 0);
            }
        }
        __builtin_amdgcn_s_setprio(0);
        // ---- causal mask (diagonal tile only) ----
        if (it == nt - 1) {
#pragma unroll
            for (int kf = 0; kf < 2; kf++)
#pragma unroll
                for (int qi = 0; qi < 2; qi++) {
                    const int qq = q0 + qi * 16 + fr;
                    const int kb0 = s0 + kf * 16 + kg * 4;
#pragma unroll
                    for (int r = 0; r < 4; r++)
                        if (kb0 + r > qq) st[kf][qi][r] = -1e30f;
                }
        }
        // ---- in-register online softmax (base-2 domain) ----
        float tm0 = st[0][0][0], tm1 = st[0][1][0];
#pragma unroll
        for (int kf = 0; kf < 2; kf++)
#pragma unroll
            for (int r = 0; r < 4; r++)
                if (kf | r) {
                    tm0 = fmaxf(tm0, st[kf][0][r]);
                    tm1 = fmaxf(tm1, st[kf][1][r]);
                }
        tm0 = fmaxf(tm0, __shfl_xor(tm0, 16)); tm0 = fmaxf(tm0, __shfl_xor(tm0, 32));
        tm1 = fmaxf(tm1, __shfl_xor(tm1, 16)); tm1 = fmaxf(tm1, __shfl_xor(tm1, 32));
        if (__any(fmaxf(tm0 - mr0, tm1 - mr1) > 8.0f)) {
            float mn0 = fmaxf(mr0, tm0), mn1 = fmaxf(mr1, tm1);
            float al0 = __builtin_amdgcn_exp2f(mr0 - mn0);
            float al1 = __builtin_amdgcn_exp2f(mr1 - mn1);
            mr0 = mn0; mr1 = mn1;
            lr0 *= al0; lr1 *= al1;
#pragma unroll
            for (int df = 0; df < 8; df++) { ot[df][0] *= al0; ot[df][1] *= al1; }
        }
        float rs0 = 0.0f, rs1 = 0.0f;
#pragma unroll
        for (int kf = 0; kf < 2; kf++)
#pragma unroll
            for (int r = 0; r < 4; r++) {
                st[kf][0][r] = __builtin_amdgcn_exp2f(st[kf][0][r] - mr0); rs0 += st[kf][0][r];
                st[kf][1][r] = __builtin_amdgcn_exp2f(st[kf][1][r] - mr1); rs1 += st[kf][1][r];
            }
        rs0 += __shfl_xor(rs0, 16); rs0 += __shfl_xor(rs0, 32);
        rs1 += __shfl_xor(rs1, 16); rs1 += __shfl_xor(rs1, 32);
        lr0 += rs0; lr1 += rs1;
        // ---- P^T through per-wave LDS, sequential qi; O^T += V^T * P from swizzled vl ----
#pragma unroll
        for (int qi = 0; qi < 2; qi++) {
            uint2v w0;
            w0[0] = cvtpk(st[0][qi][0], st[0][qi][1]);
            w0[1] = cvtpk(st[0][qi][2], st[0][qi][3]);
            *(uint2v*)&pT[w][fr][kg * 4] = w0;
            uint2v w1;
            w1[0] = cvtpk(st[1][qi][0], st[1][qi][1]);
            w1[1] = cvtpk(st[1][qi][2], st[1][qi][3]);
            *(uint2v*)&pT[w][fr][16 + kg * 4] = w1;
            bf16x8 bq = *(const bf16x8*)&pT[w][fr][kg * 8];
            __builtin_amdgcn_s_setprio(1);
#pragma unroll
            for (int df = 0; df < 8; df++) {
                const int r = df * 16 + fr;
                const int rowp = r >> 2;
                const int c16 = (((r & 3) * 4 + kg) ^ (rowp & 7));
                bf16x8 va = *(const bf16x8*)&vl[cur][rowp * 128 + c16 * 8];
                ot[df][qi] = __builtin_amdgcn_mfma_f32_16x16x32_bf16(va, bq, ot[df][qi], 0, 0, 0);
            }
            __builtin_amdgcn_s_setprio(0);
        }
        __syncthreads();
        cur ^= 1;
    }
    // ---- store: lane holds 4 consecutive d (row) for q (col) = qi*16+fr ----
    const float il0 = 1.0f / lr0, il1 = 1.0f / lr1;
#pragma unroll
    for (int df = 0; df < 8; df++) {
        uint2v w0, w1;
        w0[0] = cvtpk(ot[df][0][0] * il0, ot[df][0][1] * il0);
        w0[1] = cvtpk(ot[df][0][2] * il0, ot[df][0][3] * il0);
        w1[0] = cvtpk(ot[df][1][0] * il1, ot[df][1][1] * il1);
        w1[1] = cvtpk(ot[df][1][2] * il1, ot[df][1][3] * il1);
        *(uint2v*)&o[qbase + (long)(fr) * HD + df * 16 + kg * 4] = w0;
        *(uint2v*)&o[qbase + (long)(16 + fr) * HD + df * 16 + kg * 4] = w1;
    }
}

extern "C" void kernel_launch(void* const* d_in, const int* in_sizes, int n_in,
                              void* d_out, int out_size, void* d_ws, size_t ws_size,
                              hipStream_t stream) {
    (void)in_sizes; (void)n_in; (void)out_size; (void)ws_size;
    const float* x = (const float*)d_in[0];
    const float* Wq = (const float*)d_in[1];
    const float* Wk = (const float*)d_in[2];
    const float* Wv = (const float*)d_in[3];
    const float* Wo = (const float*)d_in[4];

    char* ws = (char*)d_ws;
    u16* xb   = (u16*)(ws + 0);            // 33.5MB  (b,t,c) bf16; later reused as attn output (b,t,h,d)
    u16* kbuf = (u16*)(ws + 33554432);     // 8.4MB   (b,t,kv,d)
    u16* vbuf = (u16*)(ws + 41943040);     // 8.4MB   (b,t,kv,d)
    u16* vtb  = (u16*)(ws + 50331648);     // 8.4MB   (b,kv,d,t)
    u16* wqt  = (u16*)(ws + 58720256);     // 8.4MB
    u16* wkt  = (u16*)(ws + 67108864);     // 2.1MB
    u16* wvt  = (u16*)(ws + 69206016);     // 2.1MB
    u16* wot  = (u16*)(ws + 71303168);     // 8.4MB
    float* cosb = (float*)(ws + 79691776); // 0.5MB
    float* sinb = (float*)(ws + 80216064); // 0.5MB
    u16* qbuf = (u16*)d_out;               // q (b,t,h,d) bf16 lives in d_out until final GEMM

    dim3 tb(32, 8);
    cast_k<<<16384, 256, 0, stream>>>(x, xb, 4194304);
    twt_k<<<dim3(64, 64), tb, 0, stream>>>(Wq, wqt, 2048, 2048);
    twt_k<<<dim3(16, 64), tb, 0, stream>>>(Wk, wkt, 2048, 512);
    twt_k<<<dim3(16, 64), tb, 0, stream>>>(Wv, wvt, 2048, 512);
    twt_k<<<dim3(64, 64), tb, 0, stream>>>(Wo, wot, 2048, 2048);
    tables_k<<<512, 256, 0, stream>>>(cosb, sinb);

    gemm_k<0><<<dim3(64, 16), 256, 0, stream>>>(xb, wqt, qbuf, 8192, 2048, 2048);
    gemm_k<0><<<dim3(64, 4), 256, 0, stream>>>(xb, wkt, kbuf, 8192, 512, 2048);
    gemm_k<0><<<dim3(64, 4), 256, 0, stream>>>(xb, wvt, vbuf, 8192, 512, 2048);

    // q scale = (1/sqrt(128)) * log2(e) -> softmax runs in exp2 domain
    rope_k<<<32768, 256, 0, stream>>>(qbuf, cosb, sinb, 16, 0.1275174316f, 8388608);
    rope_k<<<8192, 256, 0, stream>>>(kbuf, cosb, sinb, 4, 1.0f, 2097152);
    tv_k<<<dim3(4, 64, 16), tb, 0, stream>>>(vbuf, vtb);

    attn_k<<<dim3(64, 4, 4), 256, 0, stream>>>(qbuf, kbuf, vtb, xb);

    gemm_k<1><<<dim3(64, 16), 256, 0, stream>>>(xb, wot, d_out, 8192, 2048, 2048);
}

// Round 9
// 492.579 us; speedup vs baseline: 1.5527x; 1.0929x over previous
//
#include <hip/hip_runtime.h>
#include <cstdint>

#define DEV __device__ __forceinline__

typedef __attribute__((ext_vector_type(4))) float f32x4;
typedef __attribute__((ext_vector_type(4))) float float4v;
typedef __attribute__((ext_vector_type(8))) short bf16x8;
typedef __attribute__((ext_vector_type(4))) unsigned short ushort4v;
typedef __attribute__((ext_vector_type(2))) unsigned int uint2v;
typedef unsigned short u16;

static constexpr int Bb = 4, Tt = 2048, Hh = 16, KVh = 4, Dd = 128;

DEV u16 f2bf(float x) {
    union { float f; unsigned u; } v; v.f = x;
    unsigned r = v.u + 0x7FFF + ((v.u >> 16) & 1);
    return (u16)(r >> 16);
}
DEV float bf2f(u16 b) {
    union { unsigned u; float f; } v; v.u = ((unsigned)b) << 16;
    return v.f;
}
DEV unsigned cvtpk(float lo, float hi) {
    unsigned d;
    asm("v_cvt_pk_bf16_f32 %0, %1, %2" : "=v"(d) : "v"(lo), "v"(hi));
    return d;
}

typedef const void __attribute__((address_space(1)))* gas1;
typedef void __attribute__((address_space(3)))* las3;
DEV void gload16(const void* g, void* l) {
    __builtin_amdgcn_global_load_lds((gas1)g, (las3)l, 16, 0, 0);
}

// ---------------- cast x -> bf16 ----------------
__global__ __launch_bounds__(256) void cast_k(const float* __restrict__ x, u16* __restrict__ xb, long n4) {
    long id = (long)blockIdx.x * 256 + threadIdx.x;
    if (id >= n4) return;
    float4v v = *(const float4v*)&x[id * 4];
    ushort4v o;
    o[0] = f2bf(v[0]); o[1] = f2bf(v[1]); o[2] = f2bf(v[2]); o[3] = f2bf(v[3]);
    *(ushort4v*)&xb[id * 4] = o;
}

// ---------------- transpose+cast weight: W (K x N) f32 -> Wt (N x K) bf16 ----------------
__global__ __launch_bounds__(256) void twt_k(const float* __restrict__ W, u16* __restrict__ Wt, int K, int N) {
    __shared__ float tile[32][33];
    int tx = threadIdx.x, ty = threadIdx.y;
    long n0 = (long)blockIdx.x * 32, k0 = (long)blockIdx.y * 32;
#pragma unroll
    for (int j = 0; j < 4; j++)
        tile[ty + j * 8][tx] = W[(k0 + ty + j * 8) * (long)N + n0 + tx];
    __syncthreads();
#pragma unroll
    for (int j = 0; j < 4; j++)
        Wt[(n0 + ty + j * 8) * (long)K + k0 + tx] = f2bf(tile[tx][ty + j * 8]);
}

// ---------------- transpose v (b,t,kv,d) -> vt (b,kv,d,t) ----------------
__global__ __launch_bounds__(256) void tv_k(const u16* __restrict__ v, u16* __restrict__ vt) {
    __shared__ u16 tile[32][33];
    int tx = threadIdx.x, ty = threadIdx.y;
    int d0 = blockIdx.x * 32;
    int t0 = blockIdx.y * 32;
    int bk = blockIdx.z;
    int b = bk >> 2, kv = bk & 3;
#pragma unroll
    for (int j = 0; j < 4; j++)
        tile[ty + j * 8][tx] = v[((long)(b * Tt + t0 + ty + j * 8) * KVh + kv) * Dd + d0 + tx];
    __syncthreads();
#pragma unroll
    for (int j = 0; j < 4; j++)
        vt[((long)(b * KVh + kv) * Dd + d0 + ty + j * 8) * Tt + t0 + tx] = tile[tx][ty + j * 8];
}

// ---------------- rope tables: [t][i], i<64 ----------------
__global__ __launch_bounds__(256) void tables_k(float* __restrict__ cosb, float* __restrict__ sinb) {
    int id = blockIdx.x * 256 + threadIdx.x; // < 2048*64
    int t = id >> 6, i = id & 63;
    float inv = powf(10000.0f, -(float)i * (1.0f / 64.0f));
    float f = (float)t * inv;
    cosb[id] = cosf(f);
    sinb[id] = sinf(f);
}

// ---------------- rope in-place on (b,t,nh,128); scale folded for q ----------------
__global__ __launch_bounds__(256) void rope_k(u16* __restrict__ p, const float* __restrict__ cosb,
                                              const float* __restrict__ sinb, int nh, float scale, int total) {
    int id = blockIdx.x * 256 + threadIdx.x;
    if (id >= total) return;
    int i = id & 63;
    int bth = id >> 6;
    int t = (bth / nh) % Tt;
    u16* ptr = p + (long)bth * Dd;
    float x1 = bf2f(ptr[i]), x2 = bf2f(ptr[i + 64]);
    float c = cosb[t * 64 + i], s = sinb[t * 64 + i];
    ptr[i] = f2bf((x1 * c - x2 * s) * scale);
    ptr[i + 64] = f2bf((x2 * c + x1 * s) * scale);
}

// ---------------- GEMM: A (M x K) bf16 row-major, Bt (N x K) bf16 row-major -> C (M x N) ----------------
template <int F32OUT>
__global__ __launch_bounds__(256) void gemm_k(const u16* __restrict__ A, const u16* __restrict__ Bt,
                                              void* __restrict__ Cout, int M, int N, int K) {
    __shared__ u16 aLds[128 * 32];
    __shared__ u16 bLds[128 * 32];
    const int tid = threadIdx.x;
    const int lane = tid & 63;
    const int wid = __builtin_amdgcn_readfirstlane(tid >> 6);
    const long m0 = (long)blockIdx.x * 128;
    const long n0 = (long)blockIdx.y * 128;
    const int wr = wid >> 1, wc = wid & 1;
    const int r0 = wid * 32;
    const int lrow = lane >> 2;
    const int lkb = (lane & 3) * 8;
    const u16* gA = A + (m0 + r0 + lrow) * (long)K + lkb;
    const u16* gB = Bt + (n0 + r0 + lrow) * (long)K + lkb;
    u16* lA = &aLds[r0 * 32];
    u16* lB = &bLds[r0 * 32];
    f32x4 acc[4][4] = {};
    const int fr = lane & 15, fk = (lane >> 4) * 8;
    for (int kt = 0; kt < K; kt += 32) {
        gload16(gA + kt, lA);
        gload16(gA + kt + 16 * (long)K, lA + 16 * 32);
        gload16(gB + kt, lB);
        gload16(gB + kt + 16 * (long)K, lB + 16 * 32);
        __syncthreads();
        bf16x8 af[4], bfr[4];
#pragma unroll
        for (int i = 0; i < 4; i++) {
            af[i] = *(const bf16x8*)&aLds[(wr * 64 + i * 16 + fr) * 32 + fk];
            bfr[i] = *(const bf16x8*)&bLds[(wc * 64 + i * 16 + fr) * 32 + fk];
        }
#pragma unroll
        for (int i = 0; i < 4; i++)
#pragma unroll
            for (int j = 0; j < 4; j++)
                acc[i][j] = __builtin_amdgcn_mfma_f32_16x16x32_bf16(af[i], bfr[j], acc[i][j], 0, 0, 0);
        __syncthreads();
    }
    const int orow = (lane >> 4) * 4, ocol = lane & 15;
#pragma unroll
    for (int i = 0; i < 4; i++)
#pragma unroll
        for (int j = 0; j < 4; j++) {
            long r = m0 + wr * 64 + i * 16 + orow;
            long c = n0 + wc * 64 + j * 16 + ocol;
#pragma unroll
            for (int t = 0; t < 4; t++) {
                if (F32OUT)
                    ((float*)Cout)[(r + t) * N + c] = acc[i][j][t];
                else
                    ((u16*)Cout)[(r + t) * N + c] = f2bf(acc[i][j][t]);
            }
        }
}

// ---------------- flash attention v8: pair-balanced blocks ----------------
// Block (bid, kv, b) processes q-tiles {63-bid, bid} SEQUENTIALLY -> every block does exactly
// 65 compute-tiles (perfect static balance, 512 blocks = 2/CU all co-resident, no tail).
// Within a pass: identical to verified v7 (4 heads share dbuf K/V LDS staging; swapped QK^T,
// in-register exp2 softmax with defer-max, P^T via per-wave LDS stride-36, O^T = mfma(V^T,P)).
__global__ __launch_bounds__(256, 3) void attn_k(const u16* __restrict__ q, const u16* __restrict__ k,
                                                 const u16* __restrict__ vt, u16* __restrict__ o) {
    __shared__ u16 kl[2][4096];
    __shared__ u16 vl[2][4096];
    __shared__ u16 pT[4][16][36];
    const int tid = threadIdx.x;
    const int lane = tid & 63;
    const int w = tid >> 6;
    const int kv = blockIdx.y, b = blockIdx.z;
    const int h = kv * 4 + w;
    const int fr = lane & 15, kg = lane >> 4;
    const long HD = (long)Hh * Dd;
    const long KD = (long)KVh * Dd;
    const long kbase = ((long)(b * Tt)) * KD + (long)kv * Dd;
    const long vbase = ((long)(b * KVh + kv)) * (long)Dd * Tt;

    auto stage = [&](int bb, int it) {
        const int s0 = it * 32;
        const int lh = lane >> 4;     // 0..3
#pragma unroll
        for (int j = 0; j < 2; j++) { // K: 8 chunks of 1KB, chunk c = j*4+w
            int c = j * 4 + w;
            int row = c * 4 + lh;
            int c16 = (lane & 15) ^ (row & 7);
            gload16(k + kbase + (long)(s0 + row) * KD + c16 * 8, &kl[bb][c * 512]);
        }
#pragma unroll
        for (int j = 0; j < 2; j++) { // V: 8 chunks of 1KB
            int c = j * 4 + w;
            int rowp = c * 4 + lh;
            int c16u = (lane & 15) ^ (rowp & 7);
            int r = rowp * 4 + (c16u >> 2);
            gload16(vt + vbase + (long)r * Tt + s0 + (c16u & 3) * 8, &vl[bb][c * 512]);
        }
    };

    for (int pass = 0; pass < 2; ++pass) {
        const int qt = pass ? (int)blockIdx.x : 63 - (int)blockIdx.x;
        const int q0 = qt * 32;
        const long qbase = ((long)(b * Tt + q0)) * HD + (long)h * Dd;

        bf16x8 qa[2][4];
#pragma unroll
        for (int qi = 0; qi < 2; qi++)
#pragma unroll
            for (int kc = 0; kc < 4; kc++)
                qa[qi][kc] = *(const bf16x8*)&q[qbase + (long)(qi * 16 + fr) * HD + kc * 32 + kg * 8];

        f32x4 ot[8][2] = {};          // O^T accumulator: [df][qi]
        float mr0 = -1e30f, mr1 = -1e30f, lr0 = 0.0f, lr1 = 0.0f;
        const int nt = qt + 1;

        stage(0, 0);
        __syncthreads();
        int cur = 0;
        for (int it = 0; it < nt; ++it) {
            if (it + 1 < nt) stage(cur ^ 1, it + 1);
            const int s0 = it * 32;
            // ---- S^T = K * Q^T from swizzled kl ----
            f32x4 st[2][2] = {};      // [kf][qi]
            __builtin_amdgcn_s_setprio(1);
#pragma unroll
            for (int kf = 0; kf < 2; kf++) {
                const int rr = kf * 16 + fr;
                bf16x8 ka[4];
#pragma unroll
                for (int kc = 0; kc < 4; kc++)
                    ka[kc] = *(const bf16x8*)&kl[cur][rr * 128 + (((kc * 4 + kg) ^ (rr & 7)) * 8)];
#pragma unroll
                for (int kc = 0; kc < 4; kc++) {
                    st[kf][0] = __builtin_amdgcn_mfma_f32_16x16x32_bf16(ka[kc], qa[0][kc], st[kf][0], 0, 0, 0);
                    st[kf][1] = __builtin_amdgcn_mfma_f32_16x16x32_bf16(ka[kc], qa[1][kc], st[kf][1], 0, 0, 0);
                }
            }
            __builtin_amdgcn_s_setprio(0);
            // ---- causal mask (diagonal tile only) ----
            if (it == nt - 1) {
#pragma unroll
                for (int kf = 0; kf < 2; kf++)
#pragma unroll
                    for (int qi = 0; qi < 2; qi++) {
                        const int qq = q0 + qi * 16 + fr;
                        const int kb0 = s0 + kf * 16 + kg * 4;
#pragma unroll
                        for (int r = 0; r < 4; r++)
                            if (kb0 + r > qq) st[kf][qi][r] = -1e30f;
                    }
            }
            // ---- in-register online softmax (base-2 domain) ----
            float tm0 = st[0][0][0], tm1 = st[0][1][0];
#pragma unroll
            for (int kf = 0; kf < 2; kf++)
#pragma unroll
                for (int r = 0; r < 4; r++)
                    if (kf | r) {
                        tm0 = fmaxf(tm0, st[kf][0][r]);
                        tm1 = fmaxf(tm1, st[kf][1][r]);
                    }
            tm0 = fmaxf(tm0, __shfl_xor(tm0, 16)); tm0 = fmaxf(tm0, __shfl_xor(tm0, 32));
            tm1 = fmaxf(tm1, __shfl_xor(tm1, 16)); tm1 = fmaxf(tm1, __shfl_xor(tm1, 32));
            if (__any(fmaxf(tm0 - mr0, tm1 - mr1) > 8.0f)) {
                float mn0 = fmaxf(mr0, tm0), mn1 = fmaxf(mr1, tm1);
                float al0 = __builtin_amdgcn_exp2f(mr0 - mn0);
                float al1 = __builtin_amdgcn_exp2f(mr1 - mn1);
                mr0 = mn0; mr1 = mn1;
                lr0 *= al0; lr1 *= al1;
#pragma unroll
                for (int df = 0; df < 8; df++) { ot[df][0] *= al0; ot[df][1] *= al1; }
            }
            float rs0 = 0.0f, rs1 = 0.0f;
#pragma unroll
            for (int kf = 0; kf < 2; kf++)
#pragma unroll
                for (int r = 0; r < 4; r++) {
                    st[kf][0][r] = __builtin_amdgcn_exp2f(st[kf][0][r] - mr0); rs0 += st[kf][0][r];
                    st[kf][1][r] = __builtin_amdgcn_exp2f(st[kf][1][r] - mr1); rs1 += st[kf][1][r];
                }
            rs0 += __shfl_xor(rs0, 16); rs0 += __shfl_xor(rs0, 32);
            rs1 += __shfl_xor(rs1, 16); rs1 += __shfl_xor(rs1, 32);
            lr0 += rs0; lr1 += rs1;
            // ---- P^T through per-wave LDS, sequential qi; O^T += V^T * P from swizzled vl ----
#pragma unroll
            for (int qi = 0; qi < 2; qi++) {
                uint2v w0;
                w0[0] = cvtpk(st[0][qi][0], st[0][qi][1]);
                w0[1] = cvtpk(st[0][qi][2], st[0][qi][3]);
                *(uint2v*)&pT[w][fr][kg * 4] = w0;
                uint2v w1;
                w1[0] = cvtpk(st[1][qi][0], st[1][qi][1]);
                w1[1] = cvtpk(st[1][qi][2], st[1][qi][3]);
                *(uint2v*)&pT[w][fr][16 + kg * 4] = w1;
                bf16x8 bq = *(const bf16x8*)&pT[w][fr][kg * 8];
                __builtin_amdgcn_s_setprio(1);
#pragma unroll
                for (int df = 0; df < 8; df++) {
                    const int r = df * 16 + fr;
                    const int rowp = r >> 2;
                    const int c16 = (((r & 3) * 4 + kg) ^ (rowp & 7));
                    bf16x8 va = *(const bf16x8*)&vl[cur][rowp * 128 + c16 * 8];
                    ot[df][qi] = __builtin_amdgcn_mfma_f32_16x16x32_bf16(va, bq, ot[df][qi], 0, 0, 0);
                }
                __builtin_amdgcn_s_setprio(0);
            }
            __syncthreads();
            cur ^= 1;
        }
        // ---- store: lane holds 4 consecutive d (row) for q (col) = qi*16+fr ----
        const float il0 = 1.0f / lr0, il1 = 1.0f / lr1;
#pragma unroll
        for (int df = 0; df < 8; df++) {
            uint2v w0, w1;
            w0[0] = cvtpk(ot[df][0][0] * il0, ot[df][0][1] * il0);
            w0[1] = cvtpk(ot[df][0][2] * il0, ot[df][0][3] * il0);
            w1[0] = cvtpk(ot[df][1][0] * il1, ot[df][1][1] * il1);
            w1[1] = cvtpk(ot[df][1][2] * il1, ot[df][1][3] * il1);
            *(uint2v*)&o[qbase + (long)(fr) * HD + df * 16 + kg * 4] = w0;
            *(uint2v*)&o[qbase + (long)(16 + fr) * HD + df * 16 + kg * 4] = w1;
        }
    }
}

extern "C" void kernel_launch(void* const* d_in, const int* in_sizes, int n_in,
                              void* d_out, int out_size, void* d_ws, size_t ws_size,
                              hipStream_t stream) {
    (void)in_sizes; (void)n_in; (void)out_size; (void)ws_size;
    const float* x = (const float*)d_in[0];
    const float* Wq = (const float*)d_in[1];
    const float* Wk = (const float*)d_in[2];
    const float* Wv = (const float*)d_in[3];
    const float* Wo = (const float*)d_in[4];

    char* ws = (char*)d_ws;
    u16* xb   = (u16*)(ws + 0);            // 33.5MB  (b,t,c) bf16; later reused as attn output (b,t,h,d)
    u16* kbuf = (u16*)(ws + 33554432);     // 8.4MB   (b,t,kv,d)
    u16* vbuf = (u16*)(ws + 41943040);     // 8.4MB   (b,t,kv,d)
    u16* vtb  = (u16*)(ws + 50331648);     // 8.4MB   (b,kv,d,t)
    u16* wqt  = (u16*)(ws + 58720256);     // 8.4MB
    u16* wkt  = (u16*)(ws + 67108864);     // 2.1MB
    u16* wvt  = (u16*)(ws + 69206016);     // 2.1MB
    u16* wot  = (u16*)(ws + 71303168);     // 8.4MB
    float* cosb = (float*)(ws + 79691776); // 0.5MB
    float* sinb = (float*)(ws + 80216064); // 0.5MB
    u16* qbuf = (u16*)d_out;               // q (b,t,h,d) bf16 lives in d_out until final GEMM

    dim3 tb(32, 8);
    cast_k<<<16384, 256, 0, stream>>>(x, xb, 4194304);
    twt_k<<<dim3(64, 64), tb, 0, stream>>>(Wq, wqt, 2048, 2048);
    twt_k<<<dim3(16, 64), tb, 0, stream>>>(Wk, wkt, 2048, 512);
    twt_k<<<dim3(16, 64), tb, 0, stream>>>(Wv, wvt, 2048, 512);
    twt_k<<<dim3(64, 64), tb, 0, stream>>>(Wo, wot, 2048, 2048);
    tables_k<<<512, 256, 0, stream>>>(cosb, sinb);

    gemm_k<0><<<dim3(64, 16), 256, 0, stream>>>(xb, wqt, qbuf, 8192, 2048, 2048);
    gemm_k<0><<<dim3(64, 4), 256, 0, stream>>>(xb, wkt, kbuf, 8192, 512, 2048);
    gemm_k<0><<<dim3(64, 4), 256, 0, stream>>>(xb, wvt, vbuf, 8192, 512, 2048);

    // q scale = (1/sqrt(128)) * log2(e) -> softmax runs in exp2 domain
    rope_k<<<32768, 256, 0, stream>>>(qbuf, cosb, sinb, 16, 0.1275174316f, 8388608);
    rope_k<<<8192, 256, 0, stream>>>(kbuf, cosb, sinb, 4, 1.0f, 2097152);
    tv_k<<<dim3(4, 64, 16), tb, 0, stream>>>(vbuf, vtb);

    attn_k<<<dim3(32, 4, 4), 256, 0, stream>>>(qbuf, kbuf, vtb, xb);

    gemm_k<1><<<dim3(64, 16), 256, 0, stream>>>(xb, wot, d_out, 8192, 2048, 2048);
}

// Round 11
// 428.506 us; speedup vs baseline: 1.7849x; 1.1495x over previous
//
#include <hip/hip_runtime.h>
#include <cstdint>

#define DEV __device__ __forceinline__

typedef __attribute__((ext_vector_type(4))) float f32x4;
typedef __attribute__((ext_vector_type(4))) float float4v;
typedef __attribute__((ext_vector_type(8))) short bf16x8;
typedef __attribute__((ext_vector_type(4))) unsigned short ushort4v;
typedef __attribute__((ext_vector_type(2))) unsigned int uint2v;
typedef unsigned short u16;

static constexpr int Bb = 4, Tt = 2048, Hh = 16, KVh = 4, Dd = 128;
static constexpr int NQKV = 3072;   // fused projection width: 2048 q + 512 k + 512 v

DEV u16 f2bf(float x) {
    union { float f; unsigned u; } v; v.f = x;
    unsigned r = v.u + 0x7FFF + ((v.u >> 16) & 1);
    return (u16)(r >> 16);
}
DEV float bf2f(u16 b) {
    union { unsigned u; float f; } v; v.u = ((unsigned)b) << 16;
    return v.f;
}
DEV unsigned cvtpk(float lo, float hi) {
    unsigned d;
    asm("v_cvt_pk_bf16_f32 %0, %1, %2" : "=v"(d) : "v"(lo), "v"(hi));
    return d;
}

typedef const void __attribute__((address_space(1)))* gas1;
typedef void __attribute__((address_space(3)))* las3;
DEV void gload16(const void* g, void* l) {
    __builtin_amdgcn_global_load_lds((gas1)g, (las3)l, 16, 0, 0);
}

// ---------------- cast x -> bf16 ----------------
__global__ __launch_bounds__(256) void cast_k(const float* __restrict__ x, u16* __restrict__ xb, long n4) {
    long id = (long)blockIdx.x * 256 + threadIdx.x;
    if (id >= n4) return;
    float4v v = *(const float4v*)&x[id * 4];
    ushort4v o;
    o[0] = f2bf(v[0]); o[1] = f2bf(v[1]); o[2] = f2bf(v[2]); o[3] = f2bf(v[3]);
    *(ushort4v*)&xb[id * 4] = o;
}

// ---------------- transpose+cast weight: W (K x N) f32 -> Wt (N x K) bf16 ----------------
__global__ __launch_bounds__(256) void twt_k(const float* __restrict__ W, u16* __restrict__ Wt, int K, int N) {
    __shared__ float tile[32][33];
    int tx = threadIdx.x, ty = threadIdx.y;
    long n0 = (long)blockIdx.x * 32, k0 = (long)blockIdx.y * 32;
#pragma unroll
    for (int j = 0; j < 4; j++)
        tile[ty + j * 8][tx] = W[(k0 + ty + j * 8) * (long)N + n0 + tx];
    __syncthreads();
#pragma unroll
    for (int j = 0; j < 4; j++)
        Wt[(n0 + ty + j * 8) * (long)K + k0 + tx] = f2bf(tile[tx][ty + j * 8]);
}

// ---------------- transpose v (from fused qkv, stride 3072, col 2560) -> vt (b,kv,d,t) ----------------
__global__ __launch_bounds__(256) void tv_k(const u16* __restrict__ qkv, u16* __restrict__ vt) {
    __shared__ u16 tile[32][33];
    int tx = threadIdx.x, ty = threadIdx.y;
    int d0 = blockIdx.x * 32;
    int t0 = blockIdx.y * 32;
    int bk = blockIdx.z;
    int b = bk >> 2, kv = bk & 3;
#pragma unroll
    for (int j = 0; j < 4; j++)
        tile[ty + j * 8][tx] = qkv[(long)(b * Tt + t0 + ty + j * 8) * NQKV + 2560 + kv * Dd + d0 + tx];
    __syncthreads();
#pragma unroll
    for (int j = 0; j < 4; j++)
        vt[((long)(b * KVh + kv) * Dd + d0 + ty + j * 8) * Tt + t0 + tx] = tile[tx][ty + j * 8];
}

// ---------------- rope tables: [t][i], i<64 ----------------
__global__ __launch_bounds__(256) void tables_k(float* __restrict__ cosb, float* __restrict__ sinb) {
    int id = blockIdx.x * 256 + threadIdx.x; // < 2048*64
    int t = id >> 6, i = id & 63;
    float inv = powf(10000.0f, -(float)i * (1.0f / 64.0f));
    float f = (float)t * inv;
    cosb[id] = cosf(f);
    sinb[id] = sinf(f);
}

// ---------------- rope in-place on fused layout; scale folded for q ----------------
// element (row = b*T+t, col = colbase + hh*128 + i), hh = head-within-kind (nh heads)
__global__ __launch_bounds__(256) void rope_k(u16* __restrict__ p, const float* __restrict__ cosb,
                                              const float* __restrict__ sinb, int nh, float scale, int total,
                                              long rowstride, int colbase) {
    int id = blockIdx.x * 256 + threadIdx.x;
    if (id >= total) return;
    int i = id & 63;
    int bth = id >> 6;
    int row = bth / nh;
    int t = row % Tt;
    u16* ptr = p + (long)row * rowstride + colbase + (bth % nh) * Dd;
    float x1 = bf2f(ptr[i]), x2 = bf2f(ptr[i + 64]);
    float c = cosb[t * 64 + i], s = sinb[t * 64 + i];
    ptr[i] = f2bf((x1 * c - x2 * s) * scale);
    ptr[i + 64] = f2bf((x2 * c + x1 * s) * scale);
}

// ---------------- GEMM: A (M x K) bf16 row-major, Bt (N x K) bf16 row-major -> C (M x N) ----------------
template <int F32OUT>
__global__ __launch_bounds__(256) void gemm_k(const u16* __restrict__ A, const u16* __restrict__ Bt,
                                              void* __restrict__ Cout, int M, int N, int K) {
    __shared__ u16 aLds[128 * 32];
    __shared__ u16 bLds[128 * 32];
    const int tid = threadIdx.x;
    const int lane = tid & 63;
    const int wid = __builtin_amdgcn_readfirstlane(tid >> 6);
    const long m0 = (long)blockIdx.x * 128;
    const long n0 = (long)blockIdx.y * 128;
    const int wr = wid >> 1, wc = wid & 1;
    const int r0 = wid * 32;
    const int lrow = lane >> 2;
    const int lkb = (lane & 3) * 8;
    const u16* gA = A + (m0 + r0 + lrow) * (long)K + lkb;
    const u16* gB = Bt + (n0 + r0 + lrow) * (long)K + lkb;
    u16* lA = &aLds[r0 * 32];
    u16* lB = &bLds[r0 * 32];
    f32x4 acc[4][4] = {};
    const int fr = lane & 15, fk = (lane >> 4) * 8;
    for (int kt = 0; kt < K; kt += 32) {
        gload16(gA + kt, lA);
        gload16(gA + kt + 16 * (long)K, lA + 16 * 32);
        gload16(gB + kt, lB);
        gload16(gB + kt + 16 * (long)K, lB + 16 * 32);
        __syncthreads();
        bf16x8 af[4], bfr[4];
#pragma unroll
        for (int i = 0; i < 4; i++) {
            af[i] = *(const bf16x8*)&aLds[(wr * 64 + i * 16 + fr) * 32 + fk];
            bfr[i] = *(const bf16x8*)&bLds[(wc * 64 + i * 16 + fr) * 32 + fk];
        }
#pragma unroll
        for (int i = 0; i < 4; i++)
#pragma unroll
            for (int j = 0; j < 4; j++)
                acc[i][j] = __builtin_amdgcn_mfma_f32_16x16x32_bf16(af[i], bfr[j], acc[i][j], 0, 0, 0);
        __syncthreads();
    }
    const int orow = (lane >> 4) * 4, ocol = lane & 15;
#pragma unroll
    for (int i = 0; i < 4; i++)
#pragma unroll
        for (int j = 0; j < 4; j++) {
            long r = m0 + wr * 64 + i * 16 + orow;
            long c = n0 + wc * 64 + j * 16 + ocol;
#pragma unroll
            for (int t = 0; t < 4; t++) {
                if (F32OUT)
                    ((float*)Cout)[(r + t) * N + c] = acc[i][j][t];
                else
                    ((u16*)Cout)[(r + t) * N + c] = f2bf(acc[i][j][t]);
            }
        }
}

// ---------------- flash attention v9: pair-balanced blocks, fused-qkv inputs ----------------
// Block (bid, kv, b) processes q-tiles {63-bid, bid} SEQUENTIALLY -> every block does exactly
// 65 compute-tiles (perfect static balance, 512 blocks = 2/CU all co-resident, no tail).
// q/k read from fused qkv (row stride 3072; q at col h*128, k at col 2048+kv*128).
// Per-tile math verbatim from verified v7/v8: 4 heads share dbuf K/V LDS staging; swapped QK^T,
// in-register exp2 softmax with defer-max, P^T via per-wave LDS stride-36, O^T = mfma(V^T,P).
__global__ __launch_bounds__(256, 3) void attn_k(const u16* __restrict__ qkv,
                                                 const u16* __restrict__ vt, u16* __restrict__ o) {
    __shared__ u16 kl[2][4096];
    __shared__ u16 vl[2][4096];
    __shared__ u16 pT[4][16][36];
    const int tid = threadIdx.x;
    const int lane = tid & 63;
    const int w = tid >> 6;
    const int kv = blockIdx.y, b = blockIdx.z;
    const int h = kv * 4 + w;
    const int fr = lane & 15, kg = lane >> 4;
    const long HD = (long)Hh * Dd;               // output row stride (2048)
    const long QS = (long)NQKV;                  // fused row stride (3072)
    const long kbase = (long)b * Tt * QS + 2048 + (long)kv * Dd;
    const long vbase = ((long)(b * KVh + kv)) * (long)Dd * Tt;

    auto stage = [&](int bb, int it) {
        const int s0 = it * 32;
        const int lh = lane >> 4;     // 0..3
#pragma unroll
        for (int j = 0; j < 2; j++) { // K: 8 chunks of 1KB, chunk c = j*4+w
            int c = j * 4 + w;
            int row = c * 4 + lh;
            int c16 = (lane & 15) ^ (row & 7);
            gload16(qkv + kbase + (long)(s0 + row) * QS + c16 * 8, &kl[bb][c * 512]);
        }
#pragma unroll
        for (int j = 0; j < 2; j++) { // V: 8 chunks of 1KB
            int c = j * 4 + w;
            int rowp = c * 4 + lh;
            int c16u = (lane & 15) ^ (rowp & 7);
            int r = rowp * 4 + (c16u >> 2);
            gload16(vt + vbase + (long)r * Tt + s0 + (c16u & 3) * 8, &vl[bb][c * 512]);
        }
    };

    for (int pass = 0; pass < 2; ++pass) {
        const int qt = pass ? (int)blockIdx.x : 63 - (int)blockIdx.x;
        const int q0 = qt * 32;
        const long qbase = (long)(b * Tt + q0) * QS + (long)h * Dd;
        const long obase = (long)(b * Tt + q0) * HD + (long)h * Dd;

        bf16x8 qa[2][4];
#pragma unroll
        for (int qi = 0; qi < 2; qi++)
#pragma unroll
            for (int kc = 0; kc < 4; kc++)
                qa[qi][kc] = *(const bf16x8*)&qkv[qbase + (long)(qi * 16 + fr) * QS + kc * 32 + kg * 8];

        f32x4 ot[8][2] = {};          // O^T accumulator: [df][qi]
        float mr0 = -1e30f, mr1 = -1e30f, lr0 = 0.0f, lr1 = 0.0f;
        const int nt = qt + 1;

        stage(0, 0);
        __syncthreads();
        int cur = 0;
        for (int it = 0; it < nt; ++it) {
            if (it + 1 < nt) stage(cur ^ 1, it + 1);
            const int s0 = it * 32;
            // ---- S^T = K * Q^T from swizzled kl ----
            f32x4 st[2][2] = {};      // [kf][qi]
            __builtin_amdgcn_s_setprio(1);
#pragma unroll
            for (int kf = 0; kf < 2; kf++) {
                const int rr = kf * 16 + fr;
                bf16x8 ka[4];
#pragma unroll
                for (int kc = 0; kc < 4; kc++)
                    ka[kc] = *(const bf16x8*)&kl[cur][rr * 128 + (((kc * 4 + kg) ^ (rr & 7)) * 8)];
#pragma unroll
                for (int kc = 0; kc < 4; kc++) {
                    st[kf][0] = __builtin_amdgcn_mfma_f32_16x16x32_bf16(ka[kc], qa[0][kc], st[kf][0], 0, 0, 0);
                    st[kf][1] = __builtin_amdgcn_mfma_f32_16x16x32_bf16(ka[kc], qa[1][kc], st[kf][1], 0, 0, 0);
                }
            }
            __builtin_amdgcn_s_setprio(0);
            // ---- causal mask (diagonal tile only) ----
            if (it == nt - 1) {
#pragma unroll
                for (int kf = 0; kf < 2; kf++)
#pragma unroll
                    for (int qi = 0; qi < 2; qi++) {
                        const int qq = q0 + qi * 16 + fr;
                        const int kb0 = s0 + kf * 16 + kg * 4;
#pragma unroll
                        for (int r = 0; r < 4; r++)
                            if (kb0 + r > qq) st[kf][qi][r] = -1e30f;
                    }
            }
            // ---- in-register online softmax (base-2 domain) ----
            float tm0 = st[0][0][0], tm1 = st[0][1][0];
#pragma unroll
            for (int kf = 0; kf < 2; kf++)
#pragma unroll
                for (int r = 0; r < 4; r++)
                    if (kf | r) {
                        tm0 = fmaxf(tm0, st[kf][0][r]);
                        tm1 = fmaxf(tm1, st[kf][1][r]);
                    }
            tm0 = fmaxf(tm0, __shfl_xor(tm0, 16)); tm0 = fmaxf(tm0, __shfl_xor(tm0, 32));
            tm1 = fmaxf(tm1, __shfl_xor(tm1, 16)); tm1 = fmaxf(tm1, __shfl_xor(tm1, 32));
            if (__any(fmaxf(tm0 - mr0, tm1 - mr1) > 8.0f)) {
                float mn0 = fmaxf(mr0, tm0), mn1 = fmaxf(mr1, tm1);
                float al0 = __builtin_amdgcn_exp2f(mr0 - mn0);
                float al1 = __builtin_amdgcn_exp2f(mr1 - mn1);
                mr0 = mn0; mr1 = mn1;
                lr0 *= al0; lr1 *= al1;
#pragma unroll
                for (int df = 0; df < 8; df++) { ot[df][0] *= al0; ot[df][1] *= al1; }
            }
            float rs0 = 0.0f, rs1 = 0.0f;
#pragma unroll
            for (int kf = 0; kf < 2; kf++)
#pragma unroll
                for (int r = 0; r < 4; r++) {
                    st[kf][0][r] = __builtin_amdgcn_exp2f(st[kf][0][r] - mr0); rs0 += st[kf][0][r];
                    st[kf][1][r] = __builtin_amdgcn_exp2f(st[kf][1][r] - mr1); rs1 += st[kf][1][r];
                }
            rs0 += __shfl_xor(rs0, 16); rs0 += __shfl_xor(rs0, 32);
            rs1 += __shfl_xor(rs1, 16); rs1 += __shfl_xor(rs1, 32);
            lr0 += rs0; lr1 += rs1;
            // ---- P^T through per-wave LDS, sequential qi; O^T += V^T * P from swizzled vl ----
#pragma unroll
            for (int qi = 0; qi < 2; qi++) {
                uint2v w0;
                w0[0] = cvtpk(st[0][qi][0], st[0][qi][1]);
                w0[1] = cvtpk(st[0][qi][2], st[0][qi][3]);
                *(uint2v*)&pT[w][fr][kg * 4] = w0;
                uint2v w1;
                w1[0] = cvtpk(st[1][qi][0], st[1][qi][1]);
                w1[1] = cvtpk(st[1][qi][2], st[1][qi][3]);
                *(uint2v*)&pT[w][fr][16 + kg * 4] = w1;
                bf16x8 bq = *(const bf16x8*)&pT[w][fr][kg * 8];
                __builtin_amdgcn_s_setprio(1);
#pragma unroll
                for (int df = 0; df < 8; df++) {
                    const int r = df * 16 + fr;
                    const int rowp = r >> 2;
                    const int c16 = (((r & 3) * 4 + kg) ^ (rowp & 7));
                    bf16x8 va = *(const bf16x8*)&vl[cur][rowp * 128 + c16 * 8];
                    ot[df][qi] = __builtin_amdgcn_mfma_f32_16x16x32_bf16(va, bq, ot[df][qi], 0, 0, 0);
                }
                __builtin_amdgcn_s_setprio(0);
            }
            __syncthreads();
            cur ^= 1;
        }
        // ---- store: lane holds 4 consecutive d (row) for q (col) = qi*16+fr ----
        const float il0 = 1.0f / lr0, il1 = 1.0f / lr1;
#pragma unroll
        for (int df = 0; df < 8; df++) {
            uint2v w0, w1;
            w0[0] = cvtpk(ot[df][0][0] * il0, ot[df][0][1] * il0);
            w0[1] = cvtpk(ot[df][0][2] * il0, ot[df][0][3] * il0);
            w1[0] = cvtpk(ot[df][1][0] * il1, ot[df][1][1] * il1);
            w1[1] = cvtpk(ot[df][1][2] * il1, ot[df][1][3] * il1);
            *(uint2v*)&o[obase + (long)(fr) * HD + df * 16 + kg * 4] = w0;
            *(uint2v*)&o[obase + (long)(16 + fr) * HD + df * 16 + kg * 4] = w1;
        }
    }
}

extern "C" void kernel_launch(void* const* d_in, const int* in_sizes, int n_in,
                              void* d_out, int out_size, void* d_ws, size_t ws_size,
                              hipStream_t stream) {
    (void)in_sizes; (void)n_in; (void)out_size; (void)ws_size;
    const float* x = (const float*)d_in[0];
    const float* Wq = (const float*)d_in[1];
    const float* Wk = (const float*)d_in[2];
    const float* Wv = (const float*)d_in[3];
    const float* Wo = (const float*)d_in[4];

    char* ws = (char*)d_ws;
    u16* xb   = (u16*)(ws + 0);            // 33.5MB  (b,t,c) bf16; later reused as attn output (b,t,h,d)
    u16* vtb  = (u16*)(ws + 50331648);     // 8.4MB   (b,kv,d,t)
    u16* wqt  = (u16*)(ws + 58720256);     // 8.4MB   (first part of fused Wt, 3072 x 2048)
    u16* wkt  = (u16*)(ws + 67108864);     // 2.1MB   (contiguous after wqt)
    u16* wvt  = (u16*)(ws + 69206016);     // 2.1MB   (contiguous after wkt)
    u16* wot  = (u16*)(ws + 71303168);     // 8.4MB
    float* cosb = (float*)(ws + 79691776); // 0.5MB
    float* sinb = (float*)(ws + 80216064); // 0.5MB
    u16* qkv = (u16*)d_out;                // fused qkv (8192 x 3072) bf16 lives in d_out until final GEMM

    dim3 tb(32, 8);
    cast_k<<<16384, 256, 0, stream>>>(x, xb, 4194304);
    twt_k<<<dim3(64, 64), tb, 0, stream>>>(Wq, wqt, 2048, 2048);
    twt_k<<<dim3(16, 64), tb, 0, stream>>>(Wk, wkt, 2048, 512);
    twt_k<<<dim3(16, 64), tb, 0, stream>>>(Wv, wvt, 2048, 512);
    twt_k<<<dim3(64, 64), tb, 0, stream>>>(Wo, wot, 2048, 2048);
    tables_k<<<512, 256, 0, stream>>>(cosb, sinb);

    // fused QKV projection: one GEMM, N = 2048+512+512
    gemm_k<0><<<dim3(64, 24), 256, 0, stream>>>(xb, wqt, qkv, 8192, NQKV, 2048);

    // q scale = (1/sqrt(128)) * log2(e) -> softmax runs in exp2 domain
    rope_k<<<32768, 256, 0, stream>>>(qkv, cosb, sinb, 16, 0.1275174316f, 8388608, NQKV, 0);
    rope_k<<<8192, 256, 0, stream>>>(qkv, cosb, sinb, 4, 1.0f, 2097152, NQKV, 2048);
    tv_k<<<dim3(4, 64, 16), tb, 0, stream>>>(qkv, vtb);

    attn_k<<<dim3(32, 4, 4), 256, 0, stream>>>(qkv, vtb, xb);

    gemm_k<1><<<dim3(64, 16), 256, 0, stream>>>(xb, wot, d_out, 8192, 2048, 2048);
}

// Round 12
// 372.923 us; speedup vs baseline: 2.0510x; 1.1490x over previous
//
#include <hip/hip_runtime.h>
#include <cstdint>

#define DEV __device__ __forceinline__

typedef __attribute__((ext_vector_type(4))) float f32x4;
typedef __attribute__((ext_vector_type(4))) float float4v;
typedef __attribute__((ext_vector_type(8))) short bf16x8;
typedef __attribute__((ext_vector_type(4))) unsigned short ushort4v;
typedef __attribute__((ext_vector_type(2))) unsigned int uint2v;
typedef unsigned short u16;

static constexpr int Bb = 4, Tt = 2048, Hh = 16, KVh = 4, Dd = 128;
static constexpr int NQKV = 3072;   // fused projection width: 2048 q + 512 k + 512 v

DEV u16 f2bf(float x) {
    union { float f; unsigned u; } v; v.f = x;
    unsigned r = v.u + 0x7FFF + ((v.u >> 16) & 1);
    return (u16)(r >> 16);
}
DEV float bf2f(u16 b) {
    union { unsigned u; float f; } v; v.u = ((unsigned)b) << 16;
    return v.f;
}
DEV unsigned cvtpk(float lo, float hi) {
    unsigned d;
    asm("v_cvt_pk_bf16_f32 %0, %1, %2" : "=v"(d) : "v"(lo), "v"(hi));
    return d;
}

typedef const void __attribute__((address_space(1)))* gas1;
typedef void __attribute__((address_space(3)))* las3;
DEV void gload16(const void* g, void* l) {
    __builtin_amdgcn_global_load_lds((gas1)g, (las3)l, 16, 0, 0);
}

// ---------------- cast x -> bf16 ----------------
__global__ __launch_bounds__(256) void cast_k(const float* __restrict__ x, u16* __restrict__ xb, long n4) {
    long id = (long)blockIdx.x * 256 + threadIdx.x;
    if (id >= n4) return;
    float4v v = *(const float4v*)&x[id * 4];
    ushort4v o;
    o[0] = f2bf(v[0]); o[1] = f2bf(v[1]); o[2] = f2bf(v[2]); o[3] = f2bf(v[3]);
    *(ushort4v*)&xb[id * 4] = o;
}

// ---------------- transpose+cast weight: W (K x N) f32 -> Wt (N x K) bf16 ----------------
__global__ __launch_bounds__(256) void twt_k(const float* __restrict__ W, u16* __restrict__ Wt, int K, int N) {
    __shared__ float tile[32][33];
    int tx = threadIdx.x, ty = threadIdx.y;
    long n0 = (long)blockIdx.x * 32, k0 = (long)blockIdx.y * 32;
#pragma unroll
    for (int j = 0; j < 4; j++)
        tile[ty + j * 8][tx] = W[(k0 + ty + j * 8) * (long)N + n0 + tx];
    __syncthreads();
#pragma unroll
    for (int j = 0; j < 4; j++)
        Wt[(n0 + ty + j * 8) * (long)K + k0 + tx] = f2bf(tile[tx][ty + j * 8]);
}

// ---------------- transpose v (from fused qkv, stride 3072, col 2560) -> vt (b,kv,d,t) ----------------
__global__ __launch_bounds__(256) void tv_k(const u16* __restrict__ qkv, u16* __restrict__ vt) {
    __shared__ u16 tile[32][33];
    int tx = threadIdx.x, ty = threadIdx.y;
    int d0 = blockIdx.x * 32;
    int t0 = blockIdx.y * 32;
    int bk = blockIdx.z;
    int b = bk >> 2, kv = bk & 3;
#pragma unroll
    for (int j = 0; j < 4; j++)
        tile[ty + j * 8][tx] = qkv[(long)(b * Tt + t0 + ty + j * 8) * NQKV + 2560 + kv * Dd + d0 + tx];
    __syncthreads();
#pragma unroll
    for (int j = 0; j < 4; j++)
        vt[((long)(b * KVh + kv) * Dd + d0 + ty + j * 8) * Tt + t0 + tx] = tile[tx][ty + j * 8];
}

// ---------------- rope tables: [t][i], i<64 ----------------
__global__ __launch_bounds__(256) void tables_k(float* __restrict__ cosb, float* __restrict__ sinb) {
    int id = blockIdx.x * 256 + threadIdx.x; // < 2048*64
    int t = id >> 6, i = id & 63;
    float inv = powf(10000.0f, -(float)i * (1.0f / 64.0f));
    float f = (float)t * inv;
    cosb[id] = cosf(f);
    sinb[id] = sinf(f);
}

// ---------------- rope in-place on fused layout; scale folded for q ----------------
__global__ __launch_bounds__(256) void rope_k(u16* __restrict__ p, const float* __restrict__ cosb,
                                              const float* __restrict__ sinb, int nh, float scale, int total,
                                              long rowstride, int colbase) {
    int id = blockIdx.x * 256 + threadIdx.x;
    if (id >= total) return;
    int i = id & 63;
    int bth = id >> 6;
    int row = bth / nh;
    int t = row % Tt;
    u16* ptr = p + (long)row * rowstride + colbase + (bth % nh) * Dd;
    float x1 = bf2f(ptr[i]), x2 = bf2f(ptr[i + 64]);
    float c = cosb[t * 64 + i], s = sinb[t * 64 + i];
    ptr[i] = f2bf((x1 * c - x2 * s) * scale);
    ptr[i + 64] = f2bf((x2 * c + x1 * s) * scale);
}

// ---------------- GEMM v2: 128x128 tile, 3-buffer depth-2 prefetch, counted vmcnt ----------------
// Stage of tile kt+2 issued at iteration kt top; end-of-iteration waits ONLY tile kt+1's loads
// (s_waitcnt vmcnt(4)) + raw s_barrier -- tile kt+2's loads stay in flight across the barrier.
// Hazards: stage(kt+2) writes buf[(kt+2)%3], last read in iter kt-1 (reads drained pre-barrier);
// reads of buf fenced by vmcnt+barrier with asm memory clobber.
template <int F32OUT>
__global__ __launch_bounds__(256) void gemm_k(const u16* __restrict__ A, const u16* __restrict__ Bt,
                                              void* __restrict__ Cout, int M, int N, int K) {
    __shared__ u16 lds[3][8192];   // [buf][ A 128x32 | B 128x32 ]
    const int tid = threadIdx.x;
    const int lane = tid & 63;
    const int wid = __builtin_amdgcn_readfirstlane(tid >> 6);
    const long m0 = (long)blockIdx.x * 128;
    const long n0 = (long)blockIdx.y * 128;
    const int wr = wid >> 1, wc = wid & 1;
    const int r0 = wid * 32;
    const int lrow = lane >> 2;
    const int lkb = (lane & 3) * 8;
    const u16* gA = A + (m0 + r0 + lrow) * (long)K + lkb;
    const u16* gB = Bt + (n0 + r0 + lrow) * (long)K + lkb;
    f32x4 acc[4][4] = {};
    const int fr = lane & 15, fk = (lane >> 4) * 8;
    const int NT = K >> 5;

    auto stage = [&](int t) {
        u16* lA = &lds[t % 3][r0 * 32];
        u16* lB = &lds[t % 3][4096 + r0 * 32];
        const long ko = (long)t * 32;
        gload16(gA + ko, lA);
        gload16(gA + ko + 16 * (long)K, lA + 16 * 32);
        gload16(gB + ko, lB);
        gload16(gB + ko + 16 * (long)K, lB + 16 * 32);
    };

    stage(0);
    if (NT > 1) {
        stage(1);
        asm volatile("s_waitcnt vmcnt(4)" ::: "memory");
    } else {
        asm volatile("s_waitcnt vmcnt(0)" ::: "memory");
    }
    __builtin_amdgcn_s_barrier();

    for (int kt = 0; kt < NT; ++kt) {
        if (kt + 2 < NT) stage(kt + 2);
        const u16* bufA = &lds[kt % 3][0];
        const u16* bufB = &lds[kt % 3][4096];
        bf16x8 af[4], bfr[4];
#pragma unroll
        for (int i = 0; i < 4; i++) {
            af[i] = *(const bf16x8*)&bufA[(wr * 64 + i * 16 + fr) * 32 + fk];
            bfr[i] = *(const bf16x8*)&bufB[(wc * 64 + i * 16 + fr) * 32 + fk];
        }
        __builtin_amdgcn_s_setprio(1);
#pragma unroll
        for (int i = 0; i < 4; i++)
#pragma unroll
            for (int j = 0; j < 4; j++)
                acc[i][j] = __builtin_amdgcn_mfma_f32_16x16x32_bf16(af[i], bfr[j], acc[i][j], 0, 0, 0);
        __builtin_amdgcn_s_setprio(0);
        if (kt + 2 < NT)
            asm volatile("s_waitcnt vmcnt(4)" ::: "memory");
        else if (kt + 1 < NT)
            asm volatile("s_waitcnt vmcnt(0)" ::: "memory");
        __builtin_amdgcn_s_barrier();
    }
    const int orow = (lane >> 4) * 4, ocol = lane & 15;
#pragma unroll
    for (int i = 0; i < 4; i++)
#pragma unroll
        for (int j = 0; j < 4; j++) {
            long r = m0 + wr * 64 + i * 16 + orow;
            long c = n0 + wc * 64 + j * 16 + ocol;
#pragma unroll
            for (int t = 0; t < 4; t++) {
                if (F32OUT)
                    ((float*)Cout)[(r + t) * N + c] = acc[i][j][t];
                else
                    ((u16*)Cout)[(r + t) * N + c] = f2bf(acc[i][j][t]);
            }
        }
}

// ---------------- flash attention v10: pair-balanced, fused-qkv, KVBLK=64 ----------------
// KVBLK=64 built as TWO verbatim 32-sub-tiles (layouts/bank math identical to verified v7):
// halves barriers and stage calls per k-element. QK/mask/softmax over 4 kf = verified v5 code.
// PV per (qi, sub-tile s): pT slice write (kf=2s,2s+1) -> b128 read -> 8 MFMA with vl[cur][s].
__global__ __launch_bounds__(256, 2) void attn_k(const u16* __restrict__ qkv,
                                                 const u16* __restrict__ vt, u16* __restrict__ o) {
    __shared__ u16 kl[2][2][4096];
    __shared__ u16 vl[2][2][4096];
    __shared__ u16 pT[4][16][36];
    const int tid = threadIdx.x;
    const int lane = tid & 63;
    const int w = tid >> 6;
    const int kv = blockIdx.y, b = blockIdx.z;
    const int h = kv * 4 + w;
    const int fr = lane & 15, kg = lane >> 4;
    const long HD = (long)Hh * Dd;               // output row stride (2048)
    const long QS = (long)NQKV;                  // fused row stride (3072)
    const long kbase = (long)b * Tt * QS + 2048 + (long)kv * Dd;
    const long vbase = ((long)(b * KVh + kv)) * (long)Dd * Tt;

    auto stage = [&](int bb, int it) {
        const int s0 = it * 64;
        const int lh = lane >> 4;     // 0..3
#pragma unroll
        for (int s = 0; s < 2; s++) {
#pragma unroll
            for (int j = 0; j < 2; j++) { // K sub-tile s: 8 chunks of 1KB, chunk c = j*4+w
                int c = j * 4 + w;
                int row = c * 4 + lh;
                int c16 = (lane & 15) ^ (row & 7);
                gload16(qkv + kbase + (long)(s0 + s * 32 + row) * QS + c16 * 8, &kl[bb][s][c * 512]);
            }
#pragma unroll
            for (int j = 0; j < 2; j++) { // V sub-tile s: 8 chunks of 1KB
                int c = j * 4 + w;
                int rowp = c * 4 + lh;
                int c16u = (lane & 15) ^ (rowp & 7);
                int r = rowp * 4 + (c16u >> 2);
                gload16(vt + vbase + (long)r * Tt + s0 + s * 32 + (c16u & 3) * 8, &vl[bb][s][c * 512]);
            }
        }
    };

    for (int pass = 0; pass < 2; ++pass) {
        const int qt = pass ? (int)blockIdx.x : 63 - (int)blockIdx.x;
        const int q0 = qt * 32;
        const long qbase = (long)(b * Tt + q0) * QS + (long)h * Dd;
        const long obase = (long)(b * Tt + q0) * HD + (long)h * Dd;

        bf16x8 qa[2][4];
#pragma unroll
        for (int qi = 0; qi < 2; qi++)
#pragma unroll
            for (int kc = 0; kc < 4; kc++)
                qa[qi][kc] = *(const bf16x8*)&qkv[qbase + (long)(qi * 16 + fr) * QS + kc * 32 + kg * 8];

        f32x4 ot[8][2] = {};          // O^T accumulator: [df][qi]
        float mr0 = -1e30f, mr1 = -1e30f, lr0 = 0.0f, lr1 = 0.0f;
        const int nt = (qt + 2) >> 1; // 64-row k-tiles covering [0, q0+32)

        stage(0, 0);
        __syncthreads();
        int cur = 0;
        for (int it = 0; it < nt; ++it) {
            if (it + 1 < nt) stage(cur ^ 1, it + 1);
            const int s0 = it * 64;
            // ---- S^T = K * Q^T, 4 kf halves from swizzled kl sub-tiles ----
            f32x4 st[4][2] = {};      // [kf][qi]
            __builtin_amdgcn_s_setprio(1);
#pragma unroll
            for (int kf = 0; kf < 4; kf++) {
                const int s = kf >> 1;
                const int rr = (kf & 1) * 16 + fr;
                bf16x8 ka[4];
#pragma unroll
                for (int kc = 0; kc < 4; kc++)
                    ka[kc] = *(const bf16x8*)&kl[cur][s][rr * 128 + (((kc * 4 + kg) ^ (rr & 7)) * 8)];
#pragma unroll
                for (int kc = 0; kc < 4; kc++) {
                    st[kf][0] = __builtin_amdgcn_mfma_f32_16x16x32_bf16(ka[kc], qa[0][kc], st[kf][0], 0, 0, 0);
                    st[kf][1] = __builtin_amdgcn_mfma_f32_16x16x32_bf16(ka[kc], qa[1][kc], st[kf][1], 0, 0, 0);
                }
            }
            __builtin_amdgcn_s_setprio(0);
            // ---- causal mask (diagonal tile only; also kills the pad half on even qt) ----
            if (it == nt - 1) {
#pragma unroll
                for (int kf = 0; kf < 4; kf++)
#pragma unroll
                    for (int qi = 0; qi < 2; qi++) {
                        const int qq = q0 + qi * 16 + fr;
                        const int kb0 = s0 + kf * 16 + kg * 4;
#pragma unroll
                        for (int r = 0; r < 4; r++)
                            if (kb0 + r > qq) st[kf][qi][r] = -1e30f;
                    }
            }
            // ---- in-register online softmax (base-2 domain) ----
            float tm0 = st[0][0][0], tm1 = st[0][1][0];
#pragma unroll
            for (int kf = 0; kf < 4; kf++)
#pragma unroll
                for (int r = 0; r < 4; r++)
                    if (kf | r) {
                        tm0 = fmaxf(tm0, st[kf][0][r]);
                        tm1 = fmaxf(tm1, st[kf][1][r]);
                    }
            tm0 = fmaxf(tm0, __shfl_xor(tm0, 16)); tm0 = fmaxf(tm0, __shfl_xor(tm0, 32));
            tm1 = fmaxf(tm1, __shfl_xor(tm1, 16)); tm1 = fmaxf(tm1, __shfl_xor(tm1, 32));
            if (__any(fmaxf(tm0 - mr0, tm1 - mr1) > 8.0f)) {
                float mn0 = fmaxf(mr0, tm0), mn1 = fmaxf(mr1, tm1);
                float al0 = __builtin_amdgcn_exp2f(mr0 - mn0);
                float al1 = __builtin_amdgcn_exp2f(mr1 - mn1);
                mr0 = mn0; mr1 = mn1;
                lr0 *= al0; lr1 *= al1;
#pragma unroll
                for (int df = 0; df < 8; df++) { ot[df][0] *= al0; ot[df][1] *= al1; }
            }
            float rs0 = 0.0f, rs1 = 0.0f;
#pragma unroll
            for (int kf = 0; kf < 4; kf++)
#pragma unroll
                for (int r = 0; r < 4; r++) {
                    st[kf][0][r] = __builtin_amdgcn_exp2f(st[kf][0][r] - mr0); rs0 += st[kf][0][r];
                    st[kf][1][r] = __builtin_amdgcn_exp2f(st[kf][1][r] - mr1); rs1 += st[kf][1][r];
                }
            rs0 += __shfl_xor(rs0, 16); rs0 += __shfl_xor(rs0, 32);
            rs1 += __shfl_xor(rs1, 16); rs1 += __shfl_xor(rs1, 32);
            lr0 += rs0; lr1 += rs1;
            // ---- P^T via per-wave LDS per (qi, sub-tile); O^T += V^T * P ----
#pragma unroll
            for (int qi = 0; qi < 2; qi++)
#pragma unroll
                for (int s = 0; s < 2; s++) {
                    uint2v w0;
                    w0[0] = cvtpk(st[2 * s][qi][0], st[2 * s][qi][1]);
                    w0[1] = cvtpk(st[2 * s][qi][2], st[2 * s][qi][3]);
                    *(uint2v*)&pT[w][fr][kg * 4] = w0;
                    uint2v w1;
                    w1[0] = cvtpk(st[2 * s + 1][qi][0], st[2 * s + 1][qi][1]);
                    w1[1] = cvtpk(st[2 * s + 1][qi][2], st[2 * s + 1][qi][3]);
                    *(uint2v*)&pT[w][fr][16 + kg * 4] = w1;
                    bf16x8 bq = *(const bf16x8*)&pT[w][fr][kg * 8];
                    __builtin_amdgcn_s_setprio(1);
#pragma unroll
                    for (int df = 0; df < 8; df++) {
                        const int r = df * 16 + fr;
                        const int rowp = r >> 2;
                        const int c16 = (((r & 3) * 4 + kg) ^ (rowp & 7));
                        bf16x8 va = *(const bf16x8*)&vl[cur][s][rowp * 128 + c16 * 8];
                        ot[df][qi] = __builtin_amdgcn_mfma_f32_16x16x32_bf16(va, bq, ot[df][qi], 0, 0, 0);
                    }
                    __builtin_amdgcn_s_setprio(0);
                }
            __syncthreads();
            cur ^= 1;
        }
        // ---- store: lane holds 4 consecutive d (row) for q (col) = qi*16+fr ----
        const float il0 = 1.0f / lr0, il1 = 1.0f / lr1;
#pragma unroll
        for (int df = 0; df < 8; df++) {
            uint2v w0, w1;
            w0[0] = cvtpk(ot[df][0][0] * il0, ot[df][0][1] * il0);
            w0[1] = cvtpk(ot[df][0][2] * il0, ot[df][0][3] * il0);
            w1[0] = cvtpk(ot[df][1][0] * il1, ot[df][1][1] * il1);
            w1[1] = cvtpk(ot[df][1][2] * il1, ot[df][1][3] * il1);
            *(uint2v*)&o[obase + (long)(fr) * HD + df * 16 + kg * 4] = w0;
            *(uint2v*)&o[obase + (long)(16 + fr) * HD + df * 16 + kg * 4] = w1;
        }
    }
}

extern "C" void kernel_launch(void* const* d_in, const int* in_sizes, int n_in,
                              void* d_out, int out_size, void* d_ws, size_t ws_size,
                              hipStream_t stream) {
    (void)in_sizes; (void)n_in; (void)out_size; (void)ws_size;
    const float* x = (const float*)d_in[0];
    const float* Wq = (const float*)d_in[1];
    const float* Wk = (const float*)d_in[2];
    const float* Wv = (const float*)d_in[3];
    const float* Wo = (const float*)d_in[4];

    char* ws = (char*)d_ws;
    u16* xb   = (u16*)(ws + 0);            // 33.5MB  (b,t,c) bf16; later reused as attn output (b,t,h,d)
    u16* vtb  = (u16*)(ws + 50331648);     // 8.4MB   (b,kv,d,t)
    u16* wqt  = (u16*)(ws + 58720256);     // 8.4MB   (first part of fused Wt, 3072 x 2048)
    u16* wkt  = (u16*)(ws + 67108864);     // 2.1MB   (contiguous after wqt)
    u16* wvt  = (u16*)(ws + 69206016);     // 2.1MB   (contiguous after wkt)
    u16* wot  = (u16*)(ws + 71303168);     // 8.4MB
    float* cosb = (float*)(ws + 79691776); // 0.5MB
    float* sinb = (float*)(ws + 80216064); // 0.5MB
    u16* qkv = (u16*)d_out;                // fused qkv (8192 x 3072) bf16 lives in d_out until final GEMM

    dim3 tb(32, 8);
    cast_k<<<16384, 256, 0, stream>>>(x, xb, 4194304);
    twt_k<<<dim3(64, 64), tb, 0, stream>>>(Wq, wqt, 2048, 2048);
    twt_k<<<dim3(16, 64), tb, 0, stream>>>(Wk, wkt, 2048, 512);
    twt_k<<<dim3(16, 64), tb, 0, stream>>>(Wv, wvt, 2048, 512);
    twt_k<<<dim3(64, 64), tb, 0, stream>>>(Wo, wot, 2048, 2048);
    tables_k<<<512, 256, 0, stream>>>(cosb, sinb);

    // fused QKV projection: one GEMM, N = 2048+512+512
    gemm_k<0><<<dim3(64, 24), 256, 0, stream>>>(xb, wqt, qkv, 8192, NQKV, 2048);

    // q scale = (1/sqrt(128)) * log2(e) -> softmax runs in exp2 domain
    rope_k<<<32768, 256, 0, stream>>>(qkv, cosb, sinb, 16, 0.1275174316f, 8388608, NQKV, 0);
    rope_k<<<8192, 256, 0, stream>>>(qkv, cosb, sinb, 4, 1.0f, 2097152, NQKV, 2048);
    tv_k<<<dim3(4, 64, 16), tb, 0, stream>>>(qkv, vtb);

    attn_k<<<dim3(32, 4, 4), 256, 0, stream>>>(qkv, vtb, xb);

    gemm_k<1><<<dim3(64, 16), 256, 0, stream>>>(xb, wot, d_out, 8192, 2048, 2048);
}

// Round 13
// 364.773 us; speedup vs baseline: 2.0968x; 1.0223x over previous
//
#include <hip/hip_runtime.h>
#include <cstdint>

#define DEV __device__ __forceinline__

typedef __attribute__((ext_vector_type(4))) float f32x4;
typedef __attribute__((ext_vector_type(4))) float float4v;
typedef __attribute__((ext_vector_type(8))) short bf16x8;
typedef __attribute__((ext_vector_type(4))) unsigned short ushort4v;
typedef __attribute__((ext_vector_type(2))) unsigned int uint2v;
typedef unsigned short u16;

static constexpr int Bb = 4, Tt = 2048, Hh = 16, KVh = 4, Dd = 128;
static constexpr int NQKV = 3072;   // fused projection width: 2048 q + 512 k + 512 v

DEV u16 f2bf(float x) {
    union { float f; unsigned u; } v; v.f = x;
    unsigned r = v.u + 0x7FFF + ((v.u >> 16) & 1);
    return (u16)(r >> 16);
}
DEV float bf2f(u16 b) {
    union { unsigned u; float f; } v; v.u = ((unsigned)b) << 16;
    return v.f;
}
DEV unsigned cvtpk(float lo, float hi) {
    unsigned d;
    asm("v_cvt_pk_bf16_f32 %0, %1, %2" : "=v"(d) : "v"(lo), "v"(hi));
    return d;
}

typedef const void __attribute__((address_space(1)))* gas1;
typedef void __attribute__((address_space(3)))* las3;
DEV void gload16(const void* g, void* l) {
    __builtin_amdgcn_global_load_lds((gas1)g, (las3)l, 16, 0, 0);
}

// ---------------- cast x -> bf16 ----------------
__global__ __launch_bounds__(256) void cast_k(const float* __restrict__ x, u16* __restrict__ xb, long n4) {
    long id = (long)blockIdx.x * 256 + threadIdx.x;
    if (id >= n4) return;
    float4v v = *(const float4v*)&x[id * 4];
    ushort4v o;
    o[0] = f2bf(v[0]); o[1] = f2bf(v[1]); o[2] = f2bf(v[2]); o[3] = f2bf(v[3]);
    *(ushort4v*)&xb[id * 4] = o;
}

// ---------------- transpose+cast weight: W (K x N) f32 -> Wt (N x K) bf16 ----------------
__global__ __launch_bounds__(256) void twt_k(const float* __restrict__ W, u16* __restrict__ Wt, int K, int N) {
    __shared__ float tile[32][33];
    int tx = threadIdx.x, ty = threadIdx.y;
    long n0 = (long)blockIdx.x * 32, k0 = (long)blockIdx.y * 32;
#pragma unroll
    for (int j = 0; j < 4; j++)
        tile[ty + j * 8][tx] = W[(k0 + ty + j * 8) * (long)N + n0 + tx];
    __syncthreads();
#pragma unroll
    for (int j = 0; j < 4; j++)
        Wt[(n0 + ty + j * 8) * (long)K + k0 + tx] = f2bf(tile[tx][ty + j * 8]);
}

// ---------------- transpose v (from fused qkv, stride 3072, col 2560) -> vt (b,kv,d,t) ----------------
__global__ __launch_bounds__(256) void tv_k(const u16* __restrict__ qkv, u16* __restrict__ vt) {
    __shared__ u16 tile[32][33];
    int tx = threadIdx.x, ty = threadIdx.y;
    int d0 = blockIdx.x * 32;
    int t0 = blockIdx.y * 32;
    int bk = blockIdx.z;
    int b = bk >> 2, kv = bk & 3;
#pragma unroll
    for (int j = 0; j < 4; j++)
        tile[ty + j * 8][tx] = qkv[(long)(b * Tt + t0 + ty + j * 8) * NQKV + 2560 + kv * Dd + d0 + tx];
    __syncthreads();
#pragma unroll
    for (int j = 0; j < 4; j++)
        vt[((long)(b * KVh + kv) * Dd + d0 + ty + j * 8) * Tt + t0 + tx] = tile[tx][ty + j * 8];
}

// ---------------- rope tables: [t][i], i<64 ----------------
__global__ __launch_bounds__(256) void tables_k(float* __restrict__ cosb, float* __restrict__ sinb) {
    int id = blockIdx.x * 256 + threadIdx.x; // < 2048*64
    int t = id >> 6, i = id & 63;
    float inv = powf(10000.0f, -(float)i * (1.0f / 64.0f));
    float f = (float)t * inv;
    cosb[id] = cosf(f);
    sinb[id] = sinf(f);
}

// ---------------- rope in-place on fused layout; scale folded for q ----------------
__global__ __launch_bounds__(256) void rope_k(u16* __restrict__ p, const float* __restrict__ cosb,
                                              const float* __restrict__ sinb, int nh, float scale, int total,
                                              long rowstride, int colbase) {
    int id = blockIdx.x * 256 + threadIdx.x;
    if (id >= total) return;
    int i = id & 63;
    int bth = id >> 6;
    int row = bth / nh;
    int t = row % Tt;
    u16* ptr = p + (long)row * rowstride + colbase + (bth % nh) * Dd;
    float x1 = bf2f(ptr[i]), x2 = bf2f(ptr[i + 64]);
    float c = cosb[t * 64 + i], s = sinb[t * 64 + i];
    ptr[i] = f2bf((x1 * c - x2 * s) * scale);
    ptr[i + 64] = f2bf((x2 * c + x1 * s) * scale);
}

// ---------------- GEMM v3: 256x128 tile, 8 waves (4Mx2N), BK=64, 3-slot ring, swizzled LDS ----------------
// T2: tiles stored [rows][64] bf16 (128B rows = 8 slots of 16B), phys_slot = logical ^ (row&7)
//     -> fragment b128 reads spread 16 lanes over all 32 banks (2-way, free per m136).
//     Staged via LINEAR gload_lds dest + inverse-swizzled global source (m173 pattern).
// T4: stage tile t+2 while computing t; vmcnt(6) at iter end retires exactly tile t+1's 6 loads
//     (per-wave FIFO: outstanding = t+1's 6 + t+2's 6). Loads stay in flight across the barrier.
// WAR: slot (t+2)%3 last read in iter t-1, one barrier apart (same discipline as prior kernel).
template <int F32OUT>
__global__ __launch_bounds__(512) void gemm_k(const u16* __restrict__ A, const u16* __restrict__ Bt,
                                              void* __restrict__ Cout, int M, int N, int K) {
    __shared__ u16 lds[3][24576];   // per slot: A 256x64 (16384 u16) | B 128x64 (8192 u16)
    const int tid = threadIdx.x;
    const int lane = tid & 63;
    const int w = __builtin_amdgcn_readfirstlane(tid >> 6);   // 0..7
    const int wm = w >> 1, wn = w & 1;
    const long m0 = (long)blockIdx.x * 256;
    const long n0 = (long)blockIdx.y * 128;
    const int NT = K >> 6;
    const int l8 = lane >> 3, s8 = lane & 7;
    const int fr = lane & 15, kg = lane >> 4;   // kg 0..3

    auto stage = [&](int t) {
        u16* base = lds[t % 3];
        const long ko = (long)t * 64;
#pragma unroll
        for (int c4 = 0; c4 < 4; c4++) {       // A: 4 chunks of 1KB (8 rows each)
            int c = w * 4 + c4;
            int row = c * 8 + l8;
            int slog = s8 ^ (l8 & 7);
            gload16(A + (m0 + row) * (long)K + ko + slog * 8, base + c * 512);
        }
#pragma unroll
        for (int c2 = 0; c2 < 2; c2++) {       // B: 2 chunks
            int c = w * 2 + c2;
            int row = c * 8 + l8;
            int slog = s8 ^ (l8 & 7);
            gload16(Bt + (n0 + row) * (long)K + ko + slog * 8, base + 16384 + c * 512);
        }
    };

    f32x4 acc[4][4] = {};
    stage(0);
    if (NT > 1) {
        stage(1);
        asm volatile("s_waitcnt vmcnt(6)" ::: "memory");
    } else {
        asm volatile("s_waitcnt vmcnt(0)" ::: "memory");
    }
    __builtin_amdgcn_s_barrier();

    for (int t = 0; t < NT; ++t) {
        if (t + 2 < NT) stage(t + 2);
        const u16* sa = lds[t % 3];
        const u16* sb = sa + 16384;
#pragma unroll
        for (int ks = 0; ks < 2; ks++) {
            bf16x8 af[4], bfr[4];
#pragma unroll
            for (int i = 0; i < 4; i++) {
                const int row = wm * 64 + i * 16 + fr;
                af[i] = *(const bf16x8*)&sa[row * 64 + (((ks * 4 + kg) ^ (row & 7)) * 8)];
                const int col = wn * 64 + i * 16 + fr;
                bfr[i] = *(const bf16x8*)&sb[col * 64 + (((ks * 4 + kg) ^ (col & 7)) * 8)];
            }
            __builtin_amdgcn_s_setprio(1);
#pragma unroll
            for (int i = 0; i < 4; i++)
#pragma unroll
                for (int j = 0; j < 4; j++)
                    acc[i][j] = __builtin_amdgcn_mfma_f32_16x16x32_bf16(af[i], bfr[j], acc[i][j], 0, 0, 0);
            __builtin_amdgcn_s_setprio(0);
        }
        if (t + 2 < NT)
            asm volatile("s_waitcnt vmcnt(6)" ::: "memory");
        else if (t + 1 < NT)
            asm volatile("s_waitcnt vmcnt(0)" ::: "memory");
        __builtin_amdgcn_s_barrier();
    }

    const int orow = (lane >> 4) * 4, ocol = lane & 15;
#pragma unroll
    for (int i = 0; i < 4; i++)
#pragma unroll
        for (int j = 0; j < 4; j++) {
            long r = m0 + wm * 64 + i * 16 + orow;
            long c = n0 + wn * 64 + j * 16 + ocol;
#pragma unroll
            for (int t = 0; t < 4; t++) {
                if (F32OUT)
                    ((float*)Cout)[(r + t) * N + c] = acc[i][j][t];
                else
                    ((u16*)Cout)[(r + t) * N + c] = f2bf(acc[i][j][t]);
            }
        }
}

// ---------------- flash attention v10: pair-balanced, fused-qkv, KVBLK=64 ----------------
__global__ __launch_bounds__(256, 2) void attn_k(const u16* __restrict__ qkv,
                                                 const u16* __restrict__ vt, u16* __restrict__ o) {
    __shared__ u16 kl[2][2][4096];
    __shared__ u16 vl[2][2][4096];
    __shared__ u16 pT[4][16][36];
    const int tid = threadIdx.x;
    const int lane = tid & 63;
    const int w = tid >> 6;
    const int kv = blockIdx.y, b = blockIdx.z;
    const int h = kv * 4 + w;
    const int fr = lane & 15, kg = lane >> 4;
    const long HD = (long)Hh * Dd;               // output row stride (2048)
    const long QS = (long)NQKV;                  // fused row stride (3072)
    const long kbase = (long)b * Tt * QS + 2048 + (long)kv * Dd;
    const long vbase = ((long)(b * KVh + kv)) * (long)Dd * Tt;

    auto stage = [&](int bb, int it) {
        const int s0 = it * 64;
        const int lh = lane >> 4;     // 0..3
#pragma unroll
        for (int s = 0; s < 2; s++) {
#pragma unroll
            for (int j = 0; j < 2; j++) { // K sub-tile s: 8 chunks of 1KB, chunk c = j*4+w
                int c = j * 4 + w;
                int row = c * 4 + lh;
                int c16 = (lane & 15) ^ (row & 7);
                gload16(qkv + kbase + (long)(s0 + s * 32 + row) * QS + c16 * 8, &kl[bb][s][c * 512]);
            }
#pragma unroll
            for (int j = 0; j < 2; j++) { // V sub-tile s: 8 chunks of 1KB
                int c = j * 4 + w;
                int rowp = c * 4 + lh;
                int c16u = (lane & 15) ^ (rowp & 7);
                int r = rowp * 4 + (c16u >> 2);
                gload16(vt + vbase + (long)r * Tt + s0 + s * 32 + (c16u & 3) * 8, &vl[bb][s][c * 512]);
            }
        }
    };

    for (int pass = 0; pass < 2; ++pass) {
        const int qt = pass ? (int)blockIdx.x : 63 - (int)blockIdx.x;
        const int q0 = qt * 32;
        const long qbase = (long)(b * Tt + q0) * QS + (long)h * Dd;
        const long obase = (long)(b * Tt + q0) * HD + (long)h * Dd;

        bf16x8 qa[2][4];
#pragma unroll
        for (int qi = 0; qi < 2; qi++)
#pragma unroll
            for (int kc = 0; kc < 4; kc++)
                qa[qi][kc] = *(const bf16x8*)&qkv[qbase + (long)(qi * 16 + fr) * QS + kc * 32 + kg * 8];

        f32x4 ot[8][2] = {};          // O^T accumulator: [df][qi]
        float mr0 = -1e30f, mr1 = -1e30f, lr0 = 0.0f, lr1 = 0.0f;
        const int nt = (qt + 2) >> 1; // 64-row k-tiles covering [0, q0+32)

        stage(0, 0);
        __syncthreads();
        int cur = 0;
        for (int it = 0; it < nt; ++it) {
            if (it + 1 < nt) stage(cur ^ 1, it + 1);
            const int s0 = it * 64;
            // ---- S^T = K * Q^T, 4 kf halves from swizzled kl sub-tiles ----
            f32x4 st[4][2] = {};      // [kf][qi]
            __builtin_amdgcn_s_setprio(1);
#pragma unroll
            for (int kf = 0; kf < 4; kf++) {
                const int s = kf >> 1;
                const int rr = (kf & 1) * 16 + fr;
                bf16x8 ka[4];
#pragma unroll
                for (int kc = 0; kc < 4; kc++)
                    ka[kc] = *(const bf16x8*)&kl[cur][s][rr * 128 + (((kc * 4 + kg) ^ (rr & 7)) * 8)];
#pragma unroll
                for (int kc = 0; kc < 4; kc++) {
                    st[kf][0] = __builtin_amdgcn_mfma_f32_16x16x32_bf16(ka[kc], qa[0][kc], st[kf][0], 0, 0, 0);
                    st[kf][1] = __builtin_amdgcn_mfma_f32_16x16x32_bf16(ka[kc], qa[1][kc], st[kf][1], 0, 0, 0);
                }
            }
            __builtin_amdgcn_s_setprio(0);
            // ---- causal mask (diagonal tile only; also kills the pad half on even qt) ----
            if (it == nt - 1) {
#pragma unroll
                for (int kf = 0; kf < 4; kf++)
#pragma unroll
                    for (int qi = 0; qi < 2; qi++) {
                        const int qq = q0 + qi * 16 + fr;
                        const int kb0 = s0 + kf * 16 + kg * 4;
#pragma unroll
                        for (int r = 0; r < 4; r++)
                            if (kb0 + r > qq) st[kf][qi][r] = -1e30f;
                    }
            }
            // ---- in-register online softmax (base-2 domain) ----
            float tm0 = st[0][0][0], tm1 = st[0][1][0];
#pragma unroll
            for (int kf = 0; kf < 4; kf++)
#pragma unroll
                for (int r = 0; r < 4; r++)
                    if (kf | r) {
                        tm0 = fmaxf(tm0, st[kf][0][r]);
                        tm1 = fmaxf(tm1, st[kf][1][r]);
                    }
            tm0 = fmaxf(tm0, __shfl_xor(tm0, 16)); tm0 = fmaxf(tm0, __shfl_xor(tm0, 32));
            tm1 = fmaxf(tm1, __shfl_xor(tm1, 16)); tm1 = fmaxf(tm1, __shfl_xor(tm1, 32));
            if (__any(fmaxf(tm0 - mr0, tm1 - mr1) > 8.0f)) {
                float mn0 = fmaxf(mr0, tm0), mn1 = fmaxf(mr1, tm1);
                float al0 = __builtin_amdgcn_exp2f(mr0 - mn0);
                float al1 = __builtin_amdgcn_exp2f(mr1 - mn1);
                mr0 = mn0; mr1 = mn1;
                lr0 *= al0; lr1 *= al1;
#pragma unroll
                for (int df = 0; df < 8; df++) { ot[df][0] *= al0; ot[df][1] *= al1; }
            }
            float rs0 = 0.0f, rs1 = 0.0f;
#pragma unroll
            for (int kf = 0; kf < 4; kf++)
#pragma unroll
                for (int r = 0; r < 4; r++) {
                    st[kf][0][r] = __builtin_amdgcn_exp2f(st[kf][0][r] - mr0); rs0 += st[kf][0][r];
                    st[kf][1][r] = __builtin_amdgcn_exp2f(st[kf][1][r] - mr1); rs1 += st[kf][1][r];
                }
            rs0 += __shfl_xor(rs0, 16); rs0 += __shfl_xor(rs0, 32);
            rs1 += __shfl_xor(rs1, 16); rs1 += __shfl_xor(rs1, 32);
            lr0 += rs0; lr1 += rs1;
            // ---- P^T via per-wave LDS per (qi, sub-tile); O^T += V^T * P ----
#pragma unroll
            for (int qi = 0; qi < 2; qi++)
#pragma unroll
                for (int s = 0; s < 2; s++) {
                    uint2v w0;
                    w0[0] = cvtpk(st[2 * s][qi][0], st[2 * s][qi][1]);
                    w0[1] = cvtpk(st[2 * s][qi][2], st[2 * s][qi][3]);
                    *(uint2v*)&pT[w][fr][kg * 4] = w0;
                    uint2v w1;
                    w1[0] = cvtpk(st[2 * s + 1][qi][0], st[2 * s + 1][qi][1]);
                    w1[1] = cvtpk(st[2 * s + 1][qi][2], st[2 * s + 1][qi][3]);
                    *(uint2v*)&pT[w][fr][16 + kg * 4] = w1;
                    bf16x8 bq = *(const bf16x8*)&pT[w][fr][kg * 8];
                    __builtin_amdgcn_s_setprio(1);
#pragma unroll
                    for (int df = 0; df < 8; df++) {
                        const int r = df * 16 + fr;
                        const int rowp = r >> 2;
                        const int c16 = (((r & 3) * 4 + kg) ^ (rowp & 7));
                        bf16x8 va = *(const bf16x8*)&vl[cur][s][rowp * 128 + c16 * 8];
                        ot[df][qi] = __builtin_amdgcn_mfma_f32_16x16x32_bf16(va, bq, ot[df][qi], 0, 0, 0);
                    }
                    __builtin_amdgcn_s_setprio(0);
                }
            __syncthreads();
            cur ^= 1;
        }
        // ---- store: lane holds 4 consecutive d (row) for q (col) = qi*16+fr ----
        const float il0 = 1.0f / lr0, il1 = 1.0f / lr1;
#pragma unroll
        for (int df = 0; df < 8; df++) {
            uint2v w0, w1;
            w0[0] = cvtpk(ot[df][0][0] * il0, ot[df][0][1] * il0);
            w0[1] = cvtpk(ot[df][0][2] * il0, ot[df][0][3] * il0);
            w1[0] = cvtpk(ot[df][1][0] * il1, ot[df][1][1] * il1);
            w1[1] = cvtpk(ot[df][1][2] * il1, ot[df][1][3] * il1);
            *(uint2v*)&o[obase + (long)(fr) * HD + df * 16 + kg * 4] = w0;
            *(uint2v*)&o[obase + (long)(16 + fr) * HD + df * 16 + kg * 4] = w1;
        }
    }
}

extern "C" void kernel_launch(void* const* d_in, const int* in_sizes, int n_in,
                              void* d_out, int out_size, void* d_ws, size_t ws_size,
                              hipStream_t stream) {
    (void)in_sizes; (void)n_in; (void)out_size; (void)ws_size;
    const float* x = (const float*)d_in[0];
    const float* Wq = (const float*)d_in[1];
    const float* Wk = (const float*)d_in[2];
    const float* Wv = (const float*)d_in[3];
    const float* Wo = (const float*)d_in[4];

    char* ws = (char*)d_ws;
    u16* xb   = (u16*)(ws + 0);            // 33.5MB  (b,t,c) bf16; later reused as attn output (b,t,h,d)
    u16* vtb  = (u16*)(ws + 50331648);     // 8.4MB   (b,kv,d,t)
    u16* wqt  = (u16*)(ws + 58720256);     // 8.4MB   (first part of fused Wt, 3072 x 2048)
    u16* wkt  = (u16*)(ws + 67108864);     // 2.1MB   (contiguous after wqt)
    u16* wvt  = (u16*)(ws + 69206016);     // 2.1MB   (contiguous after wkt)
    u16* wot  = (u16*)(ws + 71303168);     // 8.4MB
    float* cosb = (float*)(ws + 79691776); // 0.5MB
    float* sinb = (float*)(ws + 80216064); // 0.5MB
    u16* qkv = (u16*)d_out;                // fused qkv (8192 x 3072) bf16 lives in d_out until final GEMM

    dim3 tb(32, 8);
    cast_k<<<16384, 256, 0, stream>>>(x, xb, 4194304);
    twt_k<<<dim3(64, 64), tb, 0, stream>>>(Wq, wqt, 2048, 2048);
    twt_k<<<dim3(16, 64), tb, 0, stream>>>(Wk, wkt, 2048, 512);
    twt_k<<<dim3(16, 64), tb, 0, stream>>>(Wv, wvt, 2048, 512);
    twt_k<<<dim3(64, 64), tb, 0, stream>>>(Wo, wot, 2048, 2048);
    tables_k<<<512, 256, 0, stream>>>(cosb, sinb);

    // fused QKV projection: one GEMM, N = 2048+512+512
    gemm_k<0><<<dim3(32, 24), 512, 0, stream>>>(xb, wqt, qkv, 8192, NQKV, 2048);

    // q scale = (1/sqrt(128)) * log2(e) -> softmax runs in exp2 domain
    rope_k<<<32768, 256, 0, stream>>>(qkv, cosb, sinb, 16, 0.1275174316f, 8388608, NQKV, 0);
    rope_k<<<8192, 256, 0, stream>>>(qkv, cosb, sinb, 4, 1.0f, 2097152, NQKV, 2048);
    tv_k<<<dim3(4, 64, 16), tb, 0, stream>>>(qkv, vtb);

    attn_k<<<dim3(32, 4, 4), 256, 0, stream>>>(qkv, vtb, xb);

    gemm_k<1><<<dim3(32, 16), 512, 0, stream>>>(xb, wot, d_out, 8192, 2048, 2048);
}

// Round 14
// 351.526 us; speedup vs baseline: 2.1758x; 1.0377x over previous
//
#include <hip/hip_runtime.h>
#include <cstdint>

#define DEV __device__ __forceinline__

typedef __attribute__((ext_vector_type(4))) float f32x4;
typedef __attribute__((ext_vector_type(4))) float float4v;
typedef __attribute__((ext_vector_type(8))) short bf16x8;
typedef __attribute__((ext_vector_type(4))) unsigned short ushort4v;
typedef __attribute__((ext_vector_type(2))) unsigned int uint2v;
typedef unsigned short u16;

static constexpr int Bb = 4, Tt = 2048, Hh = 16, KVh = 4, Dd = 128;
static constexpr int NQKV = 3072;   // fused projection width: 2048 q + 512 k + 512 v

DEV u16 f2bf(float x) {
    union { float f; unsigned u; } v; v.f = x;
    unsigned r = v.u + 0x7FFF + ((v.u >> 16) & 1);
    return (u16)(r >> 16);
}
DEV float bf2f(u16 b) {
    union { unsigned u; float f; } v; v.u = ((unsigned)b) << 16;
    return v.f;
}
DEV unsigned cvtpk(float lo, float hi) {
    unsigned d;
    asm("v_cvt_pk_bf16_f32 %0, %1, %2" : "=v"(d) : "v"(lo), "v"(hi));
    return d;
}

typedef const void __attribute__((address_space(1)))* gas1;
typedef void __attribute__((address_space(3)))* las3;
DEV void gload16(const void* g, void* l) {
    __builtin_amdgcn_global_load_lds((gas1)g, (las3)l, 16, 0, 0);
}

// ---------------- cast x -> bf16 ----------------
__global__ __launch_bounds__(256) void cast_k(const float* __restrict__ x, u16* __restrict__ xb, long n4) {
    long id = (long)blockIdx.x * 256 + threadIdx.x;
    if (id >= n4) return;
    float4v v = *(const float4v*)&x[id * 4];
    ushort4v o;
    o[0] = f2bf(v[0]); o[1] = f2bf(v[1]); o[2] = f2bf(v[2]); o[3] = f2bf(v[3]);
    *(ushort4v*)&xb[id * 4] = o;
}

// ---------------- transpose+cast weight: W (K x N) f32 -> Wt (N x K) bf16 ----------------
__global__ __launch_bounds__(256) void twt_k(const float* __restrict__ W, u16* __restrict__ Wt, int K, int N) {
    __shared__ float tile[32][33];
    int tx = threadIdx.x, ty = threadIdx.y;
    long n0 = (long)blockIdx.x * 32, k0 = (long)blockIdx.y * 32;
#pragma unroll
    for (int j = 0; j < 4; j++)
        tile[ty + j * 8][tx] = W[(k0 + ty + j * 8) * (long)N + n0 + tx];
    __syncthreads();
#pragma unroll
    for (int j = 0; j < 4; j++)
        Wt[(n0 + ty + j * 8) * (long)K + k0 + tx] = f2bf(tile[tx][ty + j * 8]);
}

// ---------------- transpose v (from fused qkv, stride 3072, col 2560) -> vt (b,kv,d,t) ----------------
__global__ __launch_bounds__(256) void tv_k(const u16* __restrict__ qkv, u16* __restrict__ vt) {
    __shared__ u16 tile[32][33];
    int tx = threadIdx.x, ty = threadIdx.y;
    int d0 = blockIdx.x * 32;
    int t0 = blockIdx.y * 32;
    int bk = blockIdx.z;
    int b = bk >> 2, kv = bk & 3;
#pragma unroll
    for (int j = 0; j < 4; j++)
        tile[ty + j * 8][tx] = qkv[(long)(b * Tt + t0 + ty + j * 8) * NQKV + 2560 + kv * Dd + d0 + tx];
    __syncthreads();
#pragma unroll
    for (int j = 0; j < 4; j++)
        vt[((long)(b * KVh + kv) * Dd + d0 + ty + j * 8) * Tt + t0 + tx] = tile[tx][ty + j * 8];
}

// ---------------- rope tables: [t][i], i<64 ----------------
__global__ __launch_bounds__(256) void tables_k(float* __restrict__ cosb, float* __restrict__ sinb) {
    int id = blockIdx.x * 256 + threadIdx.x; // < 2048*64
    int t = id >> 6, i = id & 63;
    float inv = powf(10000.0f, -(float)i * (1.0f / 64.0f));
    float f = (float)t * inv;
    cosb[id] = cosf(f);
    sinb[id] = sinf(f);
}

// ---------------- rope in-place on fused layout; scale folded for q ----------------
__global__ __launch_bounds__(256) void rope_k(u16* __restrict__ p, const float* __restrict__ cosb,
                                              const float* __restrict__ sinb, int nh, float scale, int total,
                                              long rowstride, int colbase) {
    int id = blockIdx.x * 256 + threadIdx.x;
    if (id >= total) return;
    int i = id & 63;
    int bth = id >> 6;
    int row = bth / nh;
    int t = row % Tt;
    u16* ptr = p + (long)row * rowstride + colbase + (bth % nh) * Dd;
    float x1 = bf2f(ptr[i]), x2 = bf2f(ptr[i + 64]);
    float c = cosb[t * 64 + i], s = sinb[t * 64 + i];
    ptr[i] = f2bf((x1 * c - x2 * s) * scale);
    ptr[i + 64] = f2bf((x2 * c + x1 * s) * scale);
}

// ---------------- GEMM v4: 256x128, 8 waves, BK=64, 3-slot ring, swizzled LDS, 2-phase interleave ----------------
// T2 swizzle: [rows][64] bf16, phys_slot = logical ^ (row&7); staged linear-dest + inverse-swizzled source.
// T4 counted vmcnt(6): tile t+2 staged during iter t; wait retires only t+1's 6 loads.
// T3-lite: iter split into 2 phases {ds_read frags | stage part | barrier | setprio MFMA x16 | barrier}
//          -- race-free by the 3-ring (slot t+2 last read in iter t-1), unlike 2-dbuf 8-phase.
template <int F32OUT>
__global__ __launch_bounds__(512) void gemm_k(const u16* __restrict__ A, const u16* __restrict__ Bt,
                                              void* __restrict__ Cout, int M, int N, int K) {
    __shared__ u16 lds[3][24576];   // per slot: A 256x64 (16384 u16) | B 128x64 (8192 u16)
    const int tid = threadIdx.x;
    const int lane = tid & 63;
    const int w = __builtin_amdgcn_readfirstlane(tid >> 6);   // 0..7
    const int wm = w >> 1, wn = w & 1;
    const long m0 = (long)blockIdx.x * 256;
    const long n0 = (long)blockIdx.y * 128;
    const int NT = K >> 6;
    const int l8 = lane >> 3, s8 = lane & 7;
    const int fr = lane & 15, kg = lane >> 4;   // kg 0..3

    auto stageA = [&](int t) {
        u16* base = lds[t % 3];
        const long ko = (long)t * 64;
#pragma unroll
        for (int c4 = 0; c4 < 4; c4++) {       // A: 4 chunks of 1KB (8 rows each)
            int c = w * 4 + c4;
            int row = c * 8 + l8;
            int slog = s8 ^ (l8 & 7);
            gload16(A + (m0 + row) * (long)K + ko + slog * 8, base + c * 512);
        }
    };
    auto stageB = [&](int t) {
        u16* base = lds[t % 3];
        const long ko = (long)t * 64;
#pragma unroll
        for (int c2 = 0; c2 < 2; c2++) {       // B: 2 chunks
            int c = w * 2 + c2;
            int row = c * 8 + l8;
            int slog = s8 ^ (l8 & 7);
            gload16(Bt + (n0 + row) * (long)K + ko + slog * 8, base + 16384 + c * 512);
        }
    };

    f32x4 acc[4][4] = {};
    stageA(0); stageB(0);
    if (NT > 1) {
        stageA(1); stageB(1);
        asm volatile("s_waitcnt vmcnt(6)" ::: "memory");
    } else {
        asm volatile("s_waitcnt vmcnt(0)" ::: "memory");
    }
    __builtin_amdgcn_s_barrier();

    for (int t = 0; t < NT; ++t) {
        const u16* sa = lds[t % 3];
        const u16* sb = sa + 16384;
        // ---- phase 0 (ks = 0) ----
        {
            bf16x8 af[4], bfr[4];
#pragma unroll
            for (int i = 0; i < 4; i++) {
                const int row = wm * 64 + i * 16 + fr;
                af[i] = *(const bf16x8*)&sa[row * 64 + ((kg ^ (row & 7)) * 8)];
                const int col = wn * 64 + i * 16 + fr;
                bfr[i] = *(const bf16x8*)&sb[col * 64 + ((kg ^ (col & 7)) * 8)];
            }
            if (t + 2 < NT) stageA(t + 2);
            __builtin_amdgcn_s_barrier();
            __builtin_amdgcn_s_setprio(1);
#pragma unroll
            for (int i = 0; i < 4; i++)
#pragma unroll
                for (int j = 0; j < 4; j++)
                    acc[i][j] = __builtin_amdgcn_mfma_f32_16x16x32_bf16(af[i], bfr[j], acc[i][j], 0, 0, 0);
            __builtin_amdgcn_s_setprio(0);
            __builtin_amdgcn_s_barrier();
        }
        // ---- phase 1 (ks = 1) ----
        {
            bf16x8 af[4], bfr[4];
#pragma unroll
            for (int i = 0; i < 4; i++) {
                const int row = wm * 64 + i * 16 + fr;
                af[i] = *(const bf16x8*)&sa[row * 64 + (((4 + kg) ^ (row & 7)) * 8)];
                const int col = wn * 64 + i * 16 + fr;
                bfr[i] = *(const bf16x8*)&sb[col * 64 + (((4 + kg) ^ (col & 7)) * 8)];
            }
            if (t + 2 < NT) stageB(t + 2);
            if (t + 2 < NT)
                asm volatile("s_waitcnt vmcnt(6)" ::: "memory");
            else if (t + 1 < NT)
                asm volatile("s_waitcnt vmcnt(0)" ::: "memory");
            __builtin_amdgcn_s_barrier();
            __builtin_amdgcn_s_setprio(1);
#pragma unroll
            for (int i = 0; i < 4; i++)
#pragma unroll
                for (int j = 0; j < 4; j++)
                    acc[i][j] = __builtin_amdgcn_mfma_f32_16x16x32_bf16(af[i], bfr[j], acc[i][j], 0, 0, 0);
            __builtin_amdgcn_s_setprio(0);
            __builtin_amdgcn_s_barrier();
        }
    }

    const int orow = (lane >> 4) * 4, ocol = lane & 15;
#pragma unroll
    for (int i = 0; i < 4; i++)
#pragma unroll
        for (int j = 0; j < 4; j++) {
            long r = m0 + wm * 64 + i * 16 + orow;
            long c = n0 + wn * 64 + j * 16 + ocol;
#pragma unroll
            for (int t = 0; t < 4; t++) {
                if (F32OUT)
                    ((float*)Cout)[(r + t) * N + c] = acc[i][j][t];
                else
                    ((u16*)Cout)[(r + t) * N + c] = f2bf(acc[i][j][t]);
            }
        }
}

// ---------------- flash attention v11: XCD-grouped grid, pair-balanced, fused-qkv, KVBLK=64 ----------------
// Grid (16, 32): x = kv + 4*b  -> linear id % 8 = x % 8, so ALL 32 pair-blocks sharing one (b,kv)
// K/V panel land on ONE XCD (2 groups/XCD, ~2.5MB K/V+vt fits 4MB L2 -> K/V loads become L2 hits).
// Per-tile math verbatim from verified v10.
__global__ __launch_bounds__(256, 2) void attn_k(const u16* __restrict__ qkv,
                                                 const u16* __restrict__ vt, u16* __restrict__ o) {
    __shared__ u16 kl[2][2][4096];
    __shared__ u16 vl[2][2][4096];
    __shared__ u16 pT[4][16][36];
    const int tid = threadIdx.x;
    const int lane = tid & 63;
    const int w = tid >> 6;
    const int kvb = blockIdx.x;       // kv + 4*b  (XCD group key)
    const int kv = kvb & 3, b = kvb >> 2;
    const int bid = blockIdx.y;       // 0..31 pair index
    const int h = kv * 4 + w;
    const int fr = lane & 15, kg = lane >> 4;
    const long HD = (long)Hh * Dd;               // output row stride (2048)
    const long QS = (long)NQKV;                  // fused row stride (3072)
    const long kbase = (long)b * Tt * QS + 2048 + (long)kv * Dd;
    const long vbase = ((long)(b * KVh + kv)) * (long)Dd * Tt;

    auto stage = [&](int bb, int it) {
        const int s0 = it * 64;
        const int lh = lane >> 4;     // 0..3
#pragma unroll
        for (int s = 0; s < 2; s++) {
#pragma unroll
            for (int j = 0; j < 2; j++) { // K sub-tile s: 8 chunks of 1KB, chunk c = j*4+w
                int c = j * 4 + w;
                int row = c * 4 + lh;
                int c16 = (lane & 15) ^ (row & 7);
                gload16(qkv + kbase + (long)(s0 + s * 32 + row) * QS + c16 * 8, &kl[bb][s][c * 512]);
            }
#pragma unroll
            for (int j = 0; j < 2; j++) { // V sub-tile s: 8 chunks of 1KB
                int c = j * 4 + w;
                int rowp = c * 4 + lh;
                int c16u = (lane & 15) ^ (rowp & 7);
                int r = rowp * 4 + (c16u >> 2);
                gload16(vt + vbase + (long)r * Tt + s0 + s * 32 + (c16u & 3) * 8, &vl[bb][s][c * 512]);
            }
        }
    };

    for (int pass = 0; pass < 2; ++pass) {
        const int qt = pass ? bid : 63 - bid;
        const int q0 = qt * 32;
        const long qbase = (long)(b * Tt + q0) * QS + (long)h * Dd;
        const long obase = (long)(b * Tt + q0) * HD + (long)h * Dd;

        bf16x8 qa[2][4];
#pragma unroll
        for (int qi = 0; qi < 2; qi++)
#pragma unroll
            for (int kc = 0; kc < 4; kc++)
                qa[qi][kc] = *(const bf16x8*)&qkv[qbase + (long)(qi * 16 + fr) * QS + kc * 32 + kg * 8];

        f32x4 ot[8][2] = {};          // O^T accumulator: [df][qi]
        float mr0 = -1e30f, mr1 = -1e30f, lr0 = 0.0f, lr1 = 0.0f;
        const int nt = (qt + 2) >> 1; // 64-row k-tiles covering [0, q0+32)

        stage(0, 0);
        __syncthreads();
        int cur = 0;
        for (int it = 0; it < nt; ++it) {
            if (it + 1 < nt) stage(cur ^ 1, it + 1);
            const int s0 = it * 64;
            // ---- S^T = K * Q^T, 4 kf halves from swizzled kl sub-tiles ----
            f32x4 st[4][2] = {};      // [kf][qi]
            __builtin_amdgcn_s_setprio(1);
#pragma unroll
            for (int kf = 0; kf < 4; kf++) {
                const int s = kf >> 1;
                const int rr = (kf & 1) * 16 + fr;
                bf16x8 ka[4];
#pragma unroll
                for (int kc = 0; kc < 4; kc++)
                    ka[kc] = *(const bf16x8*)&kl[cur][s][rr * 128 + (((kc * 4 + kg) ^ (rr & 7)) * 8)];
#pragma unroll
                for (int kc = 0; kc < 4; kc++) {
                    st[kf][0] = __builtin_amdgcn_mfma_f32_16x16x32_bf16(ka[kc], qa[0][kc], st[kf][0], 0, 0, 0);
                    st[kf][1] = __builtin_amdgcn_mfma_f32_16x16x32_bf16(ka[kc], qa[1][kc], st[kf][1], 0, 0, 0);
                }
            }
            __builtin_amdgcn_s_setprio(0);
            // ---- causal mask (diagonal tile only; also kills the pad half on even qt) ----
            if (it == nt - 1) {
#pragma unroll
                for (int kf = 0; kf < 4; kf++)
#pragma unroll
                    for (int qi = 0; qi < 2; qi++) {
                        const int qq = q0 + qi * 16 + fr;
                        const int kb0 = s0 + kf * 16 + kg * 4;
#pragma unroll
                        for (int r = 0; r < 4; r++)
                            if (kb0 + r > qq) st[kf][qi][r] = -1e30f;
                    }
            }
            // ---- in-register online softmax (base-2 domain) ----
            float tm0 = st[0][0][0], tm1 = st[0][1][0];
#pragma unroll
            for (int kf = 0; kf < 4; kf++)
#pragma unroll
                for (int r = 0; r < 4; r++)
                    if (kf | r) {
                        tm0 = fmaxf(tm0, st[kf][0][r]);
                        tm1 = fmaxf(tm1, st[kf][1][r]);
                    }
            tm0 = fmaxf(tm0, __shfl_xor(tm0, 16)); tm0 = fmaxf(tm0, __shfl_xor(tm0, 32));
            tm1 = fmaxf(tm1, __shfl_xor(tm1, 16)); tm1 = fmaxf(tm1, __shfl_xor(tm1, 32));
            if (__any(fmaxf(tm0 - mr0, tm1 - mr1) > 8.0f)) {
                float mn0 = fmaxf(mr0, tm0), mn1 = fmaxf(mr1, tm1);
                float al0 = __builtin_amdgcn_exp2f(mr0 - mn0);
                float al1 = __builtin_amdgcn_exp2f(mr1 - mn1);
                mr0 = mn0; mr1 = mn1;
                lr0 *= al0; lr1 *= al1;
#pragma unroll
                for (int df = 0; df < 8; df++) { ot[df][0] *= al0; ot[df][1] *= al1; }
            }
            float rs0 = 0.0f, rs1 = 0.0f;
#pragma unroll
            for (int kf = 0; kf < 4; kf++)
#pragma unroll
                for (int r = 0; r < 4; r++) {
                    st[kf][0][r] = __builtin_amdgcn_exp2f(st[kf][0][r] - mr0); rs0 += st[kf][0][r];
                    st[kf][1][r] = __builtin_amdgcn_exp2f(st[kf][1][r] - mr1); rs1 += st[kf][1][r];
                }
            rs0 += __shfl_xor(rs0, 16); rs0 += __shfl_xor(rs0, 32);
            rs1 += __shfl_xor(rs1, 16); rs1 += __shfl_xor(rs1, 32);
            lr0 += rs0; lr1 += rs1;
            // ---- P^T via per-wave LDS per (qi, sub-tile); O^T += V^T * P ----
#pragma unroll
            for (int qi = 0; qi < 2; qi++)
#pragma unroll
                for (int s = 0; s < 2; s++) {
                    uint2v w0;
                    w0[0] = cvtpk(st[2 * s][qi][0], st[2 * s][qi][1]);
                    w0[1] = cvtpk(st[2 * s][qi][2], st[2 * s][qi][3]);
                    *(uint2v*)&pT[w][fr][kg * 4] = w0;
                    uint2v w1;
                    w1[0] = cvtpk(st[2 * s + 1][qi][0], st[2 * s + 1][qi][1]);
                    w1[1] = cvtpk(st[2 * s + 1][qi][2], st[2 * s + 1][qi][3]);
                    *(uint2v*)&pT[w][fr][16 + kg * 4] = w1;
                    bf16x8 bq = *(const bf16x8*)&pT[w][fr][kg * 8];
                    __builtin_amdgcn_s_setprio(1);
#pragma unroll
                    for (int df = 0; df < 8; df++) {
                        const int r = df * 16 + fr;
                        const int rowp = r >> 2;
                        const int c16 = (((r & 3) * 4 + kg) ^ (rowp & 7));
                        bf16x8 va = *(const bf16x8*)&vl[cur][s][rowp * 128 + c16 * 8];
                        ot[df][qi] = __builtin_amdgcn_mfma_f32_16x16x32_bf16(va, bq, ot[df][qi], 0, 0, 0);
                    }
                    __builtin_amdgcn_s_setprio(0);
                }
            __syncthreads();
            cur ^= 1;
        }
        // ---- store: lane holds 4 consecutive d (row) for q (col) = qi*16+fr ----
        const float il0 = 1.0f / lr0, il1 = 1.0f / lr1;
#pragma unroll
        for (int df = 0; df < 8; df++) {
            uint2v w0, w1;
            w0[0] = cvtpk(ot[df][0][0] * il0, ot[df][0][1] * il0);
            w0[1] = cvtpk(ot[df][0][2] * il0, ot[df][0][3] * il0);
            w1[0] = cvtpk(ot[df][1][0] * il1, ot[df][1][1] * il1);
            w1[1] = cvtpk(ot[df][1][2] * il1, ot[df][1][3] * il1);
            *(uint2v*)&o[obase + (long)(fr) * HD + df * 16 + kg * 4] = w0;
            *(uint2v*)&o[obase + (long)(16 + fr) * HD + df * 16 + kg * 4] = w1;
        }
    }
}

extern "C" void kernel_launch(void* const* d_in, const int* in_sizes, int n_in,
                              void* d_out, int out_size, void* d_ws, size_t ws_size,
                              hipStream_t stream) {
    (void)in_sizes; (void)n_in; (void)out_size; (void)ws_size;
    const float* x = (const float*)d_in[0];
    const float* Wq = (const float*)d_in[1];
    const float* Wk = (const float*)d_in[2];
    const float* Wv = (const float*)d_in[3];
    const float* Wo = (const float*)d_in[4];

    char* ws = (char*)d_ws;
    u16* xb   = (u16*)(ws + 0);            // 33.5MB  (b,t,c) bf16; later reused as attn output (b,t,h,d)
    u16* vtb  = (u16*)(ws + 50331648);     // 8.4MB   (b,kv,d,t)
    u16* wqt  = (u16*)(ws + 58720256);     // 8.4MB   (first part of fused Wt, 3072 x 2048)
    u16* wkt  = (u16*)(ws + 67108864);     // 2.1MB   (contiguous after wqt)
    u16* wvt  = (u16*)(ws + 69206016);     // 2.1MB   (contiguous after wkt)
    u16* wot  = (u16*)(ws + 71303168);     // 8.4MB
    float* cosb = (float*)(ws + 79691776); // 0.5MB
    float* sinb = (float*)(ws + 80216064); // 0.5MB
    u16* qkv = (u16*)d_out;                // fused qkv (8192 x 3072) bf16 lives in d_out until final GEMM

    dim3 tb(32, 8);
    cast_k<<<16384, 256, 0, stream>>>(x, xb, 4194304);
    twt_k<<<dim3(64, 64), tb, 0, stream>>>(Wq, wqt, 2048, 2048);
    twt_k<<<dim3(16, 64), tb, 0, stream>>>(Wk, wkt, 2048, 512);
    twt_k<<<dim3(16, 64), tb, 0, stream>>>(Wv, wvt, 2048, 512);
    twt_k<<<dim3(64, 64), tb, 0, stream>>>(Wo, wot, 2048, 2048);
    tables_k<<<512, 256, 0, stream>>>(cosb, sinb);

    // fused QKV projection: one GEMM, N = 2048+512+512
    gemm_k<0><<<dim3(32, 24), 512, 0, stream>>>(xb, wqt, qkv, 8192, NQKV, 2048);

    // q scale = (1/sqrt(128)) * log2(e) -> softmax runs in exp2 domain
    rope_k<<<32768, 256, 0, stream>>>(qkv, cosb, sinb, 16, 0.1275174316f, 8388608, NQKV, 0);
    rope_k<<<8192, 256, 0, stream>>>(qkv, cosb, sinb, 4, 1.0f, 2097152, NQKV, 2048);
    tv_k<<<dim3(4, 64, 16), tb, 0, stream>>>(qkv, vtb);

    attn_k<<<dim3(16, 32), 256, 0, stream>>>(qkv, vtb, xb);

    gemm_k<1><<<dim3(32, 16), 512, 0, stream>>>(xb, wot, d_out, 8192, 2048, 2048);
}

// Round 15
// 344.464 us; speedup vs baseline: 2.2204x; 1.0205x over previous
//
#include <hip/hip_runtime.h>
#include <cstdint>

#define DEV __device__ __forceinline__

typedef __attribute__((ext_vector_type(4))) float f32x4;
typedef __attribute__((ext_vector_type(4))) float float4v;
typedef __attribute__((ext_vector_type(8))) short bf16x8;
typedef __attribute__((ext_vector_type(4))) unsigned short ushort4v;
typedef __attribute__((ext_vector_type(2))) unsigned int uint2v;
typedef unsigned short u16;

static constexpr int Bb = 4, Tt = 2048, Hh = 16, KVh = 4, Dd = 128;
static constexpr int NQKV = 3072;   // fused projection width: 2048 q + 512 k + 512 v

DEV u16 f2bf(float x) {
    union { float f; unsigned u; } v; v.f = x;
    unsigned r = v.u + 0x7FFF + ((v.u >> 16) & 1);
    return (u16)(r >> 16);
}
DEV float bf2f(u16 b) {
    union { unsigned u; float f; } v; v.u = ((unsigned)b) << 16;
    return v.f;
}
DEV unsigned cvtpk(float lo, float hi) {
    unsigned d;
    asm("v_cvt_pk_bf16_f32 %0, %1, %2" : "=v"(d) : "v"(lo), "v"(hi));
    return d;
}

typedef const void __attribute__((address_space(1)))* gas1;
typedef void __attribute__((address_space(3)))* las3;
DEV void gload16(const void* g, void* l) {
    __builtin_amdgcn_global_load_lds((gas1)g, (las3)l, 16, 0, 0);
}

// ---------------- cast x -> bf16 ----------------
__global__ __launch_bounds__(256) void cast_k(const float* __restrict__ x, u16* __restrict__ xb, long n4) {
    long id = (long)blockIdx.x * 256 + threadIdx.x;
    if (id >= n4) return;
    float4v v = *(const float4v*)&x[id * 4];
    ushort4v o;
    o[0] = f2bf(v[0]); o[1] = f2bf(v[1]); o[2] = f2bf(v[2]); o[3] = f2bf(v[3]);
    *(ushort4v*)&xb[id * 4] = o;
}

// ---------------- transpose+cast weight: W (K x N) f32 -> Wt (N x K) bf16 ----------------
__global__ __launch_bounds__(256) void twt_k(const float* __restrict__ W, u16* __restrict__ Wt, int K, int N) {
    __shared__ float tile[32][33];
    int tx = threadIdx.x, ty = threadIdx.y;
    long n0 = (long)blockIdx.x * 32, k0 = (long)blockIdx.y * 32;
#pragma unroll
    for (int j = 0; j < 4; j++)
        tile[ty + j * 8][tx] = W[(k0 + ty + j * 8) * (long)N + n0 + tx];
    __syncthreads();
#pragma unroll
    for (int j = 0; j < 4; j++)
        Wt[(n0 + ty + j * 8) * (long)K + k0 + tx] = f2bf(tile[tx][ty + j * 8]);
}

// ---------------- transpose v (from fused qkv, stride 3072, col 2560) -> vt (b,kv,d,t) ----------------
__global__ __launch_bounds__(256) void tv_k(const u16* __restrict__ qkv, u16* __restrict__ vt) {
    __shared__ u16 tile[32][33];
    int tx = threadIdx.x, ty = threadIdx.y;
    int d0 = blockIdx.x * 32;
    int t0 = blockIdx.y * 32;
    int bk = blockIdx.z;
    int b = bk >> 2, kv = bk & 3;
#pragma unroll
    for (int j = 0; j < 4; j++)
        tile[ty + j * 8][tx] = qkv[(long)(b * Tt + t0 + ty + j * 8) * NQKV + 2560 + kv * Dd + d0 + tx];
    __syncthreads();
#pragma unroll
    for (int j = 0; j < 4; j++)
        vt[((long)(b * KVh + kv) * Dd + d0 + ty + j * 8) * Tt + t0 + tx] = tile[tx][ty + j * 8];
}

// ---------------- rope tables: [t][i], i<64 ----------------
__global__ __launch_bounds__(256) void tables_k(float* __restrict__ cosb, float* __restrict__ sinb) {
    int id = blockIdx.x * 256 + threadIdx.x; // < 2048*64
    int t = id >> 6, i = id & 63;
    float inv = powf(10000.0f, -(float)i * (1.0f / 64.0f));
    float f = (float)t * inv;
    cosb[id] = cosf(f);
    sinb[id] = sinf(f);
}

// ---------------- rope v2: vectorized (8 lanes of rotation pair per thread) ----------------
// thread handles cols [i8*8, i8*8+8) and [64+i8*8, ...) of one (row, head): 16B loads/stores.
__global__ __launch_bounds__(256) void rope_k(u16* __restrict__ p, const float* __restrict__ cosb,
                                              const float* __restrict__ sinb, int nh, float scale, int total8,
                                              long rowstride, int colbase) {
    int id = blockIdx.x * 256 + threadIdx.x;
    if (id >= total8) return;
    int i8 = id & 7;
    int bth = id >> 3;
    int row = bth / nh;
    int t = row % Tt;
    u16* ptr = p + (long)row * rowstride + colbase + (bth % nh) * Dd + i8 * 8;
    ushort4v a0 = *(ushort4v*)&ptr[0];
    ushort4v a1 = *(ushort4v*)&ptr[4];
    ushort4v b0 = *(ushort4v*)&ptr[64];
    ushort4v b1 = *(ushort4v*)&ptr[68];
    const float4v c0 = *(const float4v*)&cosb[t * 64 + i8 * 8];
    const float4v c1 = *(const float4v*)&cosb[t * 64 + i8 * 8 + 4];
    const float4v s0 = *(const float4v*)&sinb[t * 64 + i8 * 8];
    const float4v s1 = *(const float4v*)&sinb[t * 64 + i8 * 8 + 4];
    ushort4v oa0, oa1, ob0, ob1;
#pragma unroll
    for (int j = 0; j < 4; j++) {
        float x1 = bf2f(a0[j]), x2 = bf2f(b0[j]);
        oa0[j] = f2bf((x1 * c0[j] - x2 * s0[j]) * scale);
        ob0[j] = f2bf((x2 * c0[j] + x1 * s0[j]) * scale);
        float y1 = bf2f(a1[j]), y2 = bf2f(b1[j]);
        oa1[j] = f2bf((y1 * c1[j] - y2 * s1[j]) * scale);
        ob1[j] = f2bf((y2 * c1[j] + y1 * s1[j]) * scale);
    }
    *(ushort4v*)&ptr[0] = oa0;
    *(ushort4v*)&ptr[4] = oa1;
    *(ushort4v*)&ptr[64] = ob0;
    *(ushort4v*)&ptr[68] = ob1;
}

// ---------------- GEMM v4: 256x128, 8 waves, BK=64, 3-slot ring, swizzled LDS, 2-phase interleave ----------------
template <int F32OUT>
__global__ __launch_bounds__(512) void gemm_k(const u16* __restrict__ A, const u16* __restrict__ Bt,
                                              void* __restrict__ Cout, int M, int N, int K) {
    __shared__ u16 lds[3][24576];   // per slot: A 256x64 (16384 u16) | B 128x64 (8192 u16)
    const int tid = threadIdx.x;
    const int lane = tid & 63;
    const int w = __builtin_amdgcn_readfirstlane(tid >> 6);   // 0..7
    const int wm = w >> 1, wn = w & 1;
    const long m0 = (long)blockIdx.x * 256;
    const long n0 = (long)blockIdx.y * 128;
    const int NT = K >> 6;
    const int l8 = lane >> 3, s8 = lane & 7;
    const int fr = lane & 15, kg = lane >> 4;   // kg 0..3

    auto stageA = [&](int t) {
        u16* base = lds[t % 3];
        const long ko = (long)t * 64;
#pragma unroll
        for (int c4 = 0; c4 < 4; c4++) {       // A: 4 chunks of 1KB (8 rows each)
            int c = w * 4 + c4;
            int row = c * 8 + l8;
            int slog = s8 ^ (l8 & 7);
            gload16(A + (m0 + row) * (long)K + ko + slog * 8, base + c * 512);
        }
    };
    auto stageB = [&](int t) {
        u16* base = lds[t % 3];
        const long ko = (long)t * 64;
#pragma unroll
        for (int c2 = 0; c2 < 2; c2++) {       // B: 2 chunks
            int c = w * 2 + c2;
            int row = c * 8 + l8;
            int slog = s8 ^ (l8 & 7);
            gload16(Bt + (n0 + row) * (long)K + ko + slog * 8, base + 16384 + c * 512);
        }
    };

    f32x4 acc[4][4] = {};
    stageA(0); stageB(0);
    if (NT > 1) {
        stageA(1); stageB(1);
        asm volatile("s_waitcnt vmcnt(6)" ::: "memory");
    } else {
        asm volatile("s_waitcnt vmcnt(0)" ::: "memory");
    }
    __builtin_amdgcn_s_barrier();

    for (int t = 0; t < NT; ++t) {
        const u16* sa = lds[t % 3];
        const u16* sb = sa + 16384;
        // ---- phase 0 (ks = 0) ----
        {
            bf16x8 af[4], bfr[4];
#pragma unroll
            for (int i = 0; i < 4; i++) {
                const int row = wm * 64 + i * 16 + fr;
                af[i] = *(const bf16x8*)&sa[row * 64 + ((kg ^ (row & 7)) * 8)];
                const int col = wn * 64 + i * 16 + fr;
                bfr[i] = *(const bf16x8*)&sb[col * 64 + ((kg ^ (col & 7)) * 8)];
            }
            if (t + 2 < NT) stageA(t + 2);
            __builtin_amdgcn_s_barrier();
            __builtin_amdgcn_s_setprio(1);
#pragma unroll
            for (int i = 0; i < 4; i++)
#pragma unroll
                for (int j = 0; j < 4; j++)
                    acc[i][j] = __builtin_amdgcn_mfma_f32_16x16x32_bf16(af[i], bfr[j], acc[i][j], 0, 0, 0);
            __builtin_amdgcn_s_setprio(0);
            __builtin_amdgcn_s_barrier();
        }
        // ---- phase 1 (ks = 1) ----
        {
            bf16x8 af[4], bfr[4];
#pragma unroll
            for (int i = 0; i < 4; i++) {
                const int row = wm * 64 + i * 16 + fr;
                af[i] = *(const bf16x8*)&sa[row * 64 + (((4 + kg) ^ (row & 7)) * 8)];
                const int col = wn * 64 + i * 16 + fr;
                bfr[i] = *(const bf16x8*)&sb[col * 64 + (((4 + kg) ^ (col & 7)) * 8)];
            }
            if (t + 2 < NT) stageB(t + 2);
            if (t + 2 < NT)
                asm volatile("s_waitcnt vmcnt(6)" ::: "memory");
            else if (t + 1 < NT)
                asm volatile("s_waitcnt vmcnt(0)" ::: "memory");
            __builtin_amdgcn_s_barrier();
            __builtin_amdgcn_s_setprio(1);
#pragma unroll
            for (int i = 0; i < 4; i++)
#pragma unroll
                for (int j = 0; j < 4; j++)
                    acc[i][j] = __builtin_amdgcn_mfma_f32_16x16x32_bf16(af[i], bfr[j], acc[i][j], 0, 0, 0);
            __builtin_amdgcn_s_setprio(0);
            __builtin_amdgcn_s_barrier();
        }
    }

    const int orow = (lane >> 4) * 4, ocol = lane & 15;
#pragma unroll
    for (int i = 0; i < 4; i++)
#pragma unroll
        for (int j = 0; j < 4; j++) {
            long r = m0 + wm * 64 + i * 16 + orow;
            long c = n0 + wn * 64 + j * 16 + ocol;
#pragma unroll
            for (int t = 0; t < 4; t++) {
                if (F32OUT)
                    ((float*)Cout)[(r + t) * N + c] = acc[i][j][t];
                else
                    ((u16*)Cout)[(r + t) * N + c] = f2bf(acc[i][j][t]);
            }
        }
}

// ---------------- flash attention v12: 1024 single-qt blocks, 3 blocks/CU, va-reuse ----------------
// Grid (16, 64): x = kv + 4*b (XCD key: all blocks sharing a K/V panel land on one XCD's L2),
// y -> qt = 63 - y (heavy blocks dispatch first; dynamic LPT balance at ~4 blocks/CU).
// KVBLK=32 (LDS 41KB -> 3 blocks/CU = 12 waves/CU). Per-tile math verbatim from verified v9,
// except PV: pT carries both qi slices so each V fragment is read ONCE and feeds 2 MFMAs.
__global__ __launch_bounds__(256, 3) void attn_k(const u16* __restrict__ qkv,
                                                 const u16* __restrict__ vt, u16* __restrict__ o) {
    __shared__ u16 kl[2][4096];
    __shared__ u16 vl[2][4096];
    __shared__ u16 pT[4][2][16][36];
    const int tid = threadIdx.x;
    const int lane = tid & 63;
    const int w = tid >> 6;
    const int kvb = blockIdx.x;       // kv + 4*b  (XCD group key)
    const int kv = kvb & 3, b = kvb >> 2;
    const int qt = 63 - (int)blockIdx.y;
    const int q0 = qt * 32;
    const int h = kv * 4 + w;
    const int fr = lane & 15, kg = lane >> 4;
    const long HD = (long)Hh * Dd;               // output row stride (2048)
    const long QS = (long)NQKV;                  // fused row stride (3072)
    const long kbase = (long)b * Tt * QS + 2048 + (long)kv * Dd;
    const long vbase = ((long)(b * KVh + kv)) * (long)Dd * Tt;
    const long qbase = (long)(b * Tt + q0) * QS + (long)h * Dd;
    const long obase = (long)(b * Tt + q0) * HD + (long)h * Dd;

    auto stage = [&](int bb, int it) {
        const int s0 = it * 32;
        const int lh = lane >> 4;     // 0..3
#pragma unroll
        for (int j = 0; j < 2; j++) { // K: 8 chunks of 1KB, chunk c = j*4+w
            int c = j * 4 + w;
            int row = c * 4 + lh;
            int c16 = (lane & 15) ^ (row & 7);
            gload16(qkv + kbase + (long)(s0 + row) * QS + c16 * 8, &kl[bb][c * 512]);
        }
#pragma unroll
        for (int j = 0; j < 2; j++) { // V: 8 chunks of 1KB
            int c = j * 4 + w;
            int rowp = c * 4 + lh;
            int c16u = (lane & 15) ^ (rowp & 7);
            int r = rowp * 4 + (c16u >> 2);
            gload16(vt + vbase + (long)r * Tt + s0 + (c16u & 3) * 8, &vl[bb][c * 512]);
        }
    };

    bf16x8 qa[2][4];
#pragma unroll
    for (int qi = 0; qi < 2; qi++)
#pragma unroll
        for (int kc = 0; kc < 4; kc++)
            qa[qi][kc] = *(const bf16x8*)&qkv[qbase + (long)(qi * 16 + fr) * QS + kc * 32 + kg * 8];

    f32x4 ot[8][2] = {};              // O^T accumulator: [df][qi]
    float mr0 = -1e30f, mr1 = -1e30f, lr0 = 0.0f, lr1 = 0.0f;
    const int nt = qt + 1;

    stage(0, 0);
    __syncthreads();
    int cur = 0;
    for (int it = 0; it < nt; ++it) {
        if (it + 1 < nt) stage(cur ^ 1, it + 1);
        const int s0 = it * 32;
        // ---- S^T = K * Q^T from swizzled kl ----
        f32x4 st[2][2] = {};          // [kf][qi]
        __builtin_amdgcn_s_setprio(1);
#pragma unroll
        for (int kf = 0; kf < 2; kf++) {
            const int rr = kf * 16 + fr;
            bf16x8 ka[4];
#pragma unroll
            for (int kc = 0; kc < 4; kc++)
                ka[kc] = *(const bf16x8*)&kl[cur][rr * 128 + (((kc * 4 + kg) ^ (rr & 7)) * 8)];
#pragma unroll
            for (int kc = 0; kc < 4; kc++) {
                st[kf][0] = __builtin_amdgcn_mfma_f32_16x16x32_bf16(ka[kc], qa[0][kc], st[kf][0], 0, 0, 0);
                st[kf][1] = __builtin_amdgcn_mfma_f32_16x16x32_bf16(ka[kc], qa[1][kc], st[kf][1], 0, 0, 0);
            }
        }
        __builtin_amdgcn_s_setprio(0);
        // ---- causal mask (diagonal tile only) ----
        if (it == nt - 1) {
#pragma unroll
            for (int kf = 0; kf < 2; kf++)
#pragma unroll
                for (int qi = 0; qi < 2; qi++) {
                    const int qq = q0 + qi * 16 + fr;
                    const int kb0 = s0 + kf * 16 + kg * 4;
#pragma unroll
                    for (int r = 0; r < 4; r++)
                        if (kb0 + r > qq) st[kf][qi][r] = -1e30f;
                }
        }
        // ---- in-register online softmax (base-2 domain) ----
        float tm0 = st[0][0][0], tm1 = st[0][1][0];
#pragma unroll
        for (int kf = 0; kf < 2; kf++)
#pragma unroll
            for (int r = 0; r < 4; r++)
                if (kf | r) {
                    tm0 = fmaxf(tm0, st[kf][0][r]);
                    tm1 = fmaxf(tm1, st[kf][1][r]);
                }
        tm0 = fmaxf(tm0, __shfl_xor(tm0, 16)); tm0 = fmaxf(tm0, __shfl_xor(tm0, 32));
        tm1 = fmaxf(tm1, __shfl_xor(tm1, 16)); tm1 = fmaxf(tm1, __shfl_xor(tm1, 32));
        if (__any(fmaxf(tm0 - mr0, tm1 - mr1) > 8.0f)) {
            float mn0 = fmaxf(mr0, tm0), mn1 = fmaxf(mr1, tm1);
            float al0 = __builtin_amdgcn_exp2f(mr0 - mn0);
            float al1 = __builtin_amdgcn_exp2f(mr1 - mn1);
            mr0 = mn0; mr1 = mn1;
            lr0 *= al0; lr1 *= al1;
#pragma unroll
            for (int df = 0; df < 8; df++) { ot[df][0] *= al0; ot[df][1] *= al1; }
        }
        float rs0 = 0.0f, rs1 = 0.0f;
#pragma unroll
        for (int kf = 0; kf < 2; kf++)
#pragma unroll
            for (int r = 0; r < 4; r++) {
                st[kf][0][r] = __builtin_amdgcn_exp2f(st[kf][0][r] - mr0); rs0 += st[kf][0][r];
                st[kf][1][r] = __builtin_amdgcn_exp2f(st[kf][1][r] - mr1); rs1 += st[kf][1][r];
            }
        rs0 += __shfl_xor(rs0, 16); rs0 += __shfl_xor(rs0, 32);
        rs1 += __shfl_xor(rs1, 16); rs1 += __shfl_xor(rs1, 32);
        lr0 += rs0; lr1 += rs1;
        // ---- stage P^T for BOTH qi, then PV with each V fragment read once ----
#pragma unroll
        for (int qi = 0; qi < 2; qi++) {
            uint2v w0;
            w0[0] = cvtpk(st[0][qi][0], st[0][qi][1]);
            w0[1] = cvtpk(st[0][qi][2], st[0][qi][3]);
            *(uint2v*)&pT[w][qi][fr][kg * 4] = w0;
            uint2v w1;
            w1[0] = cvtpk(st[1][qi][0], st[1][qi][1]);
            w1[1] = cvtpk(st[1][qi][2], st[1][qi][3]);
            *(uint2v*)&pT[w][qi][fr][16 + kg * 4] = w1;
        }
        {
            bf16x8 bq0 = *(const bf16x8*)&pT[w][0][fr][kg * 8];
            bf16x8 bq1 = *(const bf16x8*)&pT[w][1][fr][kg * 8];
            __builtin_amdgcn_s_setprio(1);
#pragma unroll
            for (int df = 0; df < 8; df++) {
                const int r = df * 16 + fr;
                const int rowp = r >> 2;
                const int c16 = (((r & 3) * 4 + kg) ^ (rowp & 7));
                bf16x8 va = *(const bf16x8*)&vl[cur][rowp * 128 + c16 * 8];
                ot[df][0] = __builtin_amdgcn_mfma_f32_16x16x32_bf16(va, bq0, ot[df][0], 0, 0, 0);
                ot[df][1] = __builtin_amdgcn_mfma_f32_16x16x32_bf16(va, bq1, ot[df][1], 0, 0, 0);
            }
            __builtin_amdgcn_s_setprio(0);
        }
        __syncthreads();
        cur ^= 1;
    }
    // ---- store: lane holds 4 consecutive d (row) for q (col) = qi*16+fr ----
    const float il0 = 1.0f / lr0, il1 = 1.0f / lr1;
#pragma unroll
    for (int df = 0; df < 8; df++) {
        uint2v w0, w1;
        w0[0] = cvtpk(ot[df][0][0] * il0, ot[df][0][1] * il0);
        w0[1] = cvtpk(ot[df][0][2] * il0, ot[df][0][3] * il0);
        w1[0] = cvtpk(ot[df][1][0] * il1, ot[df][1][1] * il1);
        w1[1] = cvtpk(ot[df][1][2] * il1, ot[df][1][3] * il1);
        *(uint2v*)&o[obase + (long)(fr) * HD + df * 16 + kg * 4] = w0;
        *(uint2v*)&o[obase + (long)(16 + fr) * HD + df * 16 + kg * 4] = w1;
    }
}

extern "C" void kernel_launch(void* const* d_in, const int* in_sizes, int n_in,
                              void* d_out, int out_size, void* d_ws, size_t ws_size,
                              hipStream_t stream) {
    (void)in_sizes; (void)n_in; (void)out_size; (void)ws_size;
    const float* x = (const float*)d_in[0];
    const float* Wq = (const float*)d_in[1];
    const float* Wk = (const float*)d_in[2];
    const float* Wv = (const float*)d_in[3];
    const float* Wo = (const float*)d_in[4];

    char* ws = (char*)d_ws;
    u16* xb   = (u16*)(ws + 0);            // 33.5MB  (b,t,c) bf16; later reused as attn output (b,t,h,d)
    u16* vtb  = (u16*)(ws + 50331648);     // 8.4MB   (b,kv,d,t)
    u16* wqt  = (u16*)(ws + 58720256);     // 8.4MB   (first part of fused Wt, 3072 x 2048)
    u16* wkt  = (u16*)(ws + 67108864);     // 2.1MB   (contiguous after wqt)
    u16* wvt  = (u16*)(ws + 69206016);     // 2.1MB   (contiguous after wkt)
    u16* wot  = (u16*)(ws + 71303168);     // 8.4MB
    float* cosb = (float*)(ws + 79691776); // 0.5MB
    float* sinb = (float*)(ws + 80216064); // 0.5MB
    u16* qkv = (u16*)d_out;                // fused qkv (8192 x 3072) bf16 lives in d_out until final GEMM

    dim3 tb(32, 8);
    cast_k<<<16384, 256, 0, stream>>>(x, xb, 4194304);
    twt_k<<<dim3(64, 64), tb, 0, stream>>>(Wq, wqt, 2048, 2048);
    twt_k<<<dim3(16, 64), tb, 0, stream>>>(Wk, wkt, 2048, 512);
    twt_k<<<dim3(16, 64), tb, 0, stream>>>(Wv, wvt, 2048, 512);
    twt_k<<<dim3(64, 64), tb, 0, stream>>>(Wo, wot, 2048, 2048);
    tables_k<<<512, 256, 0, stream>>>(cosb, sinb);

    // fused QKV projection: one GEMM, N = 2048+512+512
    gemm_k<0><<<dim3(32, 24), 512, 0, stream>>>(xb, wqt, qkv, 8192, NQKV, 2048);

    // q scale = (1/sqrt(128)) * log2(e) -> softmax runs in exp2 domain
    rope_k<<<4096, 256, 0, stream>>>(qkv, cosb, sinb, 16, 0.1275174316f, 1048576, NQKV, 0);
    rope_k<<<1024, 256, 0, stream>>>(qkv, cosb, sinb, 4, 1.0f, 262144, NQKV, 2048);
    tv_k<<<dim3(4, 64, 16), tb, 0, stream>>>(qkv, vtb);

    attn_k<<<dim3(16, 64), 256, 0, stream>>>(qkv, vtb, xb);

    gemm_k<1><<<dim3(32, 16), 512, 0, stream>>>(xb, wot, d_out, 8192, 2048, 2048);
}

// Round 16
// 341.888 us; speedup vs baseline: 2.2371x; 1.0075x over previous
//
#include <hip/hip_runtime.h>
#include <cstdint>

#define DEV __device__ __forceinline__

typedef __attribute__((ext_vector_type(4))) float f32x4;
typedef __attribute__((ext_vector_type(4))) float float4v;
typedef __attribute__((ext_vector_type(8))) short bf16x8;
typedef __attribute__((ext_vector_type(4))) unsigned short ushort4v;
typedef __attribute__((ext_vector_type(2))) unsigned int uint2v;
typedef unsigned short u16;

static constexpr int Bb = 4, Tt = 2048, Hh = 16, KVh = 4, Dd = 128;
static constexpr int NQKV = 3072;   // fused projection width: 2048 q + 512 k + 512 v

DEV u16 f2bf(float x) {
    union { float f; unsigned u; } v; v.f = x;
    unsigned r = v.u + 0x7FFF + ((v.u >> 16) & 1);
    return (u16)(r >> 16);
}
DEV float bf2f(u16 b) {
    union { unsigned u; float f; } v; v.u = ((unsigned)b) << 16;
    return v.f;
}
DEV unsigned cvtpk(float lo, float hi) {
    unsigned d;
    asm("v_cvt_pk_bf16_f32 %0, %1, %2" : "=v"(d) : "v"(lo), "v"(hi));
    return d;
}

typedef const void __attribute__((address_space(1)))* gas1;
typedef void __attribute__((address_space(3)))* las3;
DEV void gload16(const void* g, void* l) {
    __builtin_amdgcn_global_load_lds((gas1)g, (las3)l, 16, 0, 0);
}

// ---------------- cast x -> bf16 ----------------
__global__ __launch_bounds__(256) void cast_k(const float* __restrict__ x, u16* __restrict__ xb, long n4) {
    long id = (long)blockIdx.x * 256 + threadIdx.x;
    if (id >= n4) return;
    float4v v = *(const float4v*)&x[id * 4];
    ushort4v o;
    o[0] = f2bf(v[0]); o[1] = f2bf(v[1]); o[2] = f2bf(v[2]); o[3] = f2bf(v[3]);
    *(ushort4v*)&xb[id * 4] = o;
}

// ---------------- transpose+cast weight: W (K x N) f32 -> Wt (N x K) bf16 ----------------
__global__ __launch_bounds__(256) void twt_k(const float* __restrict__ W, u16* __restrict__ Wt, int K, int N) {
    __shared__ float tile[32][33];
    int tx = threadIdx.x, ty = threadIdx.y;
    long n0 = (long)blockIdx.x * 32, k0 = (long)blockIdx.y * 32;
#pragma unroll
    for (int j = 0; j < 4; j++)
        tile[ty + j * 8][tx] = W[(k0 + ty + j * 8) * (long)N + n0 + tx];
    __syncthreads();
#pragma unroll
    for (int j = 0; j < 4; j++)
        Wt[(n0 + ty + j * 8) * (long)K + k0 + tx] = f2bf(tile[tx][ty + j * 8]);
}

// ---------------- transpose v (from fused qkv, stride 3072, col 2560) -> vt (b,kv,d,t) ----------------
__global__ __launch_bounds__(256) void tv_k(const u16* __restrict__ qkv, u16* __restrict__ vt) {
    __shared__ u16 tile[32][33];
    int tx = threadIdx.x, ty = threadIdx.y;
    int d0 = blockIdx.x * 32;
    int t0 = blockIdx.y * 32;
    int bk = blockIdx.z;
    int b = bk >> 2, kv = bk & 3;
#pragma unroll
    for (int j = 0; j < 4; j++)
        tile[ty + j * 8][tx] = qkv[(long)(b * Tt + t0 + ty + j * 8) * NQKV + 2560 + kv * Dd + d0 + tx];
    __syncthreads();
#pragma unroll
    for (int j = 0; j < 4; j++)
        vt[((long)(b * KVh + kv) * Dd + d0 + ty + j * 8) * Tt + t0 + tx] = tile[tx][ty + j * 8];
}

// ---------------- rope tables: [t][i], i<64 ----------------
__global__ __launch_bounds__(256) void tables_k(float* __restrict__ cosb, float* __restrict__ sinb) {
    int id = blockIdx.x * 256 + threadIdx.x; // < 2048*64
    int t = id >> 6, i = id & 63;
    float inv = powf(10000.0f, -(float)i * (1.0f / 64.0f));
    float f = (float)t * inv;
    cosb[id] = cosf(f);
    sinb[id] = sinf(f);
}

// ---------------- rope v2: vectorized (8 lanes of rotation pair per thread) ----------------
__global__ __launch_bounds__(256) void rope_k(u16* __restrict__ p, const float* __restrict__ cosb,
                                              const float* __restrict__ sinb, int nh, float scale, int total8,
                                              long rowstride, int colbase) {
    int id = blockIdx.x * 256 + threadIdx.x;
    if (id >= total8) return;
    int i8 = id & 7;
    int bth = id >> 3;
    int row = bth / nh;
    int t = row % Tt;
    u16* ptr = p + (long)row * rowstride + colbase + (bth % nh) * Dd + i8 * 8;
    ushort4v a0 = *(ushort4v*)&ptr[0];
    ushort4v a1 = *(ushort4v*)&ptr[4];
    ushort4v b0 = *(ushort4v*)&ptr[64];
    ushort4v b1 = *(ushort4v*)&ptr[68];
    const float4v c0 = *(const float4v*)&cosb[t * 64 + i8 * 8];
    const float4v c1 = *(const float4v*)&cosb[t * 64 + i8 * 8 + 4];
    const float4v s0 = *(const float4v*)&sinb[t * 64 + i8 * 8];
    const float4v s1 = *(const float4v*)&sinb[t * 64 + i8 * 8 + 4];
    ushort4v oa0, oa1, ob0, ob1;
#pragma unroll
    for (int j = 0; j < 4; j++) {
        float x1 = bf2f(a0[j]), x2 = bf2f(b0[j]);
        oa0[j] = f2bf((x1 * c0[j] - x2 * s0[j]) * scale);
        ob0[j] = f2bf((x2 * c0[j] + x1 * s0[j]) * scale);
        float y1 = bf2f(a1[j]), y2 = bf2f(b1[j]);
        oa1[j] = f2bf((y1 * c1[j] - y2 * s1[j]) * scale);
        ob1[j] = f2bf((y2 * c1[j] + y1 * s1[j]) * scale);
    }
    *(ushort4v*)&ptr[0] = oa0;
    *(ushort4v*)&ptr[4] = oa1;
    *(ushort4v*)&ptr[64] = ob0;
    *(ushort4v*)&ptr[68] = ob1;
}

// ---------------- GEMM v4: 256x128, 8 waves, BK=64, 3-slot ring, swizzled LDS, 2-phase interleave ----------------
template <int F32OUT>
__global__ __launch_bounds__(512) void gemm_k(const u16* __restrict__ A, const u16* __restrict__ Bt,
                                              void* __restrict__ Cout, int M, int N, int K) {
    __shared__ u16 lds[3][24576];   // per slot: A 256x64 (16384 u16) | B 128x64 (8192 u16)
    const int tid = threadIdx.x;
    const int lane = tid & 63;
    const int w = __builtin_amdgcn_readfirstlane(tid >> 6);   // 0..7
    const int wm = w >> 1, wn = w & 1;
    const long m0 = (long)blockIdx.x * 256;
    const long n0 = (long)blockIdx.y * 128;
    const int NT = K >> 6;
    const int l8 = lane >> 3, s8 = lane & 7;
    const int fr = lane & 15, kg = lane >> 4;   // kg 0..3

    auto stageA = [&](int t) {
        u16* base = lds[t % 3];
        const long ko = (long)t * 64;
#pragma unroll
        for (int c4 = 0; c4 < 4; c4++) {       // A: 4 chunks of 1KB (8 rows each)
            int c = w * 4 + c4;
            int row = c * 8 + l8;
            int slog = s8 ^ (l8 & 7);
            gload16(A + (m0 + row) * (long)K + ko + slog * 8, base + c * 512);
        }
    };
    auto stageB = [&](int t) {
        u16* base = lds[t % 3];
        const long ko = (long)t * 64;
#pragma unroll
        for (int c2 = 0; c2 < 2; c2++) {       // B: 2 chunks
            int c = w * 2 + c2;
            int row = c * 8 + l8;
            int slog = s8 ^ (l8 & 7);
            gload16(Bt + (n0 + row) * (long)K + ko + slog * 8, base + 16384 + c * 512);
        }
    };

    f32x4 acc[4][4] = {};
    stageA(0); stageB(0);
    if (NT > 1) {
        stageA(1); stageB(1);
        asm volatile("s_waitcnt vmcnt(6)" ::: "memory");
    } else {
        asm volatile("s_waitcnt vmcnt(0)" ::: "memory");
    }
    __builtin_amdgcn_s_barrier();

    for (int t = 0; t < NT; ++t) {
        const u16* sa = lds[t % 3];
        const u16* sb = sa + 16384;
        // ---- phase 0 (ks = 0) ----
        {
            bf16x8 af[4], bfr[4];
#pragma unroll
            for (int i = 0; i < 4; i++) {
                const int row = wm * 64 + i * 16 + fr;
                af[i] = *(const bf16x8*)&sa[row * 64 + ((kg ^ (row & 7)) * 8)];
                const int col = wn * 64 + i * 16 + fr;
                bfr[i] = *(const bf16x8*)&sb[col * 64 + ((kg ^ (col & 7)) * 8)];
            }
            if (t + 2 < NT) stageA(t + 2);
            __builtin_amdgcn_s_barrier();
            __builtin_amdgcn_s_setprio(1);
#pragma unroll
            for (int i = 0; i < 4; i++)
#pragma unroll
                for (int j = 0; j < 4; j++)
                    acc[i][j] = __builtin_amdgcn_mfma_f32_16x16x32_bf16(af[i], bfr[j], acc[i][j], 0, 0, 0);
            __builtin_amdgcn_s_setprio(0);
            __builtin_amdgcn_s_barrier();
        }
        // ---- phase 1 (ks = 1) ----
        {
            bf16x8 af[4], bfr[4];
#pragma unroll
            for (int i = 0; i < 4; i++) {
                const int row = wm * 64 + i * 16 + fr;
                af[i] = *(const bf16x8*)&sa[row * 64 + (((4 + kg) ^ (row & 7)) * 8)];
                const int col = wn * 64 + i * 16 + fr;
                bfr[i] = *(const bf16x8*)&sb[col * 64 + (((4 + kg) ^ (col & 7)) * 8)];
            }
            if (t + 2 < NT) stageB(t + 2);
            if (t + 2 < NT)
                asm volatile("s_waitcnt vmcnt(6)" ::: "memory");
            else if (t + 1 < NT)
                asm volatile("s_waitcnt vmcnt(0)" ::: "memory");
            __builtin_amdgcn_s_barrier();
            __builtin_amdgcn_s_setprio(1);
#pragma unroll
            for (int i = 0; i < 4; i++)
#pragma unroll
                for (int j = 0; j < 4; j++)
                    acc[i][j] = __builtin_amdgcn_mfma_f32_16x16x32_bf16(af[i], bfr[j], acc[i][j], 0, 0, 0);
            __builtin_amdgcn_s_setprio(0);
            __builtin_amdgcn_s_barrier();
        }
    }

    const int orow = (lane >> 4) * 4, ocol = lane & 15;
#pragma unroll
    for (int i = 0; i < 4; i++)
#pragma unroll
        for (int j = 0; j < 4; j++) {
            long r = m0 + wm * 64 + i * 16 + orow;
            long c = n0 + wn * 64 + j * 16 + ocol;
#pragma unroll
            for (int t = 0; t < 4; t++) {
                if (F32OUT)
                    ((float*)Cout)[(r + t) * N + c] = acc[i][j][t];
                else
                    ((u16*)Cout)[(r + t) * N + c] = f2bf(acc[i][j][t]);
            }
        }
}

// ---------------- flash attention v13: QK-ahead pipeline (3-ring K), XCD-grouped, va-reuse ----------------
// Per tile the serial chain {QK -> softmax -> pT -> PV} is broken by computing QK(it+1) between
// softmax(it) and PV(it): its ds_reads+MFMAs overlap the softmax VALU chain + pT roundtrip.
// K in a 3-slot ring staged 2 ahead (slot (it+2)%3 last read by QK(it) at iter it-1, one barrier
// apart); V 2-buffer staged 1 ahead (unchanged WAR discipline). __syncthreads vmcnt(0) drain is
// covered by a full body of compute. All per-tile math verbatim from verified v12.
__global__ __launch_bounds__(256, 3) void attn_k(const u16* __restrict__ qkv,
                                                 const u16* __restrict__ vt, u16* __restrict__ o) {
    __shared__ u16 kl[3][4096];
    __shared__ u16 vl[2][4096];
    __shared__ u16 pT[4][2][16][36];
    const int tid = threadIdx.x;
    const int lane = tid & 63;
    const int w = tid >> 6;
    const int kvb = blockIdx.x;       // kv + 4*b  (XCD group key)
    const int kv = kvb & 3, b = kvb >> 2;
    const int qt = 63 - (int)blockIdx.y;
    const int q0 = qt * 32;
    const int h = kv * 4 + w;
    const int fr = lane & 15, kg = lane >> 4;
    const long HD = (long)Hh * Dd;               // output row stride (2048)
    const long QS = (long)NQKV;                  // fused row stride (3072)
    const long kbase = (long)b * Tt * QS + 2048 + (long)kv * Dd;
    const long vbase = ((long)(b * KVh + kv)) * (long)Dd * Tt;
    const long qbase = (long)(b * Tt + q0) * QS + (long)h * Dd;
    const long obase = (long)(b * Tt + q0) * HD + (long)h * Dd;

    auto stage_k = [&](int t) {
        const int s0 = t * 32;
        const int lh = lane >> 4;     // 0..3
#pragma unroll
        for (int j = 0; j < 2; j++) { // K: 8 chunks of 1KB, chunk c = j*4+w
            int c = j * 4 + w;
            int row = c * 4 + lh;
            int c16 = (lane & 15) ^ (row & 7);
            gload16(qkv + kbase + (long)(s0 + row) * QS + c16 * 8, &kl[t % 3][c * 512]);
        }
    };
    auto stage_v = [&](int t) {
        const int s0 = t * 32;
        const int lh = lane >> 4;
#pragma unroll
        for (int j = 0; j < 2; j++) { // V: 8 chunks of 1KB
            int c = j * 4 + w;
            int rowp = c * 4 + lh;
            int c16u = (lane & 15) ^ (rowp & 7);
            int r = rowp * 4 + (c16u >> 2);
            gload16(vt + vbase + (long)r * Tt + s0 + (c16u & 3) * 8, &vl[t & 1][c * 512]);
        }
    };

    bf16x8 qa[2][4];
#pragma unroll
    for (int qi = 0; qi < 2; qi++)
#pragma unroll
        for (int kc = 0; kc < 4; kc++)
            qa[qi][kc] = *(const bf16x8*)&qkv[qbase + (long)(qi * 16 + fr) * QS + kc * 32 + kg * 8];

    // QK^T of one 32-k tile from a given kl slot into st[kf][qi]
    auto qkcomp = [&](const u16* klbuf, f32x4 (&st)[2][2]) {
        __builtin_amdgcn_s_setprio(1);
#pragma unroll
        for (int kf = 0; kf < 2; kf++) {
            const int rr = kf * 16 + fr;
            bf16x8 ka[4];
#pragma unroll
            for (int kc = 0; kc < 4; kc++)
                ka[kc] = *(const bf16x8*)&klbuf[rr * 128 + (((kc * 4 + kg) ^ (rr & 7)) * 8)];
#pragma unroll
            for (int kc = 0; kc < 4; kc++) {
                st[kf][0] = __builtin_amdgcn_mfma_f32_16x16x32_bf16(ka[kc], qa[0][kc], st[kf][0], 0, 0, 0);
                st[kf][1] = __builtin_amdgcn_mfma_f32_16x16x32_bf16(ka[kc], qa[1][kc], st[kf][1], 0, 0, 0);
            }
        }
        __builtin_amdgcn_s_setprio(0);
    };

    f32x4 ot[8][2] = {};              // O^T accumulator: [df][qi]
    float mr0 = -1e30f, mr1 = -1e30f, lr0 = 0.0f, lr1 = 0.0f;
    const int nt = qt + 1;

    stage_k(0); stage_v(0);
    if (nt > 1) stage_k(1);
    __syncthreads();

    f32x4 stA[2][2] = {};
    qkcomp(kl[0], stA);

    for (int it = 0; it < nt; ++it) {
        if (it + 2 < nt) stage_k(it + 2);
        if (it + 1 < nt) stage_v(it + 1);
        const int s0 = it * 32;
        // ---- causal mask (diagonal tile only) ----
        if (it == nt - 1) {
#pragma unroll
            for (int kf = 0; kf < 2; kf++)
#pragma unroll
                for (int qi = 0; qi < 2; qi++) {
                    const int qq = q0 + qi * 16 + fr;
                    const int kb0 = s0 + kf * 16 + kg * 4;
#pragma unroll
                    for (int r = 0; r < 4; r++)
                        if (kb0 + r > qq) stA[kf][qi][r] = -1e30f;
                }
        }
        // ---- in-register online softmax (base-2 domain) ----
        float tm0 = stA[0][0][0], tm1 = stA[0][1][0];
#pragma unroll
        for (int kf = 0; kf < 2; kf++)
#pragma unroll
            for (int r = 0; r < 4; r++)
                if (kf | r) {
                    tm0 = fmaxf(tm0, stA[kf][0][r]);
                    tm1 = fmaxf(tm1, stA[kf][1][r]);
                }
        tm0 = fmaxf(tm0, __shfl_xor(tm0, 16)); tm0 = fmaxf(tm0, __shfl_xor(tm0, 32));
        tm1 = fmaxf(tm1, __shfl_xor(tm1, 16)); tm1 = fmaxf(tm1, __shfl_xor(tm1, 32));
        if (__any(fmaxf(tm0 - mr0, tm1 - mr1) > 8.0f)) {
            float mn0 = fmaxf(mr0, tm0), mn1 = fmaxf(mr1, tm1);
            float al0 = __builtin_amdgcn_exp2f(mr0 - mn0);
            float al1 = __builtin_amdgcn_exp2f(mr1 - mn1);
            mr0 = mn0; mr1 = mn1;
            lr0 *= al0; lr1 *= al1;
#pragma unroll
            for (int df = 0; df < 8; df++) { ot[df][0] *= al0; ot[df][1] *= al1; }
        }
        float rs0 = 0.0f, rs1 = 0.0f;
#pragma unroll
        for (int kf = 0; kf < 2; kf++)
#pragma unroll
            for (int r = 0; r < 4; r++) {
                stA[kf][0][r] = __builtin_amdgcn_exp2f(stA[kf][0][r] - mr0); rs0 += stA[kf][0][r];
                stA[kf][1][r] = __builtin_amdgcn_exp2f(stA[kf][1][r] - mr1); rs1 += stA[kf][1][r];
            }
        rs0 += __shfl_xor(rs0, 16); rs0 += __shfl_xor(rs0, 32);
        rs1 += __shfl_xor(rs1, 16); rs1 += __shfl_xor(rs1, 32);
        lr0 += rs0; lr1 += rs1;
        // ---- stage P^T for BOTH qi ----
#pragma unroll
        for (int qi = 0; qi < 2; qi++) {
            uint2v w0;
            w0[0] = cvtpk(stA[0][qi][0], stA[0][qi][1]);
            w0[1] = cvtpk(stA[0][qi][2], stA[0][qi][3]);
            *(uint2v*)&pT[w][qi][fr][kg * 4] = w0;
            uint2v w1;
            w1[0] = cvtpk(stA[1][qi][0], stA[1][qi][1]);
            w1[1] = cvtpk(stA[1][qi][2], stA[1][qi][3]);
            *(uint2v*)&pT[w][qi][fr][16 + kg * 4] = w1;
        }
        // ---- QK-ahead: compute next tile's S^T while softmax results settle ----
        f32x4 stB[2][2] = {};
        if (it + 1 < nt) qkcomp(kl[(it + 1) % 3], stB);
        // ---- PV: each V fragment read once, feeds both qi ----
        {
            bf16x8 bq0 = *(const bf16x8*)&pT[w][0][fr][kg * 8];
            bf16x8 bq1 = *(const bf16x8*)&pT[w][1][fr][kg * 8];
            __builtin_amdgcn_s_setprio(1);
#pragma unroll
            for (int df = 0; df < 8; df++) {
                const int r = df * 16 + fr;
                const int rowp = r >> 2;
                const int c16 = (((r & 3) * 4 + kg) ^ (rowp & 7));
                bf16x8 va = *(const bf16x8*)&vl[it & 1][rowp * 128 + c16 * 8];
                ot[df][0] = __builtin_amdgcn_mfma_f32_16x16x32_bf16(va, bq0, ot[df][0], 0, 0, 0);
                ot[df][1] = __builtin_amdgcn_mfma_f32_16x16x32_bf16(va, bq1, ot[df][1], 0, 0, 0);
            }
            __builtin_amdgcn_s_setprio(0);
        }
        __syncthreads();
#pragma unroll
        for (int kf = 0; kf < 2; kf++)
#pragma unroll
            for (int qi = 0; qi < 2; qi++)
                stA[kf][qi] = stB[kf][qi];
    }
    // ---- store: lane holds 4 consecutive d (row) for q (col) = qi*16+fr ----
    const float il0 = 1.0f / lr0, il1 = 1.0f / lr1;
#pragma unroll
    for (int df = 0; df < 8; df++) {
        uint2v w0, w1;
        w0[0] = cvtpk(ot[df][0][0] * il0, ot[df][0][1] * il0);
        w0[1] = cvtpk(ot[df][0][2] * il0, ot[df][0][3] * il0);
        w1[0] = cvtpk(ot[df][1][0] * il1, ot[df][1][1] * il1);
        w1[1] = cvtpk(ot[df][1][2] * il1, ot[df][1][3] * il1);
        *(uint2v*)&o[obase + (long)(fr) * HD + df * 16 + kg * 4] = w0;
        *(uint2v*)&o[obase + (long)(16 + fr) * HD + df * 16 + kg * 4] = w1;
    }
}

extern "C" void kernel_launch(void* const* d_in, const int* in_sizes, int n_in,
                              void* d_out, int out_size, void* d_ws, size_t ws_size,
                              hipStream_t stream) {
    (void)in_sizes; (void)n_in; (void)out_size; (void)ws_size;
    const float* x = (const float*)d_in[0];
    const float* Wq = (const float*)d_in[1];
    const float* Wk = (const float*)d_in[2];
    const float* Wv = (const float*)d_in[3];
    const float* Wo = (const float*)d_in[4];

    char* ws = (char*)d_ws;
    u16* xb   = (u16*)(ws + 0);            // 33.5MB  (b,t,c) bf16; later reused as attn output (b,t,h,d)
    u16* vtb  = (u16*)(ws + 50331648);     // 8.4MB   (b,kv,d,t)
    u16* wqt  = (u16*)(ws + 58720256);     // 8.4MB   (first part of fused Wt, 3072 x 2048)
    u16* wkt  = (u16*)(ws + 67108864);     // 2.1MB   (contiguous after wqt)
    u16* wvt  = (u16*)(ws + 69206016);     // 2.1MB   (contiguous after wkt)
    u16* wot  = (u16*)(ws + 71303168);     // 8.4MB
    float* cosb = (float*)(ws + 79691776); // 0.5MB
    float* sinb = (float*)(ws + 80216064); // 0.5MB
    u16* qkv = (u16*)d_out;                // fused qkv (8192 x 3072) bf16 lives in d_out until final GEMM

    dim3 tb(32, 8);
    cast_k<<<16384, 256, 0, stream>>>(x, xb, 4194304);
    twt_k<<<dim3(64, 64), tb, 0, stream>>>(Wq, wqt, 2048, 2048);
    twt_k<<<dim3(16, 64), tb, 0, stream>>>(Wk, wkt, 2048, 512);
    twt_k<<<dim3(16, 64), tb, 0, stream>>>(Wv, wvt, 2048, 512);
    twt_k<<<dim3(64, 64), tb, 0, stream>>>(Wo, wot, 2048, 2048);
    tables_k<<<512, 256, 0, stream>>>(cosb, sinb);

    // fused QKV projection: one GEMM, N = 2048+512+512
    gemm_k<0><<<dim3(32, 24), 512, 0, stream>>>(xb, wqt, qkv, 8192, NQKV, 2048);

    // q scale = (1/sqrt(128)) * log2(e) -> softmax runs in exp2 domain
    rope_k<<<4096, 256, 0, stream>>>(qkv, cosb, sinb, 16, 0.1275174316f, 1048576, NQKV, 0);
    rope_k<<<1024, 256, 0, stream>>>(qkv, cosb, sinb, 4, 1.0f, 262144, NQKV, 2048);
    tv_k<<<dim3(4, 64, 16), tb, 0, stream>>>(qkv, vtb);

    attn_k<<<dim3(16, 64), 256, 0, stream>>>(qkv, vtb, xb);

    gemm_k<1><<<dim3(32, 16), 512, 0, stream>>>(xb, wot, d_out, 8192, 2048, 2048);
}